// Round 10
// baseline (462.069 us; speedup 1.0000x reference)
//
#include <hip/hip_runtime.h>
#include <hip/hip_bf16.h>
#include <hip/hip_fp16.h>

#define HID 128
#define BIN_T 8192
#define NBMAX 1664   // max 64-node buckets (N <= 106496)

typedef _Float16 f16;
typedef __attribute__((ext_vector_type(2))) _Float16 f16x2;
typedef __attribute__((ext_vector_type(4))) _Float16 f16x4;
typedef __attribute__((ext_vector_type(8))) _Float16 f16x8;
typedef __attribute__((ext_vector_type(4))) float f32x4;

// ---------------- bucket histogram (dst>>6) ----------------

__global__ void k_hist_bucket(const int* __restrict__ dst, int* __restrict__ bcount,
                              int E, int NB) {
    __shared__ int h[NBMAX];
    for (int i = threadIdx.x; i < NB; i += 256) h[i] = 0;
    __syncthreads();
    for (long long i = (long long)blockIdx.x * 256 + threadIdx.x; i < E;
         i += (long long)gridDim.x * 256)
        atomicAdd(&h[((unsigned)dst[i]) >> 6], 1);
    __syncthreads();
    for (int i = threadIdx.x; i < NB; i += 256)
        if (h[i]) atomicAdd(&bcount[i], h[i]);
}

// single-block exclusive scan over NB buckets -> boff, bcursor; re-zeros bcount
__global__ void k_bucket_scan(const int* __restrict__ bcount_in, int* __restrict__ bcount,
                              int* __restrict__ boff, int* __restrict__ bcursor, int NB) {
    __shared__ int tt[256];
    int ts = threadIdx.x;
    int b0 = ts * 7;
    int loc[7]; int run = 0;
    #pragma unroll
    for (int k = 0; k < 7; ++k) {
        int b = b0 + k;
        int c = (b < NB) ? bcount_in[b] : 0;
        loc[k] = run; run += c;
    }
    tt[ts] = run;
    __syncthreads();
    int val = run;
    for (int off = 1; off < 256; off <<= 1) {
        int add = (ts >= off) ? tt[ts - off] : 0;
        __syncthreads();
        tt[ts] += add;
        __syncthreads();
    }
    int ebase = tt[ts] - val;
    #pragma unroll
    for (int k = 0; k < 7; ++k) {
        int b = b0 + k;
        if (b < NB) {
            boff[b] = ebase + loc[k];
            bcursor[b] = ebase + loc[k];
            bcount[b] = 0;   // ready for next branch
        }
    }
    if (ts == 255) boff[NB] = tt[255];
}

// ---------------- tile-sorted bucket binning (coalesced writes) ----------------
// pairs[slot] = src | (dst&63)<<26, grouped by bucket (dst>>6).

__global__ void k_tile_bin(const int* __restrict__ src, const int* __restrict__ dst,
                           int* __restrict__ bcursor, unsigned int* __restrict__ pairs,
                           int E, int NB) {
    __shared__ unsigned int dbuf[BIN_T];
    __shared__ unsigned short perm[BIN_T];
    __shared__ int hist[NBMAX];
    __shared__ int lbase[NBMAX];
    __shared__ int gbase[NBMAX];
    __shared__ int tt[256];
    int t = threadIdx.x;
    int tilebase = blockIdx.x * BIN_T;
    int n = min(BIN_T, E - tilebase);
    for (int i = t; i < NB; i += 256) hist[i] = 0;
    __syncthreads();
    for (int i = t; i < n; i += 256) {
        unsigned int d = (unsigned int)dst[tilebase + i];
        dbuf[i] = d;
        atomicAdd(&hist[d >> 6], 1);
    }
    __syncthreads();
    {
        int b0 = t * 7, loc[7], run = 0;
        #pragma unroll
        for (int k = 0; k < 7; ++k) {
            int b = b0 + k;
            int c = (b < NB) ? hist[b] : 0;
            loc[k] = run; run += c;
        }
        tt[t] = run;
        __syncthreads();
        int val = run;
        for (int off = 1; off < 256; off <<= 1) {
            int add = (t >= off) ? tt[t - off] : 0;
            __syncthreads();
            tt[t] += add;
            __syncthreads();
        }
        int ebase = tt[t] - val;
        #pragma unroll
        for (int k = 0; k < 7; ++k) {
            int b = b0 + k;
            if (b < NB) lbase[b] = ebase + loc[k];
        }
    }
    __syncthreads();
    for (int i = t; i < NB; i += 256) {
        int c = hist[i];
        gbase[i] = (c > 0) ? atomicAdd(&bcursor[i], c) : 0;
    }
    __syncthreads();
    for (int i = t; i < NB; i += 256) hist[i] = lbase[i];
    __syncthreads();
    for (int i = t; i < n; i += 256) {
        int b = (int)(dbuf[i] >> 6);
        int p = atomicAdd(&hist[b], 1);
        perm[p] = (unsigned short)i;
    }
    __syncthreads();
    for (int p = t; p < n; p += 256) {
        int li = perm[p];
        unsigned int d = dbuf[li];
        int b = (int)(d >> 6);
        int addr = gbase[b] + (p - lbase[b]);
        pairs[addr] = (unsigned int)src[tilebase + li] | ((d & 63u) << 26);
    }
}

// ---------------- bucket fill: degrees, dinv, rowptr, rec8, res8, csr ----------------

__global__ void k_bucket_fill2(const unsigned int* __restrict__ pairs,
                               const int* __restrict__ boff,
                               const int* __restrict__ residue, const float* __restrict__ pos,
                               int* __restrict__ csr_src, f16x4* __restrict__ rec8,
                               unsigned char* __restrict__ res8, float* __restrict__ dinvA,
                               int* __restrict__ rowptr, int N) {
    __shared__ int cnt[64];
    __shared__ int cur[64];
    int b = blockIdx.x, t = threadIdx.x, base = b * 64;
    if (t < 64) cnt[t] = 0;
    __syncthreads();
    int lo = boff[b], hi = boff[b + 1];
    for (int e = lo + t; e < hi; e += 256)
        atomicAdd(&cnt[pairs[e] >> 26], 1);
    __syncthreads();
    if (t < 64) {
        int off = 0;
        for (int k = 0; k < t; ++k) off += cnt[k];
        int node = base + t;
        if (node < N) {
            rowptr[node] = lo + off;
            if (node == N - 1) rowptr[N] = hi;
            float d = (float)cnt[t] + 1.0f;   // +1 self loop
            float di = 1.0f / sqrtf(d);
            dinvA[node] = di;
            float px = pos[node * 3 + 0], py = pos[node * 3 + 1], pz = pos[node * 3 + 2];
            f16x4 r;
            r[0] = (f16)di; r[1] = (f16)(di * px); r[2] = (f16)(di * py); r[3] = (f16)(di * pz);
            rec8[node] = r;
            res8[node] = (unsigned char)residue[node];
        }
        cur[t] = lo + off;
    }
    __syncthreads();
    for (int e = lo + t; e < hi; e += 256) {
        unsigned int pk = pairs[e];
        int slot = atomicAdd(&cur[pk >> 26], 1);
        csr_src[slot] = (int)(pk & 0x3FFFFFFu);
    }
}

// ---------------- fused layer-1: bucket aggregation (24-dim) + GEMM + premult ----------------

__global__ __launch_bounds__(256) void k_l1_fused(
        const unsigned int* __restrict__ pairs, const int* __restrict__ boff,
        const f16x4* __restrict__ rec8, const unsigned char* __restrict__ res8,
        const float* __restrict__ W, const float* __restrict__ bias,
        const float* __restrict__ dinvA, f16* __restrict__ y1h, int N) {
    __shared__ float acc[64][25];
    __shared__ float Ws[23 * 128];
    __shared__ float sdv[64];
    int b = blockIdx.x, t = threadIdx.x, base = b * 64;
    for (int q = t; q < 64 * 25; q += 256) ((float*)acc)[q] = 0.f;
    for (int q = t; q < 23 * 128; q += 256) Ws[q] = W[q];
    if (t < 64 && base + t < N) sdv[t] = dinvA[base + t];
    __syncthreads();
    int lo = boff[b], hi = boff[b + 1];
    for (int e = lo + t; e < hi; e += 256) {
        unsigned int pk = pairs[e];
        int s = (int)(pk & 0x3FFFFFFu), dl = (int)(pk >> 26);
        f16x4 r = rec8[s];
        int rs = res8[s];
        atomicAdd(&acc[dl][rs], (float)r[0]);
        atomicAdd(&acc[dl][20], (float)r[1]);
        atomicAdd(&acc[dl][21], (float)r[2]);
        atomicAdd(&acc[dl][22], (float)r[3]);
    }
    __syncthreads();
    if (t < 64) {
        int node = base + t;
        if (node < N) {
            f16x4 r = rec8[node];
            acc[t][res8[node]] += (float)r[0];
            acc[t][20] += (float)r[1];
            acc[t][21] += (float)r[2];
            acc[t][22] += (float)r[3];
            float di = sdv[t];
            #pragma unroll
            for (int k = 0; k < 23; ++k) acc[t][k] *= di;
        }
    }
    __syncthreads();
    int jj = (t & 63) * 2, slot = t >> 6;   // 4 slots x 16 rows
    float bj0 = bias[jj], bj1 = bias[jj + 1];
    for (int r = slot * 16; r < slot * 16 + 16; ++r) {
        int node = base + r;
        if (node >= N) break;
        float a0 = bj0, a1 = bj1;
        #pragma unroll
        for (int k = 0; k < 23; ++k) {
            float zv = acc[r][k];
            a0 += zv * Ws[k * 128 + jj];
            a1 += zv * Ws[k * 128 + jj + 1];
        }
        float dv = sdv[r];
        f16x2 o;
        o[0] = (f16)(fmaxf(a0, 0.f) * dv);
        o[1] = (f16)(fmaxf(a1, 0.f) * dv);
        *(f16x2*)&y1h[(size_t)node * HID + jj] = o;
    }
}

// ---------------- layer-2 aggregation: wave-per-node, 2 edges in parallel, f16 out ----------------
// lanes 0-31 handle edge e (8B each), lanes 32-63 edge e+1; shfl_xor(32) combines.

__global__ __launch_bounds__(256) void k_agg_f16(
        const f16* __restrict__ y1h, const int* __restrict__ rowptr,
        const int* __restrict__ csr_src, const float* __restrict__ dinvA,
        f16* __restrict__ zh, int N) {
    int gw = (int)(((long long)blockIdx.x * blockDim.x + threadIdx.x) >> 6);
    int lane = threadIdx.x & 63;
    if (gw >= N) return;
    int half = lane >> 5;
    int c4 = (lane & 31) * 4;
    int s0 = rowptr[gw], s1 = rowptr[gw + 1];
    float a0 = 0.f, a1 = 0.f, a2 = 0.f, a3 = 0.f;
    int e = s0;
    for (; e + 4 <= s1; e += 4) {
        int sA = csr_src[e + half];
        int sB = csr_src[e + 2 + half];
        f16x4 vA = *(const f16x4*)(y1h + (size_t)sA * HID + c4);
        f16x4 vB = *(const f16x4*)(y1h + (size_t)sB * HID + c4);
        a0 += (float)vA[0] + (float)vB[0];
        a1 += (float)vA[1] + (float)vB[1];
        a2 += (float)vA[2] + (float)vB[2];
        a3 += (float)vA[3] + (float)vB[3];
    }
    if (e + 2 <= s1) {
        int sA = csr_src[e + half];
        f16x4 vA = *(const f16x4*)(y1h + (size_t)sA * HID + c4);
        a0 += (float)vA[0]; a1 += (float)vA[1];
        a2 += (float)vA[2]; a3 += (float)vA[3];
        e += 2;
    }
    if (e < s1 && half == 0) {
        int sA = csr_src[e];
        f16x4 vA = *(const f16x4*)(y1h + (size_t)sA * HID + c4);
        a0 += (float)vA[0]; a1 += (float)vA[1];
        a2 += (float)vA[2]; a3 += (float)vA[3];
    }
    a0 += __shfl_xor(a0, 32);
    a1 += __shfl_xor(a1, 32);
    a2 += __shfl_xor(a2, 32);
    a3 += __shfl_xor(a3, 32);
    if (half == 0) {
        float di = dinvA[gw];
        f16x4 sv = *(const f16x4*)(y1h + (size_t)gw * HID + c4);
        f16x4 o;
        o[0] = (f16)((a0 + (float)sv[0]) * di);
        o[1] = (f16)((a1 + (float)sv[1]) * di);
        o[2] = (f16)((a2 + (float)sv[2]) * di);
        o[3] = (f16)((a3 + (float)sv[3]) * di);
        *(f16x4*)(zh + (size_t)gw * HID + c4) = o;
    }
}

// ---------------- weight prep: fp16 transposed tables (+ zero bcount) ----------------

__global__ void k_prep_w(const float* __restrict__ Wp2, const float* __restrict__ Wm2,
                         const float* __restrict__ W1,
                         f16* __restrict__ Wp2t, f16* __restrict__ Wm2t,
                         f16* __restrict__ W1at, int* __restrict__ bcount) {
    int idx = blockIdx.x * 256 + threadIdx.x;
    if (idx <= NBMAX) bcount[idx] = 0;
    if (idx >= 128 * 128) return;
    int n = idx & 127, k = idx >> 7;
    Wp2t[n * 128 + k] = (f16)Wp2[k * 128 + n];
    Wm2t[n * 128 + k] = (f16)Wm2[k * 128 + n];
    W1at[n * 128 + k] = (f16)W1[k * 128 + n];
}

// graph sizes via binary search (batch sorted) + zero psum
__global__ void k_graph_sizes(const int* __restrict__ batch, int* __restrict__ pcnt,
                              float* __restrict__ psum, int N) {
    int t = blockIdx.x * 256 + threadIdx.x;
    if (t < 64 * HID) psum[t] = 0.f;
    if (t >= 64) return;
    int g = t;
    int lo = 0, hi = N;
    while (lo < hi) { int mid = (lo + hi) >> 1; if (batch[mid] < g) lo = mid + 1; else hi = mid; }
    int a = lo;
    lo = 0; hi = N;
    while (lo < hi) { int mid = (lo + hi) >> 1; if (batch[mid] < g + 1) lo = mid + 1; else hi = mid; }
    pcnt[g] = lo - a;
}

// ctxW[g] = (psum[g]/cnt[g]) @ W1[128:,:] + b1
__global__ void k_ctxw_div(const float* __restrict__ psum, const int* __restrict__ pcnt,
                           const float* __restrict__ W1, const float* __restrict__ b1,
                           float* __restrict__ ctxW) {
    __shared__ float pr[128];
    int g = blockIdx.x, j = threadIdx.x;
    pr[j] = psum[g * HID + j] / fmaxf((float)pcnt[g], 1.f);
    __syncthreads();
    float a = b1[j];
    #pragma unroll 4
    for (int k = 0; k < HID; ++k) a += pr[k] * W1[(HID + k) * HID + j];
    ctxW[g * HID + j] = a;
}

// ---------------- protein: x2 = relu(zh@Wp2+b) -> register pool -> psum ----------------
// A-frag: lane(lr,kb) reads zh row tile+w*16+lr, cols kc*32+kb*8 (f16x8, native layout).

__global__ __launch_bounds__(256) void k_gemm_pool_mfma(
        const f16* __restrict__ zh, const f16* __restrict__ Wt,
        const float* __restrict__ b, const int* __restrict__ batch,
        float* __restrict__ psum, int N) {
    __shared__ float red[4][128];
    int tile = blockIdx.x * 64;
    int t = threadIdx.x, lane = t & 63, w = t >> 6;
    int lr = lane & 15, kb = lane >> 4;
    int g0 = batch[tile];
    bool uni = (tile + 63 < N) && (g0 == batch[tile + 63]);
    int gr[4]; bool val[4];
    if (!uni) {
        #pragma unroll
        for (int r = 0; r < 4; ++r) {
            int row = tile + w * 16 + kb * 4 + r;
            val[r] = row < N;
            gr[r] = batch[min(row, N - 1)];
        }
    }
    int cr = min(tile + w * 16 + lr, N - 1);
    f16x8 afr[4];
    #pragma unroll
    for (int kc = 0; kc < 4; ++kc)
        afr[kc] = *(const f16x8*)(zh + (size_t)cr * HID + kc * 32 + kb * 8);
    float ps[8];
    #pragma unroll
    for (int ct = 0; ct < 8; ++ct) ps[ct] = 0.f;
    #pragma unroll
    for (int ct = 0; ct < 8; ++ct) {
        f32x4 c4 = {0.f, 0.f, 0.f, 0.f};
        int col = ct * 16 + lr;
        const f16* wp = Wt + (size_t)col * HID + kb * 8;
        #pragma unroll
        for (int kc = 0; kc < 4; ++kc) {
            f16x8 bf = *(const f16x8*)(wp + kc * 32);
            c4 = __builtin_amdgcn_mfma_f32_16x16x32_f16(afr[kc], bf, c4, 0, 0, 0);
        }
        float bj = b[col];
        if (uni) {
            #pragma unroll
            for (int r = 0; r < 4; ++r) ps[ct] += fmaxf(c4[r] + bj, 0.f);
        } else {
            #pragma unroll
            for (int r = 0; r < 4; ++r)
                if (val[r]) atomicAdd(&psum[gr[r] * HID + col], fmaxf(c4[r] + bj, 0.f));
        }
    }
    if (uni) {
        #pragma unroll
        for (int ct = 0; ct < 8; ++ct) {
            ps[ct] += __shfl_xor(ps[ct], 16);
            ps[ct] += __shfl_xor(ps[ct], 32);
        }
        if (kb == 0) {
            #pragma unroll
            for (int ct = 0; ct < 8; ++ct) red[w][ct * 16 + lr] = ps[ct];
        }
        __syncthreads();
        if (t < 128) {
            float s = red[0][t] + red[1][t] + red[2][t] + red[3][t];
            atomicAdd(&psum[g0 * HID + t], s);
        }
    }
}

// ---------------- mm tail: x2 -> h -> out (reads zh), wave-local fence ----------------

__global__ __launch_bounds__(256) void k_mm_tail_mfma(
        const f16* __restrict__ zh, const f16* __restrict__ Wm2t,
        const float* __restrict__ bm2, const int* __restrict__ batch,
        const float* __restrict__ ctxW, const f16* __restrict__ W1at,
        const float* __restrict__ W2, const float* __restrict__ b2,
        float* __restrict__ out, int N) {
    __shared__ f16 x2s[64][136];
    int tile = blockIdx.x * 64;
    int t = threadIdx.x, lane = t & 63, w = t >> 6;
    int lr = lane & 15, kb = lane >> 4;
    // phase 1: x2 = relu(zh @ Wm2 + bm2) -> LDS f16 (wave-local rows)
    {
        int cr = min(tile + w * 16 + lr, N - 1);
        f16x8 afr[4];
        #pragma unroll
        for (int kc = 0; kc < 4; ++kc)
            afr[kc] = *(const f16x8*)(zh + (size_t)cr * HID + kc * 32 + kb * 8);
        #pragma unroll
        for (int ct = 0; ct < 8; ++ct) {
            f32x4 c4 = {0.f, 0.f, 0.f, 0.f};
            int col = ct * 16 + lr;
            const f16* wp = Wm2t + (size_t)col * HID + kb * 8;
            #pragma unroll
            for (int kc = 0; kc < 4; ++kc) {
                f16x8 bf = *(const f16x8*)(wp + kc * 32);
                c4 = __builtin_amdgcn_mfma_f32_16x16x32_f16(afr[kc], bf, c4, 0, 0, 0);
            }
            float bj = bm2[col];
            #pragma unroll
            for (int r = 0; r < 4; ++r)
                x2s[w * 16 + kb * 4 + r][col] = (f16)fmaxf(c4[r] + bj, 0.f);
        }
    }
    // wave-local LDS fence (phase 1 writes -> phase 2 reads are same-wave rows)
    asm volatile("s_waitcnt lgkmcnt(0)" ::: "memory");
    __builtin_amdgcn_sched_barrier(0);
    // phase 2+3: h = relu(x2 @ W1a + ctxW[batch]); out partials in registers
    {
        f16x8 afr[4];
        #pragma unroll
        for (int kc = 0; kc < 4; ++kc)
            afr[kc] = *(const f16x8*)&x2s[w * 16 + lr][kc * 32 + kb * 8];
        int gidx[4];
        #pragma unroll
        for (int r = 0; r < 4; ++r)
            gidx[r] = batch[min(tile + w * 16 + kb * 4 + r, N - 1)];
        float po[4][3] = {};
        #pragma unroll
        for (int ct = 0; ct < 8; ++ct) {
            f32x4 c4 = {0.f, 0.f, 0.f, 0.f};
            int col = ct * 16 + lr;
            const f16* wp = W1at + (size_t)col * HID + kb * 8;
            #pragma unroll
            for (int kc = 0; kc < 4; ++kc) {
                f16x8 bf = *(const f16x8*)(wp + kc * 32);
                c4 = __builtin_amdgcn_mfma_f32_16x16x32_f16(afr[kc], bf, c4, 0, 0, 0);
            }
            float w0 = W2[col * 3 + 0], w1 = W2[col * 3 + 1], w2 = W2[col * 3 + 2];
            #pragma unroll
            for (int r = 0; r < 4; ++r) {
                float h = fmaxf(c4[r] + ctxW[gidx[r] * HID + col], 0.f);
                po[r][0] += h * w0;
                po[r][1] += h * w1;
                po[r][2] += h * w2;
            }
        }
        #pragma unroll
        for (int m = 1; m < 16; m <<= 1) {
            #pragma unroll
            for (int r = 0; r < 4; ++r) {
                po[r][0] += __shfl_xor(po[r][0], m);
                po[r][1] += __shfl_xor(po[r][1], m);
                po[r][2] += __shfl_xor(po[r][2], m);
            }
        }
        if (lr == 0) {
            #pragma unroll
            for (int r = 0; r < 4; ++r) {
                int row = tile + w * 16 + kb * 4 + r;
                if (row < N) {
                    out[(size_t)row * 3 + 0] = po[r][0] + b2[0];
                    out[(size_t)row * 3 + 1] = po[r][1] + b2[1];
                    out[(size_t)row * 3 + 2] = po[r][2] + b2[2];
                }
            }
        }
    }
}

// ---------------- launch ----------------

extern "C" void kernel_launch(void* const* d_in, const int* in_sizes, int n_in,
                              void* d_out, int out_size, void* d_ws, size_t ws_size,
                              hipStream_t stream) {
    const int*   residue_p = (const int*)d_in[0];
    const float* pos_p     = (const float*)d_in[1];
    const int*   ei_p      = (const int*)d_in[2];
    const int*   batch_p   = (const int*)d_in[3];
    const int*   residue_m = (const int*)d_in[4];
    const float* pos_m     = (const float*)d_in[5];
    const int*   ei_m      = (const int*)d_in[6];
    const int*   batch_m   = (const int*)d_in[7];
    const float* W_p1 = (const float*)d_in[8];
    const float* b_p1 = (const float*)d_in[9];
    const float* W_p2 = (const float*)d_in[10];
    const float* b_p2 = (const float*)d_in[11];
    const float* W_m1 = (const float*)d_in[12];
    const float* b_m1 = (const float*)d_in[13];
    const float* W_m2 = (const float*)d_in[14];
    const float* b_m2 = (const float*)d_in[15];
    const float* W1   = (const float*)d_in[16];
    const float* b1   = (const float*)d_in[17];
    const float* W2   = (const float*)d_in[18];
    const float* b2   = (const float*)d_in[19];

    const int N_P = in_sizes[0];
    const int E_P = in_sizes[2] / 2;
    const int N_M = in_sizes[4];
    const int E_M = in_sizes[6] / 2;
    const int G = 64;

    char* ws = (char*)d_ws;
    size_t off = 0;
    auto alloc = [&](size_t bytes) {
        char* p = ws + off;
        off += (bytes + 511) & ~size_t(511);
        return p;
    };
    f16*           y1h     = (f16*)  alloc((size_t)N_P * HID * 2);   // y1 = dinv*x1 fp16
    f16*           zh      = (f16*)  alloc((size_t)N_P * HID * 2);   // z fp16
    f16x4*         rec8    = (f16x4*)alloc((size_t)N_P * 8);
    unsigned char* res8    = (unsigned char*)alloc((size_t)N_P);
    float*         dinvA   = (float*)alloc((size_t)N_P * 4);
    int*           rowptr  = (int*)  alloc((size_t)(N_P + 1) * 4);
    int*           bcount  = (int*)  alloc((NBMAX + 1) * 4);
    int*           boff    = (int*)  alloc((NBMAX + 1) * 4);
    int*           bcursor = (int*)  alloc((NBMAX + 1) * 4);
    unsigned int*  pairs   = (unsigned int*)alloc((size_t)E_P * 4);
    int*           csr_src = (int*)  alloc((size_t)E_P * 4);
    float*         psum    = (float*)alloc((size_t)G * HID * 4);
    int*           pcnt    = (int*)  alloc((size_t)G * 4);
    float*         ctxW    = (float*)alloc((size_t)G * HID * 4);
    f16*           Wp2t    = (f16*)  alloc(128 * 128 * 2);
    f16*           Wm2t    = (f16*)  alloc(128 * 128 * 2);
    f16*           W1at    = (f16*)  alloc(128 * 128 * 2);

    k_prep_w<<<64, 256, 0, stream>>>(W_p2, W_m2, W1, Wp2t, Wm2t, W1at, bcount);
    k_graph_sizes<<<32, 256, 0, stream>>>(batch_p, pcnt, psum, N_P);

    auto build_graph = [&](const int* residue, const float* pos, const int* ei,
                           const float* Wl1, const float* bl1, int N, int E) {
        const int* srcp = ei;
        const int* dstp = ei + E;
        int NB = (N + 63) / 64;
        k_hist_bucket<<<256, 256, 0, stream>>>(dstp, bcount, E, NB);
        k_bucket_scan<<<1, 256, 0, stream>>>(bcount, bcount, boff, bcursor, NB);
        k_tile_bin<<<(E + BIN_T - 1) / BIN_T, 256, 0, stream>>>(srcp, dstp, bcursor, pairs, E, NB);
        k_bucket_fill2<<<NB, 256, 0, stream>>>(pairs, boff, residue, pos, csr_src,
                                               rec8, res8, dinvA, rowptr, N);
        k_l1_fused<<<NB, 256, 0, stream>>>(pairs, boff, rec8, res8, Wl1, bl1, dinvA, y1h, N);
        k_agg_f16<<<(N + 3) / 4, 256, 0, stream>>>(y1h, rowptr, csr_src, dinvA, zh, N);
    };

    // ---- protein branch ----
    build_graph(residue_p, pos_p, ei_p, W_p1, b_p1, N_P, E_P);
    k_gemm_pool_mfma<<<(N_P + 63) / 64, 256, 0, stream>>>(zh, Wp2t, b_p2, batch_p, psum, N_P);
    k_ctxw_div<<<G, HID, 0, stream>>>(psum, pcnt, W1, b1, ctxW);

    // ---- micromolecule branch ----
    build_graph(residue_m, pos_m, ei_m, W_m1, b_m1, N_M, E_M);
    k_mm_tail_mfma<<<(N_M + 63) / 64, 256, 0, stream>>>(zh, Wm2t, b_m2, batch_m, ctxW,
                                                        W1at, W2, b2, (float*)d_out, N_M);
}

// Round 11
// 433.535 us; speedup vs baseline: 1.0658x; 1.0658x over previous
//
#include <hip/hip_runtime.h>
#include <hip/hip_bf16.h>
#include <hip/hip_fp16.h>

#define HID 128
#define BIN_T 8192
#define NBMAX 1664   // max 64-node buckets (N <= 106496)

typedef _Float16 f16;
typedef __attribute__((ext_vector_type(2))) _Float16 f16x2;
typedef __attribute__((ext_vector_type(4))) _Float16 f16x4;
typedef __attribute__((ext_vector_type(8))) _Float16 f16x8;
typedef __attribute__((ext_vector_type(4))) float f32x4;

// ---------------- prep: weight transpose tables, zero counters, graph sizes ----------------

__global__ void k_prep_all(const float* __restrict__ Wp2, const float* __restrict__ Wm2,
                           const float* __restrict__ W1,
                           f16* __restrict__ Wp2t, f16* __restrict__ Wm2t,
                           f16* __restrict__ W1at,
                           int* __restrict__ bc_p, int* __restrict__ bc_m,
                           const int* __restrict__ batch_p, int* __restrict__ pcnt,
                           float* __restrict__ psum, int N_P) {
    int idx = blockIdx.x * 256 + threadIdx.x;   // grid 64 -> 16384 threads
    if (idx < 16384) {
        int n = idx & 127, k = idx >> 7;
        Wp2t[n * 128 + k] = (f16)Wp2[k * 128 + n];
        Wm2t[n * 128 + k] = (f16)Wm2[k * 128 + n];
        W1at[n * 128 + k] = (f16)W1[k * 128 + n];
    }
    if (idx <= NBMAX) { bc_p[idx] = 0; bc_m[idx] = 0; }
    if (idx < 64 * HID) psum[idx] = 0.f;
    if (idx < 64) {
        int g = idx;
        int lo = 0, hi = N_P;
        while (lo < hi) { int mid = (lo + hi) >> 1; if (batch_p[mid] < g) lo = mid + 1; else hi = mid; }
        int a = lo;
        lo = 0; hi = N_P;
        while (lo < hi) { int mid = (lo + hi) >> 1; if (batch_p[mid] < g + 1) lo = mid + 1; else hi = mid; }
        pcnt[g] = lo - a;
    }
}

// ---------------- bucket histogram (both branches, branch-split grid) ----------------

#define HB_P 256
#define HB_M 128

__global__ void k_hist2(const int* __restrict__ dst_p, int E_p, int* __restrict__ bc_p, int NB_p,
                        const int* __restrict__ dst_m, int E_m, int* __restrict__ bc_m, int NB_m) {
    __shared__ int h[NBMAX];
    bool isP = blockIdx.x < HB_P;
    const int* dst = isP ? dst_p : dst_m;
    int E = isP ? E_p : E_m;
    int* bc = isP ? bc_p : bc_m;
    int NB = isP ? NB_p : NB_m;
    int nb = isP ? HB_P : HB_M;
    int bid = isP ? blockIdx.x : blockIdx.x - HB_P;
    for (int i = threadIdx.x; i < NB; i += 256) h[i] = 0;
    __syncthreads();
    for (long long i = (long long)bid * 256 + threadIdx.x; i < E; i += (long long)nb * 256)
        atomicAdd(&h[((unsigned)dst[i]) >> 6], 1);
    __syncthreads();
    for (int i = threadIdx.x; i < NB; i += 256)
        if (h[i]) atomicAdd(&bc[i], h[i]);
}

// ---------------- exclusive scan over buckets (2 blocks: protein, mm) ----------------

__global__ void k_bucket_scan2(const int* __restrict__ bc_p, int* __restrict__ boff_p,
                               int* __restrict__ bcur_p, int NB_p,
                               const int* __restrict__ bc_m, int* __restrict__ boff_m,
                               int* __restrict__ bcur_m, int NB_m) {
    __shared__ int tt[256];
    const int* bc = blockIdx.x ? bc_m : bc_p;
    int* boff = blockIdx.x ? boff_m : boff_p;
    int* bcur = blockIdx.x ? bcur_m : bcur_p;
    int NB = blockIdx.x ? NB_m : NB_p;
    int ts = threadIdx.x;
    int b0 = ts * 7;
    int loc[7]; int run = 0;
    #pragma unroll
    for (int k = 0; k < 7; ++k) {
        int b = b0 + k;
        int c = (b < NB) ? bc[b] : 0;
        loc[k] = run; run += c;
    }
    tt[ts] = run;
    __syncthreads();
    int val = run;
    for (int off = 1; off < 256; off <<= 1) {
        int add = (ts >= off) ? tt[ts - off] : 0;
        __syncthreads();
        tt[ts] += add;
        __syncthreads();
    }
    int ebase = tt[ts] - val;
    #pragma unroll
    for (int k = 0; k < 7; ++k) {
        int b = b0 + k;
        if (b < NB) { boff[b] = ebase + loc[k]; bcur[b] = ebase + loc[k]; }
    }
    if (ts == 255) boff[NB] = tt[255];
}

// ---------------- tile-sorted bucket binning (both branches) ----------------
// pairs[slot] = src | (dst&63)<<26, grouped by bucket (dst>>6).

__global__ void k_tile_bin2(const int* __restrict__ src_p, const int* __restrict__ dst_p,
                            int* __restrict__ bcur_p, unsigned int* __restrict__ pairs_p,
                            int E_p, int NB_p, int TP,
                            const int* __restrict__ src_m, const int* __restrict__ dst_m,
                            int* __restrict__ bcur_m, unsigned int* __restrict__ pairs_m,
                            int E_m, int NB_m) {
    __shared__ unsigned int dbuf[BIN_T];
    __shared__ unsigned short perm[BIN_T];
    __shared__ int hist[NBMAX];
    __shared__ int lbase[NBMAX];
    __shared__ int gbase[NBMAX];
    __shared__ int tt[256];
    bool isP = (int)blockIdx.x < TP;
    const int* src = isP ? src_p : src_m;
    const int* dst = isP ? dst_p : dst_m;
    int* bcursor = isP ? bcur_p : bcur_m;
    unsigned int* pairs = isP ? pairs_p : pairs_m;
    int E = isP ? E_p : E_m;
    int NB = isP ? NB_p : NB_m;
    int tilebase = (isP ? blockIdx.x : blockIdx.x - TP) * BIN_T;
    int t = threadIdx.x;
    int n = min(BIN_T, E - tilebase);
    for (int i = t; i < NB; i += 256) hist[i] = 0;
    __syncthreads();
    for (int i = t; i < n; i += 256) {
        unsigned int d = (unsigned int)dst[tilebase + i];
        dbuf[i] = d;
        atomicAdd(&hist[d >> 6], 1);
    }
    __syncthreads();
    {
        int b0 = t * 7, loc[7], run = 0;
        #pragma unroll
        for (int k = 0; k < 7; ++k) {
            int b = b0 + k;
            int c = (b < NB) ? hist[b] : 0;
            loc[k] = run; run += c;
        }
        tt[t] = run;
        __syncthreads();
        int val = run;
        for (int off = 1; off < 256; off <<= 1) {
            int add = (t >= off) ? tt[t - off] : 0;
            __syncthreads();
            tt[t] += add;
            __syncthreads();
        }
        int ebase = tt[t] - val;
        #pragma unroll
        for (int k = 0; k < 7; ++k) {
            int b = b0 + k;
            if (b < NB) lbase[b] = ebase + loc[k];
        }
    }
    __syncthreads();
    for (int i = t; i < NB; i += 256) {
        int c = hist[i];
        gbase[i] = (c > 0) ? atomicAdd(&bcursor[i], c) : 0;
    }
    __syncthreads();
    for (int i = t; i < NB; i += 256) hist[i] = lbase[i];
    __syncthreads();
    for (int i = t; i < n; i += 256) {
        int b = (int)(dbuf[i] >> 6);
        int p = atomicAdd(&hist[b], 1);
        perm[p] = (unsigned short)i;
    }
    __syncthreads();
    for (int p = t; p < n; p += 256) {
        int li = perm[p];
        unsigned int d = dbuf[li];
        int b = (int)(d >> 6);
        int addr = gbase[b] + (p - lbase[b]);
        pairs[addr] = (unsigned int)src[tilebase + li] | ((d & 63u) << 26);
    }
}

// ---------------- bucket fill (both branches): deg, dinv, rowptr, rec8, res8, csr ----------------

__global__ void k_bucket_fill3(
        const unsigned int* __restrict__ pairs_p, const int* __restrict__ boff_p,
        const int* __restrict__ residue_p, const float* __restrict__ pos_p,
        int* __restrict__ csr_p, f16x4* __restrict__ rec8_p, unsigned char* __restrict__ res8_p,
        float* __restrict__ dinv_p, int* __restrict__ rowptr_p, int N_p, int NB_p,
        const unsigned int* __restrict__ pairs_m, const int* __restrict__ boff_m,
        const int* __restrict__ residue_m, const float* __restrict__ pos_m,
        int* __restrict__ csr_m, f16x4* __restrict__ rec8_m, unsigned char* __restrict__ res8_m,
        float* __restrict__ dinv_m, int* __restrict__ rowptr_m, int N_m) {
    __shared__ int cnt[64];
    __shared__ int cur[64];
    bool isP = (int)blockIdx.x < NB_p;
    const unsigned int* pairs = isP ? pairs_p : pairs_m;
    const int* boff = isP ? boff_p : boff_m;
    const int* residue = isP ? residue_p : residue_m;
    const float* pos = isP ? pos_p : pos_m;
    int* csr_src = isP ? csr_p : csr_m;
    f16x4* rec8 = isP ? rec8_p : rec8_m;
    unsigned char* res8 = isP ? res8_p : res8_m;
    float* dinvA = isP ? dinv_p : dinv_m;
    int* rowptr = isP ? rowptr_p : rowptr_m;
    int N = isP ? N_p : N_m;
    int b = isP ? blockIdx.x : blockIdx.x - NB_p;
    int t = threadIdx.x, base = b * 64;
    if (t < 64) cnt[t] = 0;
    __syncthreads();
    int lo = boff[b], hi = boff[b + 1];
    for (int e = lo + t; e < hi; e += 256)
        atomicAdd(&cnt[pairs[e] >> 26], 1);
    __syncthreads();
    if (t < 64) {
        int off = 0;
        for (int k = 0; k < t; ++k) off += cnt[k];
        int node = base + t;
        if (node < N) {
            rowptr[node] = lo + off;
            if (node == N - 1) rowptr[N] = hi;
            float d = (float)cnt[t] + 1.0f;   // +1 self loop
            float di = 1.0f / sqrtf(d);
            dinvA[node] = di;
            float px = pos[node * 3 + 0], py = pos[node * 3 + 1], pz = pos[node * 3 + 2];
            f16x4 r;
            r[0] = (f16)di; r[1] = (f16)(di * px); r[2] = (f16)(di * py); r[3] = (f16)(di * pz);
            rec8[node] = r;
            res8[node] = (unsigned char)residue[node];
        }
        cur[t] = lo + off;
    }
    __syncthreads();
    for (int e = lo + t; e < hi; e += 256) {
        unsigned int pk = pairs[e];
        int slot = atomicAdd(&cur[pk >> 26], 1);
        csr_src[slot] = (int)(pk & 0x3FFFFFFu);
    }
}

// ---------------- fused layer-1 (both branches): bucket agg (24-dim) + GEMM + premult ----------------
// z0_i = dinv_i*(sum_s y0_s + y0_i), y0 = dinv*[onehot,pos]; y1 = dinv*relu(z0@W+b) f16

__global__ __launch_bounds__(256) void k_l1_fused2(
        const unsigned int* __restrict__ pairs_p, const int* __restrict__ boff_p,
        const f16x4* __restrict__ rec8_p, const unsigned char* __restrict__ res8_p,
        const float* __restrict__ W_p, const float* __restrict__ bias_p,
        const float* __restrict__ dinv_p, f16* __restrict__ y1_p, int N_p, int NB_p,
        const unsigned int* __restrict__ pairs_m, const int* __restrict__ boff_m,
        const f16x4* __restrict__ rec8_m, const unsigned char* __restrict__ res8_m,
        const float* __restrict__ W_m, const float* __restrict__ bias_m,
        const float* __restrict__ dinv_m, f16* __restrict__ y1_m, int N_m) {
    __shared__ float acc[64][25];
    __shared__ float Ws[23 * 128];
    __shared__ float sdv[64];
    bool isP = (int)blockIdx.x < NB_p;
    const unsigned int* pairs = isP ? pairs_p : pairs_m;
    const int* boff = isP ? boff_p : boff_m;
    const f16x4* rec8 = isP ? rec8_p : rec8_m;
    const unsigned char* res8 = isP ? res8_p : res8_m;
    const float* W = isP ? W_p : W_m;
    const float* bias = isP ? bias_p : bias_m;
    const float* dinvA = isP ? dinv_p : dinv_m;
    f16* y1h = isP ? y1_p : y1_m;
    int N = isP ? N_p : N_m;
    int b = isP ? blockIdx.x : blockIdx.x - NB_p;
    int t = threadIdx.x, base = b * 64;
    for (int q = t; q < 64 * 25; q += 256) ((float*)acc)[q] = 0.f;
    for (int q = t; q < 23 * 128; q += 256) Ws[q] = W[q];
    if (t < 64 && base + t < N) sdv[t] = dinvA[base + t];
    __syncthreads();
    int lo = boff[b], hi = boff[b + 1];
    for (int e = lo + t; e < hi; e += 256) {
        unsigned int pk = pairs[e];
        int s = (int)(pk & 0x3FFFFFFu), dl = (int)(pk >> 26);
        f16x4 r = rec8[s];
        int rs = res8[s];
        atomicAdd(&acc[dl][rs], (float)r[0]);
        atomicAdd(&acc[dl][20], (float)r[1]);
        atomicAdd(&acc[dl][21], (float)r[2]);
        atomicAdd(&acc[dl][22], (float)r[3]);
    }
    __syncthreads();
    if (t < 64) {
        int node = base + t;
        if (node < N) {
            f16x4 r = rec8[node];
            acc[t][res8[node]] += (float)r[0];
            acc[t][20] += (float)r[1];
            acc[t][21] += (float)r[2];
            acc[t][22] += (float)r[3];
            float di = sdv[t];
            #pragma unroll
            for (int k = 0; k < 23; ++k) acc[t][k] *= di;
        }
    }
    __syncthreads();
    int jj = (t & 63) * 2, slot = t >> 6;   // 4 slots x 16 rows
    float bj0 = bias[jj], bj1 = bias[jj + 1];
    for (int r = slot * 16; r < slot * 16 + 16; ++r) {
        int node = base + r;
        if (node >= N) break;
        float a0 = bj0, a1 = bj1;
        #pragma unroll
        for (int k = 0; k < 23; ++k) {
            float zv = acc[r][k];
            a0 += zv * Ws[k * 128 + jj];
            a1 += zv * Ws[k * 128 + jj + 1];
        }
        float dv = sdv[r];
        f16x2 o;
        o[0] = (f16)(fmaxf(a0, 0.f) * dv);
        o[1] = (f16)(fmaxf(a1, 0.f) * dv);
        *(f16x2*)&y1h[(size_t)node * HID + jj] = o;
    }
}

// ---------------- wave-per-node agg into LDS z-tile (f16), wave-local ----------------
// wave w aggregates rows tile+w*16+i (i=0..15): full-wave half2 gather, 4-edge unroll.

#define AGG_TO_LDS(zs)                                                          \
    {                                                                           \
        const __half2* y2 = (const __half2*)y1h;                                \
        for (int i = 0; i < 16; ++i) {                                          \
            int node = tile + w * 16 + i;                                       \
            int cn = min(node, N - 1);                                          \
            int s0 = rowptr[cn], s1 = rowptr[cn + 1];                           \
            float ax = 0.f, ay = 0.f;                                           \
            int e = s0;                                                         \
            for (; e + 4 <= s1; e += 4) {                                       \
                int sA = csr_src[e],     sB = csr_src[e + 1];                   \
                int sC = csr_src[e + 2], sD = csr_src[e + 3];                   \
                float2 vA = __half22float2(y2[(size_t)sA * 64 + lane]);         \
                float2 vB = __half22float2(y2[(size_t)sB * 64 + lane]);         \
                float2 vC = __half22float2(y2[(size_t)sC * 64 + lane]);         \
                float2 vD = __half22float2(y2[(size_t)sD * 64 + lane]);         \
                ax += vA.x + vB.x + vC.x + vD.x;                                \
                ay += vA.y + vB.y + vC.y + vD.y;                                \
            }                                                                   \
            for (; e < s1; ++e) {                                               \
                float2 v = __half22float2(y2[(size_t)csr_src[e] * 64 + lane]);  \
                ax += v.x; ay += v.y;                                           \
            }                                                                   \
            float di = dinvA[cn];                                               \
            float2 vs = __half22float2(y2[(size_t)cn * 64 + lane]);             \
            f16x2 o;                                                            \
            o[0] = (f16)((ax + vs.x) * di);                                     \
            o[1] = (f16)((ay + vs.y) * di);                                     \
            *(f16x2*)&zs[w * 16 + i][lane * 2] = o;                             \
        }                                                                       \
    }                                                                           \
    asm volatile("s_waitcnt lgkmcnt(0)" ::: "memory");                          \
    __builtin_amdgcn_sched_barrier(0);

// protein: agg(LDS) -> x2 = relu(z@Wp2+b) -> register pool -> psum
__global__ __launch_bounds__(256) void k_agg_gemm_pool(
        const f16* __restrict__ y1h, const int* __restrict__ rowptr,
        const int* __restrict__ csr_src, const float* __restrict__ dinvA,
        const f16* __restrict__ Wt, const float* __restrict__ b,
        const int* __restrict__ batch, float* __restrict__ psum, int N) {
    __shared__ f16 zs[64][136];
    __shared__ float red[4][128];
    int tile = blockIdx.x * 64;
    int t = threadIdx.x, lane = t & 63, w = t >> 6;
    AGG_TO_LDS(zs)
    int lr = lane & 15, kb = lane >> 4;
    int g0 = batch[tile];
    bool uni = (tile + 63 < N) && (g0 == batch[tile + 63]);
    int gr[4]; bool val[4];
    if (!uni) {
        #pragma unroll
        for (int r = 0; r < 4; ++r) {
            int row = tile + w * 16 + kb * 4 + r;
            val[r] = row < N;
            gr[r] = batch[min(row, N - 1)];
        }
    }
    f16x8 afr[4];
    #pragma unroll
    for (int kc = 0; kc < 4; ++kc)
        afr[kc] = *(const f16x8*)&zs[w * 16 + lr][kc * 32 + kb * 8];
    float ps[8];
    #pragma unroll
    for (int ct = 0; ct < 8; ++ct) ps[ct] = 0.f;
    #pragma unroll
    for (int ct = 0; ct < 8; ++ct) {
        f32x4 c4 = {0.f, 0.f, 0.f, 0.f};
        int col = ct * 16 + lr;
        const f16* wp = Wt + (size_t)col * HID + kb * 8;
        #pragma unroll
        for (int kc = 0; kc < 4; ++kc) {
            f16x8 bf = *(const f16x8*)(wp + kc * 32);
            c4 = __builtin_amdgcn_mfma_f32_16x16x32_f16(afr[kc], bf, c4, 0, 0, 0);
        }
        float bj = b[col];
        if (uni) {
            #pragma unroll
            for (int r = 0; r < 4; ++r) ps[ct] += fmaxf(c4[r] + bj, 0.f);
        } else {
            #pragma unroll
            for (int r = 0; r < 4; ++r)
                if (val[r]) atomicAdd(&psum[gr[r] * HID + col], fmaxf(c4[r] + bj, 0.f));
        }
    }
    if (uni) {
        #pragma unroll
        for (int ct = 0; ct < 8; ++ct) {
            ps[ct] += __shfl_xor(ps[ct], 16);
            ps[ct] += __shfl_xor(ps[ct], 32);
        }
        if (kb == 0) {
            #pragma unroll
            for (int ct = 0; ct < 8; ++ct) red[w][ct * 16 + lr] = ps[ct];
        }
        __syncthreads();
        if (t < 128) {
            float s = red[0][t] + red[1][t] + red[2][t] + red[3][t];
            atomicAdd(&psum[g0 * HID + t], s);
        }
    }
}

// ctxW[g] = (psum[g]/cnt[g]) @ W1[128:,:] + b1
__global__ void k_ctxw_div(const float* __restrict__ psum, const int* __restrict__ pcnt,
                           const float* __restrict__ W1, const float* __restrict__ b1,
                           float* __restrict__ ctxW) {
    __shared__ float pr[128];
    int g = blockIdx.x, j = threadIdx.x;
    pr[j] = psum[g * HID + j] / fmaxf((float)pcnt[g], 1.f);
    __syncthreads();
    float a = b1[j];
    #pragma unroll 4
    for (int k = 0; k < HID; ++k) a += pr[k] * W1[(HID + k) * HID + j];
    ctxW[g * HID + j] = a;
}

// mm: agg(LDS) -> x2 -> h -> out, wave-local throughout
__global__ __launch_bounds__(256) void k_agg_mm_tail(
        const f16* __restrict__ y1h, const int* __restrict__ rowptr,
        const int* __restrict__ csr_src, const float* __restrict__ dinvA,
        const f16* __restrict__ Wm2t, const float* __restrict__ bm2,
        const int* __restrict__ batch, const float* __restrict__ ctxW,
        const f16* __restrict__ W1at, const float* __restrict__ W2,
        const float* __restrict__ b2, float* __restrict__ out, int N) {
    __shared__ f16 zs[64][136];
    int tile = blockIdx.x * 64;
    int t = threadIdx.x, lane = t & 63, w = t >> 6;
    AGG_TO_LDS(zs)
    int lr = lane & 15, kb = lane >> 4;
    // phase 1: afr = z frags (regs), then x2 overwrites zs in place (wave-local rows)
    {
        f16x8 afr[4];
        #pragma unroll
        for (int kc = 0; kc < 4; ++kc)
            afr[kc] = *(const f16x8*)&zs[w * 16 + lr][kc * 32 + kb * 8];
        // ensure all z reads complete before x2 writes reuse the tile
        asm volatile("s_waitcnt lgkmcnt(0)" ::: "memory");
        __builtin_amdgcn_sched_barrier(0);
        #pragma unroll
        for (int ct = 0; ct < 8; ++ct) {
            f32x4 c4 = {0.f, 0.f, 0.f, 0.f};
            int col = ct * 16 + lr;
            const f16* wp = Wm2t + (size_t)col * HID + kb * 8;
            #pragma unroll
            for (int kc = 0; kc < 4; ++kc) {
                f16x8 bf = *(const f16x8*)(wp + kc * 32);
                c4 = __builtin_amdgcn_mfma_f32_16x16x32_f16(afr[kc], bf, c4, 0, 0, 0);
            }
            float bj = bm2[col];
            #pragma unroll
            for (int r = 0; r < 4; ++r)
                zs[w * 16 + kb * 4 + r][col] = (f16)fmaxf(c4[r] + bj, 0.f);
        }
    }
    asm volatile("s_waitcnt lgkmcnt(0)" ::: "memory");
    __builtin_amdgcn_sched_barrier(0);
    // phase 2+3: h = relu(x2 @ W1a + ctxW[batch]); out partials in registers
    {
        f16x8 afr[4];
        #pragma unroll
        for (int kc = 0; kc < 4; ++kc)
            afr[kc] = *(const f16x8*)&zs[w * 16 + lr][kc * 32 + kb * 8];
        int gidx[4];
        #pragma unroll
        for (int r = 0; r < 4; ++r)
            gidx[r] = batch[min(tile + w * 16 + kb * 4 + r, N - 1)];
        float po[4][3] = {};
        #pragma unroll
        for (int ct = 0; ct < 8; ++ct) {
            f32x4 c4 = {0.f, 0.f, 0.f, 0.f};
            int col = ct * 16 + lr;
            const f16* wp = W1at + (size_t)col * HID + kb * 8;
            #pragma unroll
            for (int kc = 0; kc < 4; ++kc) {
                f16x8 bf = *(const f16x8*)(wp + kc * 32);
                c4 = __builtin_amdgcn_mfma_f32_16x16x32_f16(afr[kc], bf, c4, 0, 0, 0);
            }
            float w0 = W2[col * 3 + 0], w1 = W2[col * 3 + 1], w2 = W2[col * 3 + 2];
            #pragma unroll
            for (int r = 0; r < 4; ++r) {
                float h = fmaxf(c4[r] + ctxW[gidx[r] * HID + col], 0.f);
                po[r][0] += h * w0;
                po[r][1] += h * w1;
                po[r][2] += h * w2;
            }
        }
        #pragma unroll
        for (int m = 1; m < 16; m <<= 1) {
            #pragma unroll
            for (int r = 0; r < 4; ++r) {
                po[r][0] += __shfl_xor(po[r][0], m);
                po[r][1] += __shfl_xor(po[r][1], m);
                po[r][2] += __shfl_xor(po[r][2], m);
            }
        }
        if (lr == 0) {
            #pragma unroll
            for (int r = 0; r < 4; ++r) {
                int row = tile + w * 16 + kb * 4 + r;
                if (row < N) {
                    out[(size_t)row * 3 + 0] = po[r][0] + b2[0];
                    out[(size_t)row * 3 + 1] = po[r][1] + b2[1];
                    out[(size_t)row * 3 + 2] = po[r][2] + b2[2];
                }
            }
        }
    }
}

// ---------------- launch ----------------

extern "C" void kernel_launch(void* const* d_in, const int* in_sizes, int n_in,
                              void* d_out, int out_size, void* d_ws, size_t ws_size,
                              hipStream_t stream) {
    const int*   residue_p = (const int*)d_in[0];
    const float* pos_p     = (const float*)d_in[1];
    const int*   ei_p      = (const int*)d_in[2];
    const int*   batch_p   = (const int*)d_in[3];
    const int*   residue_m = (const int*)d_in[4];
    const float* pos_m     = (const float*)d_in[5];
    const int*   ei_m      = (const int*)d_in[6];
    const int*   batch_m   = (const int*)d_in[7];
    const float* W_p1 = (const float*)d_in[8];
    const float* b_p1 = (const float*)d_in[9];
    const float* W_p2 = (const float*)d_in[10];
    const float* b_p2 = (const float*)d_in[11];
    const float* W_m1 = (const float*)d_in[12];
    const float* b_m1 = (const float*)d_in[13];
    const float* W_m2 = (const float*)d_in[14];
    const float* b_m2 = (const float*)d_in[15];
    const float* W1   = (const float*)d_in[16];
    const float* b1   = (const float*)d_in[17];
    const float* W2   = (const float*)d_in[18];
    const float* b2   = (const float*)d_in[19];

    const int N_P = in_sizes[0];
    const int E_P = in_sizes[2] / 2;
    const int N_M = in_sizes[4];
    const int E_M = in_sizes[6] / 2;
    const int G = 64;
    const int NB_P = (N_P + 63) / 64;
    const int NB_M = (N_M + 63) / 64;

    char* ws = (char*)d_ws;
    size_t off = 0;
    auto alloc = [&](size_t bytes) {
        char* p = ws + off;
        off += (bytes + 511) & ~size_t(511);
        return p;
    };
    f16*           y1_p   = (f16*)  alloc((size_t)N_P * HID * 2);
    f16*           y1_m   = (f16*)  alloc((size_t)N_M * HID * 2);
    f16x4*         rec8_p = (f16x4*)alloc((size_t)N_P * 8);
    f16x4*         rec8_m = (f16x4*)alloc((size_t)N_M * 8);
    unsigned char* res8_p = (unsigned char*)alloc((size_t)N_P);
    unsigned char* res8_m = (unsigned char*)alloc((size_t)N_M);
    float*         dinv_p = (float*)alloc((size_t)N_P * 4);
    float*         dinv_m = (float*)alloc((size_t)N_M * 4);
    int*           rp_p   = (int*)  alloc((size_t)(N_P + 1) * 4);
    int*           rp_m   = (int*)  alloc((size_t)(N_M + 1) * 4);
    int*           bc_p   = (int*)  alloc((NBMAX + 1) * 4);
    int*           bc_m   = (int*)  alloc((NBMAX + 1) * 4);
    int*           boff_p = (int*)  alloc((NBMAX + 1) * 4);
    int*           boff_m = (int*)  alloc((NBMAX + 1) * 4);
    int*           bcur_p = (int*)  alloc((NBMAX + 1) * 4);
    int*           bcur_m = (int*)  alloc((NBMAX + 1) * 4);
    unsigned int*  prs_p  = (unsigned int*)alloc((size_t)E_P * 4);
    unsigned int*  prs_m  = (unsigned int*)alloc((size_t)E_M * 4);
    int*           csr_p  = (int*)  alloc((size_t)E_P * 4);
    int*           csr_m  = (int*)  alloc((size_t)E_M * 4);
    float*         psum   = (float*)alloc((size_t)G * HID * 4);
    int*           pcnt   = (int*)  alloc((size_t)G * 4);
    float*         ctxW   = (float*)alloc((size_t)G * HID * 4);
    f16*           Wp2t   = (f16*)  alloc(128 * 128 * 2);
    f16*           Wm2t   = (f16*)  alloc(128 * 128 * 2);
    f16*           W1at   = (f16*)  alloc(128 * 128 * 2);

    const int TP = (E_P + BIN_T - 1) / BIN_T;
    const int TM = (E_M + BIN_T - 1) / BIN_T;

    // 1. prep (weights, counter zeroing, graph sizes)
    k_prep_all<<<64, 256, 0, stream>>>(W_p2, W_m2, W1, Wp2t, Wm2t, W1at,
                                       bc_p, bc_m, batch_p, pcnt, psum, N_P);
    // 2. histograms (both branches)
    k_hist2<<<HB_P + HB_M, 256, 0, stream>>>(ei_p + E_P, E_P, bc_p, NB_P,
                                             ei_m + E_M, E_M, bc_m, NB_M);
    // 3. scans
    k_bucket_scan2<<<2, 256, 0, stream>>>(bc_p, boff_p, bcur_p, NB_P,
                                          bc_m, boff_m, bcur_m, NB_M);
    // 4. binning
    k_tile_bin2<<<TP + TM, 256, 0, stream>>>(ei_p, ei_p + E_P, bcur_p, prs_p, E_P, NB_P, TP,
                                             ei_m, ei_m + E_M, bcur_m, prs_m, E_M, NB_M);
    // 5. bucket fill
    k_bucket_fill3<<<NB_P + NB_M, 256, 0, stream>>>(
        prs_p, boff_p, residue_p, pos_p, csr_p, rec8_p, res8_p, dinv_p, rp_p, N_P, NB_P,
        prs_m, boff_m, residue_m, pos_m, csr_m, rec8_m, res8_m, dinv_m, rp_m, N_M);
    // 6. layer 1 (both branches)
    k_l1_fused2<<<NB_P + NB_M, 256, 0, stream>>>(
        prs_p, boff_p, rec8_p, res8_p, W_p1, b_p1, dinv_p, y1_p, N_P, NB_P,
        prs_m, boff_m, rec8_m, res8_m, W_m1, b_m1, dinv_m, y1_m, N_M);
    // 7. protein: agg + gemm + pool
    k_agg_gemm_pool<<<NB_P, 256, 0, stream>>>(y1_p, rp_p, csr_p, dinv_p,
                                              Wp2t, b_p2, batch_p, psum, N_P);
    // 8. ctxW
    k_ctxw_div<<<G, HID, 0, stream>>>(psum, pcnt, W1, b1, ctxW);
    // 9. mm: agg + gemm + gemm + head
    k_agg_mm_tail<<<NB_M, 256, 0, stream>>>(y1_m, rp_m, csr_m, dinv_m,
                                            Wm2t, b_m2, batch_m, ctxW,
                                            W1at, W2, b2, (float*)d_out, N_M);
}

// Round 12
// 350.899 us; speedup vs baseline: 1.3168x; 1.2355x over previous
//
#include <hip/hip_runtime.h>
#include <hip/hip_bf16.h>
#include <hip/hip_fp16.h>

#define HID 128
#define BIN_T 8192
#define NBMAX 1664   // max 64-node buckets (N <= 106496)

typedef _Float16 f16;
typedef __attribute__((ext_vector_type(2))) _Float16 f16x2;
typedef __attribute__((ext_vector_type(4))) _Float16 f16x4;
typedef __attribute__((ext_vector_type(8))) _Float16 f16x8;
typedef __attribute__((ext_vector_type(4))) float f32x4;

// ---------------- prep: weight transpose tables, zero counters, graph sizes ----------------

__global__ void k_prep_all(const float* __restrict__ Wp2, const float* __restrict__ Wm2,
                           const float* __restrict__ W1,
                           f16* __restrict__ Wp2t, f16* __restrict__ Wm2t,
                           f16* __restrict__ W1at,
                           int* __restrict__ bc_p, int* __restrict__ bc_m,
                           const int* __restrict__ batch_p, int* __restrict__ pcnt,
                           float* __restrict__ psum, int N_P) {
    int idx = blockIdx.x * 256 + threadIdx.x;   // grid 64 -> 16384 threads
    if (idx < 16384) {
        int n = idx & 127, k = idx >> 7;
        Wp2t[n * 128 + k] = (f16)Wp2[k * 128 + n];
        Wm2t[n * 128 + k] = (f16)Wm2[k * 128 + n];
        W1at[n * 128 + k] = (f16)W1[k * 128 + n];
    }
    if (idx <= NBMAX) { bc_p[idx] = 0; bc_m[idx] = 0; }
    if (idx < 64 * HID) psum[idx] = 0.f;
    if (idx < 64) {
        int g = idx;
        int lo = 0, hi = N_P;
        while (lo < hi) { int mid = (lo + hi) >> 1; if (batch_p[mid] < g) lo = mid + 1; else hi = mid; }
        int a = lo;
        lo = 0; hi = N_P;
        while (lo < hi) { int mid = (lo + hi) >> 1; if (batch_p[mid] < g + 1) lo = mid + 1; else hi = mid; }
        pcnt[g] = lo - a;
    }
}

// ---------------- bucket histogram (both branches, branch-split grid) ----------------

#define HB_P 256
#define HB_M 128

__global__ void k_hist2(const int* __restrict__ dst_p, int E_p, int* __restrict__ bc_p, int NB_p,
                        const int* __restrict__ dst_m, int E_m, int* __restrict__ bc_m, int NB_m) {
    __shared__ int h[NBMAX];
    bool isP = blockIdx.x < HB_P;
    const int* dst = isP ? dst_p : dst_m;
    int E = isP ? E_p : E_m;
    int* bc = isP ? bc_p : bc_m;
    int NB = isP ? NB_p : NB_m;
    int nb = isP ? HB_P : HB_M;
    int bid = isP ? blockIdx.x : blockIdx.x - HB_P;
    for (int i = threadIdx.x; i < NB; i += 256) h[i] = 0;
    __syncthreads();
    for (long long i = (long long)bid * 256 + threadIdx.x; i < E; i += (long long)nb * 256)
        atomicAdd(&h[((unsigned)dst[i]) >> 6], 1);
    __syncthreads();
    for (int i = threadIdx.x; i < NB; i += 256)
        if (h[i]) atomicAdd(&bc[i], h[i]);
}

// ---------------- exclusive scan over buckets (2 blocks: protein, mm) ----------------

__global__ void k_bucket_scan2(const int* __restrict__ bc_p, int* __restrict__ boff_p,
                               int* __restrict__ bcur_p, int NB_p,
                               const int* __restrict__ bc_m, int* __restrict__ boff_m,
                               int* __restrict__ bcur_m, int NB_m) {
    __shared__ int tt[256];
    const int* bc = blockIdx.x ? bc_m : bc_p;
    int* boff = blockIdx.x ? boff_m : boff_p;
    int* bcur = blockIdx.x ? bcur_m : bcur_p;
    int NB = blockIdx.x ? NB_m : NB_p;
    int ts = threadIdx.x;
    int b0 = ts * 7;
    int loc[7]; int run = 0;
    #pragma unroll
    for (int k = 0; k < 7; ++k) {
        int b = b0 + k;
        int c = (b < NB) ? bc[b] : 0;
        loc[k] = run; run += c;
    }
    tt[ts] = run;
    __syncthreads();
    int val = run;
    for (int off = 1; off < 256; off <<= 1) {
        int add = (ts >= off) ? tt[ts - off] : 0;
        __syncthreads();
        tt[ts] += add;
        __syncthreads();
    }
    int ebase = tt[ts] - val;
    #pragma unroll
    for (int k = 0; k < 7; ++k) {
        int b = b0 + k;
        if (b < NB) { boff[b] = ebase + loc[k]; bcur[b] = ebase + loc[k]; }
    }
    if (ts == 255) boff[NB] = tt[255];
}

// ---------------- tile-sorted bucket binning (both branches) ----------------
// pairs[slot] = src | (dst&63)<<26, grouped by bucket (dst>>6).

__global__ void k_tile_bin2(const int* __restrict__ src_p, const int* __restrict__ dst_p,
                            int* __restrict__ bcur_p, unsigned int* __restrict__ pairs_p,
                            int E_p, int NB_p, int TP,
                            const int* __restrict__ src_m, const int* __restrict__ dst_m,
                            int* __restrict__ bcur_m, unsigned int* __restrict__ pairs_m,
                            int E_m, int NB_m) {
    __shared__ unsigned int dbuf[BIN_T];
    __shared__ unsigned short perm[BIN_T];
    __shared__ int hist[NBMAX];
    __shared__ int lbase[NBMAX];
    __shared__ int gbase[NBMAX];
    __shared__ int tt[256];
    bool isP = (int)blockIdx.x < TP;
    const int* src = isP ? src_p : src_m;
    const int* dst = isP ? dst_p : dst_m;
    int* bcursor = isP ? bcur_p : bcur_m;
    unsigned int* pairs = isP ? pairs_p : pairs_m;
    int E = isP ? E_p : E_m;
    int NB = isP ? NB_p : NB_m;
    int tilebase = (isP ? blockIdx.x : blockIdx.x - TP) * BIN_T;
    int t = threadIdx.x;
    int n = min(BIN_T, E - tilebase);
    for (int i = t; i < NB; i += 256) hist[i] = 0;
    __syncthreads();
    for (int i = t; i < n; i += 256) {
        unsigned int d = (unsigned int)dst[tilebase + i];
        dbuf[i] = d;
        atomicAdd(&hist[d >> 6], 1);
    }
    __syncthreads();
    {
        int b0 = t * 7, loc[7], run = 0;
        #pragma unroll
        for (int k = 0; k < 7; ++k) {
            int b = b0 + k;
            int c = (b < NB) ? hist[b] : 0;
            loc[k] = run; run += c;
        }
        tt[t] = run;
        __syncthreads();
        int val = run;
        for (int off = 1; off < 256; off <<= 1) {
            int add = (t >= off) ? tt[t - off] : 0;
            __syncthreads();
            tt[t] += add;
            __syncthreads();
        }
        int ebase = tt[t] - val;
        #pragma unroll
        for (int k = 0; k < 7; ++k) {
            int b = b0 + k;
            if (b < NB) lbase[b] = ebase + loc[k];
        }
    }
    __syncthreads();
    for (int i = t; i < NB; i += 256) {
        int c = hist[i];
        gbase[i] = (c > 0) ? atomicAdd(&bcursor[i], c) : 0;
    }
    __syncthreads();
    for (int i = t; i < NB; i += 256) hist[i] = lbase[i];
    __syncthreads();
    for (int i = t; i < n; i += 256) {
        int b = (int)(dbuf[i] >> 6);
        int p = atomicAdd(&hist[b], 1);
        perm[p] = (unsigned short)i;
    }
    __syncthreads();
    for (int p = t; p < n; p += 256) {
        int li = perm[p];
        unsigned int d = dbuf[li];
        int b = (int)(d >> 6);
        int addr = gbase[b] + (p - lbase[b]);
        pairs[addr] = (unsigned int)src[tilebase + li] | ((d & 63u) << 26);
    }
}

// ---------------- bucket fill (both branches): deg, dinv, rowptr, rec8, res8, csr ----------------

__global__ void k_bucket_fill3(
        const unsigned int* __restrict__ pairs_p, const int* __restrict__ boff_p,
        const int* __restrict__ residue_p, const float* __restrict__ pos_p,
        int* __restrict__ csr_p, f16x4* __restrict__ rec8_p, unsigned char* __restrict__ res8_p,
        float* __restrict__ dinv_p, int* __restrict__ rowptr_p, int N_p, int NB_p,
        const unsigned int* __restrict__ pairs_m, const int* __restrict__ boff_m,
        const int* __restrict__ residue_m, const float* __restrict__ pos_m,
        int* __restrict__ csr_m, f16x4* __restrict__ rec8_m, unsigned char* __restrict__ res8_m,
        float* __restrict__ dinv_m, int* __restrict__ rowptr_m, int N_m) {
    __shared__ int cnt[64];
    __shared__ int cur[64];
    bool isP = (int)blockIdx.x < NB_p;
    const unsigned int* pairs = isP ? pairs_p : pairs_m;
    const int* boff = isP ? boff_p : boff_m;
    const int* residue = isP ? residue_p : residue_m;
    const float* pos = isP ? pos_p : pos_m;
    int* csr_src = isP ? csr_p : csr_m;
    f16x4* rec8 = isP ? rec8_p : rec8_m;
    unsigned char* res8 = isP ? res8_p : res8_m;
    float* dinvA = isP ? dinv_p : dinv_m;
    int* rowptr = isP ? rowptr_p : rowptr_m;
    int N = isP ? N_p : N_m;
    int b = isP ? blockIdx.x : blockIdx.x - NB_p;
    int t = threadIdx.x, base = b * 64;
    if (t < 64) cnt[t] = 0;
    __syncthreads();
    int lo = boff[b], hi = boff[b + 1];
    for (int e = lo + t; e < hi; e += 256)
        atomicAdd(&cnt[pairs[e] >> 26], 1);
    __syncthreads();
    if (t < 64) {
        int off = 0;
        for (int k = 0; k < t; ++k) off += cnt[k];
        int node = base + t;
        if (node < N) {
            rowptr[node] = lo + off;
            if (node == N - 1) rowptr[N] = hi;
            float d = (float)cnt[t] + 1.0f;   // +1 self loop
            float di = 1.0f / sqrtf(d);
            dinvA[node] = di;
            float px = pos[node * 3 + 0], py = pos[node * 3 + 1], pz = pos[node * 3 + 2];
            f16x4 r;
            r[0] = (f16)di; r[1] = (f16)(di * px); r[2] = (f16)(di * py); r[3] = (f16)(di * pz);
            rec8[node] = r;
            res8[node] = (unsigned char)residue[node];
        }
        cur[t] = lo + off;
    }
    __syncthreads();
    for (int e = lo + t; e < hi; e += 256) {
        unsigned int pk = pairs[e];
        int slot = atomicAdd(&cur[pk >> 26], 1);
        csr_src[slot] = (int)(pk & 0x3FFFFFFu);
    }
}

// ---------------- fused layer-1 (both branches): bucket agg (24-dim) + GEMM + premult ----------------
// z0_i = dinv_i*(sum_s y0_s + y0_i), y0 = dinv*[onehot,pos]; y1 = dinv*relu(z0@W+b) f16

__global__ __launch_bounds__(256) void k_l1_fused2(
        const unsigned int* __restrict__ pairs_p, const int* __restrict__ boff_p,
        const f16x4* __restrict__ rec8_p, const unsigned char* __restrict__ res8_p,
        const float* __restrict__ W_p, const float* __restrict__ bias_p,
        const float* __restrict__ dinv_p, f16* __restrict__ y1_p, int N_p, int NB_p,
        const unsigned int* __restrict__ pairs_m, const int* __restrict__ boff_m,
        const f16x4* __restrict__ rec8_m, const unsigned char* __restrict__ res8_m,
        const float* __restrict__ W_m, const float* __restrict__ bias_m,
        const float* __restrict__ dinv_m, f16* __restrict__ y1_m, int N_m) {
    __shared__ float acc[64][25];
    __shared__ float Ws[23 * 128];
    __shared__ float sdv[64];
    bool isP = (int)blockIdx.x < NB_p;
    const unsigned int* pairs = isP ? pairs_p : pairs_m;
    const int* boff = isP ? boff_p : boff_m;
    const f16x4* rec8 = isP ? rec8_p : rec8_m;
    const unsigned char* res8 = isP ? res8_p : res8_m;
    const float* W = isP ? W_p : W_m;
    const float* bias = isP ? bias_p : bias_m;
    const float* dinvA = isP ? dinv_p : dinv_m;
    f16* y1h = isP ? y1_p : y1_m;
    int N = isP ? N_p : N_m;
    int b = isP ? blockIdx.x : blockIdx.x - NB_p;
    int t = threadIdx.x, base = b * 64;
    for (int q = t; q < 64 * 25; q += 256) ((float*)acc)[q] = 0.f;
    for (int q = t; q < 23 * 128; q += 256) Ws[q] = W[q];
    if (t < 64 && base + t < N) sdv[t] = dinvA[base + t];
    __syncthreads();
    int lo = boff[b], hi = boff[b + 1];
    for (int e = lo + t; e < hi; e += 256) {
        unsigned int pk = pairs[e];
        int s = (int)(pk & 0x3FFFFFFu), dl = (int)(pk >> 26);
        f16x4 r = rec8[s];
        int rs = res8[s];
        atomicAdd(&acc[dl][rs], (float)r[0]);
        atomicAdd(&acc[dl][20], (float)r[1]);
        atomicAdd(&acc[dl][21], (float)r[2]);
        atomicAdd(&acc[dl][22], (float)r[3]);
    }
    __syncthreads();
    if (t < 64) {
        int node = base + t;
        if (node < N) {
            f16x4 r = rec8[node];
            acc[t][res8[node]] += (float)r[0];
            acc[t][20] += (float)r[1];
            acc[t][21] += (float)r[2];
            acc[t][22] += (float)r[3];
            float di = sdv[t];
            #pragma unroll
            for (int k = 0; k < 23; ++k) acc[t][k] *= di;
        }
    }
    __syncthreads();
    int jj = (t & 63) * 2, slot = t >> 6;   // 4 slots x 16 rows
    float bj0 = bias[jj], bj1 = bias[jj + 1];
    for (int r = slot * 16; r < slot * 16 + 16; ++r) {
        int node = base + r;
        if (node >= N) break;
        float a0 = bj0, a1 = bj1;
        #pragma unroll
        for (int k = 0; k < 23; ++k) {
            float zv = acc[r][k];
            a0 += zv * Ws[k * 128 + jj];
            a1 += zv * Ws[k * 128 + jj + 1];
        }
        float dv = sdv[r];
        f16x2 o;
        o[0] = (f16)(fmaxf(a0, 0.f) * dv);
        o[1] = (f16)(fmaxf(a1, 0.f) * dv);
        *(f16x2*)&y1h[(size_t)node * HID + jj] = o;
    }
}

// ---------------- wave-per-node agg into 16-row LDS z-tile (f16) ----------------
// wave w aggregates nodes tile+w*4+i (i=0..3): full-wave half2 gather, 4-edge unroll.

#define AGG16_TO_LDS(zs)                                                        \
    {                                                                           \
        const __half2* y2 = (const __half2*)y1h;                                \
        for (int i = 0; i < 4; ++i) {                                           \
            int node = tile + w * 4 + i;                                        \
            int cn = min(node, N - 1);                                          \
            int s0 = rowptr[cn], s1 = rowptr[cn + 1];                           \
            float ax = 0.f, ay = 0.f;                                           \
            int e = s0;                                                         \
            for (; e + 4 <= s1; e += 4) {                                       \
                int sA = csr_src[e],     sB = csr_src[e + 1];                   \
                int sC = csr_src[e + 2], sD = csr_src[e + 3];                   \
                float2 vA = __half22float2(y2[(size_t)sA * 64 + lane]);         \
                float2 vB = __half22float2(y2[(size_t)sB * 64 + lane]);         \
                float2 vC = __half22float2(y2[(size_t)sC * 64 + lane]);         \
                float2 vD = __half22float2(y2[(size_t)sD * 64 + lane]);         \
                ax += vA.x + vB.x + vC.x + vD.x;                                \
                ay += vA.y + vB.y + vC.y + vD.y;                                \
            }                                                                   \
            for (; e < s1; ++e) {                                               \
                float2 v = __half22float2(y2[(size_t)csr_src[e] * 64 + lane]);  \
                ax += v.x; ay += v.y;                                           \
            }                                                                   \
            float di = dinvA[cn];                                               \
            float2 vs = __half22float2(y2[(size_t)cn * 64 + lane]);             \
            f16x2 o;                                                            \
            o[0] = (f16)((ax + vs.x) * di);                                     \
            o[1] = (f16)((ay + vs.y) * di);                                     \
            *(f16x2*)&zs[w * 4 + i][lane * 2] = o;                              \
        }                                                                       \
    }                                                                           \
    __syncthreads();

// protein: agg(LDS,16 rows) -> x2 = relu(z@Wp2+b) -> per-wave col-pool -> psum
// wave w computes col-tiles ct = 2w, 2w+1 (disjoint cols -> no cross-wave reduce)
__global__ __launch_bounds__(256) void k_agg_gemm_pool(
        const f16* __restrict__ y1h, const int* __restrict__ rowptr,
        const int* __restrict__ csr_src, const float* __restrict__ dinvA,
        const f16* __restrict__ Wt, const float* __restrict__ b,
        const int* __restrict__ batch, float* __restrict__ psum, int N) {
    __shared__ f16 zs[16][136];
    int tile = blockIdx.x * 16;
    int t = threadIdx.x, lane = t & 63, w = t >> 6;
    AGG16_TO_LDS(zs)
    int lr = lane & 15, kb = lane >> 4;
    int g0 = batch[min(tile, N - 1)];
    bool uni = (tile + 15 < N) && (g0 == batch[tile + 15]);
    int gr[4]; bool val[4];
    if (!uni) {
        #pragma unroll
        for (int r = 0; r < 4; ++r) {
            int row = tile + kb * 4 + r;
            val[r] = row < N;
            gr[r] = batch[min(row, N - 1)];
        }
    }
    f16x8 afr[4];
    #pragma unroll
    for (int kc = 0; kc < 4; ++kc)
        afr[kc] = *(const f16x8*)&zs[lr][kc * 32 + kb * 8];
    #pragma unroll
    for (int q = 0; q < 2; ++q) {
        int ct = w * 2 + q;
        f32x4 c4 = {0.f, 0.f, 0.f, 0.f};
        int col = ct * 16 + lr;
        const f16* wp = Wt + (size_t)col * HID + kb * 8;
        #pragma unroll
        for (int kc = 0; kc < 4; ++kc) {
            f16x8 bf = *(const f16x8*)(wp + kc * 32);
            c4 = __builtin_amdgcn_mfma_f32_16x16x32_f16(afr[kc], bf, c4, 0, 0, 0);
        }
        float bj = b[col];
        if (uni) {
            float ps = 0.f;
            #pragma unroll
            for (int r = 0; r < 4; ++r) ps += fmaxf(c4[r] + bj, 0.f);
            ps += __shfl_xor(ps, 16);
            ps += __shfl_xor(ps, 32);
            if (kb == 0) atomicAdd(&psum[g0 * HID + col], ps);
        } else {
            #pragma unroll
            for (int r = 0; r < 4; ++r)
                if (val[r]) atomicAdd(&psum[gr[r] * HID + col], fmaxf(c4[r] + bj, 0.f));
        }
    }
}

// ctxW[g] = (psum[g]/cnt[g]) @ W1[128:,:] + b1
__global__ void k_ctxw_div(const float* __restrict__ psum, const int* __restrict__ pcnt,
                           const float* __restrict__ W1, const float* __restrict__ b1,
                           float* __restrict__ ctxW) {
    __shared__ float pr[128];
    int g = blockIdx.x, j = threadIdx.x;
    pr[j] = psum[g * HID + j] / fmaxf((float)pcnt[g], 1.f);
    __syncthreads();
    float a = b1[j];
    #pragma unroll 4
    for (int k = 0; k < HID; ++k) a += pr[k] * W1[(HID + k) * HID + j];
    ctxW[g * HID + j] = a;
}

// mm: agg(LDS,16 rows) -> x2 -> h -> out; wave w computes col-tiles 2w, 2w+1
__global__ __launch_bounds__(256) void k_agg_mm_tail(
        const f16* __restrict__ y1h, const int* __restrict__ rowptr,
        const int* __restrict__ csr_src, const float* __restrict__ dinvA,
        const f16* __restrict__ Wm2t, const float* __restrict__ bm2,
        const int* __restrict__ batch, const float* __restrict__ ctxW,
        const f16* __restrict__ W1at, const float* __restrict__ W2,
        const float* __restrict__ b2, float* __restrict__ out, int N) {
    __shared__ f16 zs[16][136];
    __shared__ f16 x2s[16][136];
    __shared__ float part[4][16][3];
    int tile = blockIdx.x * 16;
    int t = threadIdx.x, lane = t & 63, w = t >> 6;
    AGG16_TO_LDS(zs)
    int lr = lane & 15, kb = lane >> 4;
    // phase 1: x2 = relu(z @ Wm2 + bm2) -> x2s
    {
        f16x8 afr[4];
        #pragma unroll
        for (int kc = 0; kc < 4; ++kc)
            afr[kc] = *(const f16x8*)&zs[lr][kc * 32 + kb * 8];
        #pragma unroll
        for (int q = 0; q < 2; ++q) {
            int ct = w * 2 + q;
            f32x4 c4 = {0.f, 0.f, 0.f, 0.f};
            int col = ct * 16 + lr;
            const f16* wp = Wm2t + (size_t)col * HID + kb * 8;
            #pragma unroll
            for (int kc = 0; kc < 4; ++kc) {
                f16x8 bf = *(const f16x8*)(wp + kc * 32);
                c4 = __builtin_amdgcn_mfma_f32_16x16x32_f16(afr[kc], bf, c4, 0, 0, 0);
            }
            float bj = bm2[col];
            #pragma unroll
            for (int r = 0; r < 4; ++r)
                x2s[kb * 4 + r][col] = (f16)fmaxf(c4[r] + bj, 0.f);
        }
    }
    __syncthreads();
    // phase 2+3: h = relu(x2 @ W1a + ctxW[batch]); out partials per wave-cols
    {
        f16x8 afr[4];
        #pragma unroll
        for (int kc = 0; kc < 4; ++kc)
            afr[kc] = *(const f16x8*)&x2s[lr][kc * 32 + kb * 8];
        int gidx[4];
        #pragma unroll
        for (int r = 0; r < 4; ++r)
            gidx[r] = batch[min(tile + kb * 4 + r, N - 1)];
        float po[4][3] = {};
        #pragma unroll
        for (int q = 0; q < 2; ++q) {
            int ct = w * 2 + q;
            f32x4 c4 = {0.f, 0.f, 0.f, 0.f};
            int col = ct * 16 + lr;
            const f16* wp = W1at + (size_t)col * HID + kb * 8;
            #pragma unroll
            for (int kc = 0; kc < 4; ++kc) {
                f16x8 bf = *(const f16x8*)(wp + kc * 32);
                c4 = __builtin_amdgcn_mfma_f32_16x16x32_f16(afr[kc], bf, c4, 0, 0, 0);
            }
            float w0 = W2[col * 3 + 0], w1 = W2[col * 3 + 1], w2 = W2[col * 3 + 2];
            #pragma unroll
            for (int r = 0; r < 4; ++r) {
                float h = fmaxf(c4[r] + ctxW[gidx[r] * HID + col], 0.f);
                po[r][0] += h * w0;
                po[r][1] += h * w1;
                po[r][2] += h * w2;
            }
        }
        #pragma unroll
        for (int m = 1; m < 16; m <<= 1) {
            #pragma unroll
            for (int r = 0; r < 4; ++r) {
                po[r][0] += __shfl_xor(po[r][0], m);
                po[r][1] += __shfl_xor(po[r][1], m);
                po[r][2] += __shfl_xor(po[r][2], m);
            }
        }
        if (lr == 0) {
            #pragma unroll
            for (int r = 0; r < 4; ++r) {
                part[w][kb * 4 + r][0] = po[r][0];
                part[w][kb * 4 + r][1] = po[r][1];
                part[w][kb * 4 + r][2] = po[r][2];
            }
        }
    }
    __syncthreads();
    if (t < 48) {
        int row = t / 3, c = t - row * 3;
        int gr2 = tile + row;
        if (gr2 < N)
            out[(size_t)gr2 * 3 + c] = part[0][row][c] + part[1][row][c] +
                                       part[2][row][c] + part[3][row][c] + b2[c];
    }
}

// ---------------- launch ----------------

extern "C" void kernel_launch(void* const* d_in, const int* in_sizes, int n_in,
                              void* d_out, int out_size, void* d_ws, size_t ws_size,
                              hipStream_t stream) {
    const int*   residue_p = (const int*)d_in[0];
    const float* pos_p     = (const float*)d_in[1];
    const int*   ei_p      = (const int*)d_in[2];
    const int*   batch_p   = (const int*)d_in[3];
    const int*   residue_m = (const int*)d_in[4];
    const float* pos_m     = (const float*)d_in[5];
    const int*   ei_m      = (const int*)d_in[6];
    const int*   batch_m   = (const int*)d_in[7];
    const float* W_p1 = (const float*)d_in[8];
    const float* b_p1 = (const float*)d_in[9];
    const float* W_p2 = (const float*)d_in[10];
    const float* b_p2 = (const float*)d_in[11];
    const float* W_m1 = (const float*)d_in[12];
    const float* b_m1 = (const float*)d_in[13];
    const float* W_m2 = (const float*)d_in[14];
    const float* b_m2 = (const float*)d_in[15];
    const float* W1   = (const float*)d_in[16];
    const float* b1   = (const float*)d_in[17];
    const float* W2   = (const float*)d_in[18];
    const float* b2   = (const float*)d_in[19];

    const int N_P = in_sizes[0];
    const int E_P = in_sizes[2] / 2;
    const int N_M = in_sizes[4];
    const int E_M = in_sizes[6] / 2;
    const int G = 64;
    const int NB_P = (N_P + 63) / 64;
    const int NB_M = (N_M + 63) / 64;

    char* ws = (char*)d_ws;
    size_t off = 0;
    auto alloc = [&](size_t bytes) {
        char* p = ws + off;
        off += (bytes + 511) & ~size_t(511);
        return p;
    };
    f16*           y1_p   = (f16*)  alloc((size_t)N_P * HID * 2);
    f16*           y1_m   = (f16*)  alloc((size_t)N_M * HID * 2);
    f16x4*         rec8_p = (f16x4*)alloc((size_t)N_P * 8);
    f16x4*         rec8_m = (f16x4*)alloc((size_t)N_M * 8);
    unsigned char* res8_p = (unsigned char*)alloc((size_t)N_P);
    unsigned char* res8_m = (unsigned char*)alloc((size_t)N_M);
    float*         dinv_p = (float*)alloc((size_t)N_P * 4);
    float*         dinv_m = (float*)alloc((size_t)N_M * 4);
    int*           rp_p   = (int*)  alloc((size_t)(N_P + 1) * 4);
    int*           rp_m   = (int*)  alloc((size_t)(N_M + 1) * 4);
    int*           bc_p   = (int*)  alloc((NBMAX + 1) * 4);
    int*           bc_m   = (int*)  alloc((NBMAX + 1) * 4);
    int*           boff_p = (int*)  alloc((NBMAX + 1) * 4);
    int*           boff_m = (int*)  alloc((NBMAX + 1) * 4);
    int*           bcur_p = (int*)  alloc((NBMAX + 1) * 4);
    int*           bcur_m = (int*)  alloc((NBMAX + 1) * 4);
    unsigned int*  prs_p  = (unsigned int*)alloc((size_t)E_P * 4);
    unsigned int*  prs_m  = (unsigned int*)alloc((size_t)E_M * 4);
    int*           csr_p  = (int*)  alloc((size_t)E_P * 4);
    int*           csr_m  = (int*)  alloc((size_t)E_M * 4);
    float*         psum   = (float*)alloc((size_t)G * HID * 4);
    int*           pcnt   = (int*)  alloc((size_t)G * 4);
    float*         ctxW   = (float*)alloc((size_t)G * HID * 4);
    f16*           Wp2t   = (f16*)  alloc(128 * 128 * 2);
    f16*           Wm2t   = (f16*)  alloc(128 * 128 * 2);
    f16*           W1at   = (f16*)  alloc(128 * 128 * 2);

    const int TP = (E_P + BIN_T - 1) / BIN_T;
    const int TM = (E_M + BIN_T - 1) / BIN_T;

    // 1. prep (weights, counter zeroing, graph sizes)
    k_prep_all<<<64, 256, 0, stream>>>(W_p2, W_m2, W1, Wp2t, Wm2t, W1at,
                                       bc_p, bc_m, batch_p, pcnt, psum, N_P);
    // 2. histograms (both branches)
    k_hist2<<<HB_P + HB_M, 256, 0, stream>>>(ei_p + E_P, E_P, bc_p, NB_P,
                                             ei_m + E_M, E_M, bc_m, NB_M);
    // 3. scans
    k_bucket_scan2<<<2, 256, 0, stream>>>(bc_p, boff_p, bcur_p, NB_P,
                                          bc_m, boff_m, bcur_m, NB_M);
    // 4. binning
    k_tile_bin2<<<TP + TM, 256, 0, stream>>>(ei_p, ei_p + E_P, bcur_p, prs_p, E_P, NB_P, TP,
                                             ei_m, ei_m + E_M, bcur_m, prs_m, E_M, NB_M);
    // 5. bucket fill
    k_bucket_fill3<<<NB_P + NB_M, 256, 0, stream>>>(
        prs_p, boff_p, residue_p, pos_p, csr_p, rec8_p, res8_p, dinv_p, rp_p, N_P, NB_P,
        prs_m, boff_m, residue_m, pos_m, csr_m, rec8_m, res8_m, dinv_m, rp_m, N_M);
    // 6. layer 1 (both branches)
    k_l1_fused2<<<NB_P + NB_M, 256, 0, stream>>>(
        prs_p, boff_p, rec8_p, res8_p, W_p1, b_p1, dinv_p, y1_p, N_P, NB_P,
        prs_m, boff_m, rec8_m, res8_m, W_m1, b_m1, dinv_m, y1_m, N_M);
    // 7. protein: agg + gemm + pool (16-row tiles)
    k_agg_gemm_pool<<<(N_P + 15) / 16, 256, 0, stream>>>(y1_p, rp_p, csr_p, dinv_p,
                                                         Wp2t, b_p2, batch_p, psum, N_P);
    // 8. ctxW
    k_ctxw_div<<<G, HID, 0, stream>>>(psum, pcnt, W1, b1, ctxW);
    // 9. mm: agg + gemm + gemm + head (16-row tiles)
    k_agg_mm_tail<<<(N_M + 15) / 16, 256, 0, stream>>>(y1_m, rp_m, csr_m, dinv_m,
                                                       Wm2t, b_m2, batch_m, ctxW,
                                                       W1at, W2, b2, (float*)d_out, N_M);
}

// Round 13
// 333.344 us; speedup vs baseline: 1.3862x; 1.0527x over previous
//
#include <hip/hip_runtime.h>
#include <hip/hip_bf16.h>
#include <hip/hip_fp16.h>

#define HID 128
#define BIN_T 8192
#define NBMAX 1664   // max 64-node buckets (N <= 106496; src id fits 17 bits)

typedef _Float16 f16;
typedef __attribute__((ext_vector_type(2))) _Float16 f16x2;
typedef __attribute__((ext_vector_type(4))) _Float16 f16x4;
typedef __attribute__((ext_vector_type(8))) _Float16 f16x8;
typedef __attribute__((ext_vector_type(4))) float f32x4;

// pairs layout: src[16:0] | residue[21:17] | dl[31:26]

// ---------------- prep: weight transpose tables, zero counters, graph sizes ----------------

__global__ void k_prep_all(const float* __restrict__ Wp2, const float* __restrict__ Wm2,
                           const float* __restrict__ W1,
                           f16* __restrict__ Wp2t, f16* __restrict__ Wm2t,
                           f16* __restrict__ W1at,
                           int* __restrict__ bc_p, int* __restrict__ bc_m,
                           const int* __restrict__ batch_p, int* __restrict__ pcnt,
                           float* __restrict__ psum, int N_P) {
    int idx = blockIdx.x * 256 + threadIdx.x;   // grid 64 -> 16384 threads
    if (idx < 16384) {
        int n = idx & 127, k = idx >> 7;
        Wp2t[n * 128 + k] = (f16)Wp2[k * 128 + n];
        Wm2t[n * 128 + k] = (f16)Wm2[k * 128 + n];
        W1at[n * 128 + k] = (f16)W1[k * 128 + n];
    }
    if (idx <= NBMAX) { bc_p[idx] = 0; bc_m[idx] = 0; }
    if (idx < 64 * HID) psum[idx] = 0.f;
    if (idx < 64) {
        int g = idx;
        int lo = 0, hi = N_P;
        while (lo < hi) { int mid = (lo + hi) >> 1; if (batch_p[mid] < g) lo = mid + 1; else hi = mid; }
        int a = lo;
        lo = 0; hi = N_P;
        while (lo < hi) { int mid = (lo + hi) >> 1; if (batch_p[mid] < g + 1) lo = mid + 1; else hi = mid; }
        pcnt[g] = lo - a;
    }
}

// ---------------- bucket histogram (both branches, branch-split grid) ----------------

#define HB_P 256
#define HB_M 128

__global__ void k_hist2(const int* __restrict__ dst_p, int E_p, int* __restrict__ bc_p, int NB_p,
                        const int* __restrict__ dst_m, int E_m, int* __restrict__ bc_m, int NB_m) {
    __shared__ int h[NBMAX];
    bool isP = blockIdx.x < HB_P;
    const int* dst = isP ? dst_p : dst_m;
    int E = isP ? E_p : E_m;
    int* bc = isP ? bc_p : bc_m;
    int NB = isP ? NB_p : NB_m;
    int nb = isP ? HB_P : HB_M;
    int bid = isP ? blockIdx.x : blockIdx.x - HB_P;
    for (int i = threadIdx.x; i < NB; i += 256) h[i] = 0;
    __syncthreads();
    for (long long i = (long long)bid * 256 + threadIdx.x; i < E; i += (long long)nb * 256)
        atomicAdd(&h[((unsigned)dst[i]) >> 6], 1);
    __syncthreads();
    for (int i = threadIdx.x; i < NB; i += 256)
        if (h[i]) atomicAdd(&bc[i], h[i]);
}

// ---------------- exclusive scan over buckets (2 blocks: protein, mm) ----------------

__global__ void k_bucket_scan2(const int* __restrict__ bc_p, int* __restrict__ boff_p,
                               int* __restrict__ bcur_p, int NB_p,
                               const int* __restrict__ bc_m, int* __restrict__ boff_m,
                               int* __restrict__ bcur_m, int NB_m) {
    __shared__ int tt[256];
    const int* bc = blockIdx.x ? bc_m : bc_p;
    int* boff = blockIdx.x ? boff_m : boff_p;
    int* bcur = blockIdx.x ? bcur_m : bcur_p;
    int NB = blockIdx.x ? NB_m : NB_p;
    int ts = threadIdx.x;
    int b0 = ts * 7;
    int loc[7]; int run = 0;
    #pragma unroll
    for (int k = 0; k < 7; ++k) {
        int b = b0 + k;
        int c = (b < NB) ? bc[b] : 0;
        loc[k] = run; run += c;
    }
    tt[ts] = run;
    __syncthreads();
    int val = run;
    for (int off = 1; off < 256; off <<= 1) {
        int add = (ts >= off) ? tt[ts - off] : 0;
        __syncthreads();
        tt[ts] += add;
        __syncthreads();
    }
    int ebase = tt[ts] - val;
    #pragma unroll
    for (int k = 0; k < 7; ++k) {
        int b = b0 + k;
        if (b < NB) { boff[b] = ebase + loc[k]; bcur[b] = ebase + loc[k]; }
    }
    if (ts == 255) boff[NB] = tt[255];
}

// ---------------- tile-sorted bucket binning (both branches) ----------------

__global__ void k_tile_bin2(const int* __restrict__ src_p, const int* __restrict__ dst_p,
                            const int* __restrict__ res_p,
                            int* __restrict__ bcur_p, unsigned int* __restrict__ pairs_p,
                            int E_p, int NB_p, int TP,
                            const int* __restrict__ src_m, const int* __restrict__ dst_m,
                            const int* __restrict__ res_m,
                            int* __restrict__ bcur_m, unsigned int* __restrict__ pairs_m,
                            int E_m, int NB_m) {
    __shared__ unsigned int dbuf[BIN_T];
    __shared__ unsigned short perm[BIN_T];
    __shared__ int hist[NBMAX];
    __shared__ int lbase[NBMAX];
    __shared__ int gbase[NBMAX];
    __shared__ int tt[256];
    bool isP = (int)blockIdx.x < TP;
    const int* src = isP ? src_p : src_m;
    const int* dst = isP ? dst_p : dst_m;
    const int* res = isP ? res_p : res_m;
    int* bcursor = isP ? bcur_p : bcur_m;
    unsigned int* pairs = isP ? pairs_p : pairs_m;
    int E = isP ? E_p : E_m;
    int NB = isP ? NB_p : NB_m;
    int tilebase = (isP ? blockIdx.x : blockIdx.x - TP) * BIN_T;
    int t = threadIdx.x;
    int n = min(BIN_T, E - tilebase);
    for (int i = t; i < NB; i += 256) hist[i] = 0;
    __syncthreads();
    for (int i = t; i < n; i += 256) {
        unsigned int d = (unsigned int)dst[tilebase + i];
        dbuf[i] = d;
        atomicAdd(&hist[d >> 6], 1);
    }
    __syncthreads();
    {
        int b0 = t * 7, loc[7], run = 0;
        #pragma unroll
        for (int k = 0; k < 7; ++k) {
            int b = b0 + k;
            int c = (b < NB) ? hist[b] : 0;
            loc[k] = run; run += c;
        }
        tt[t] = run;
        __syncthreads();
        int val = run;
        for (int off = 1; off < 256; off <<= 1) {
            int add = (t >= off) ? tt[t - off] : 0;
            __syncthreads();
            tt[t] += add;
            __syncthreads();
        }
        int ebase = tt[t] - val;
        #pragma unroll
        for (int k = 0; k < 7; ++k) {
            int b = b0 + k;
            if (b < NB) lbase[b] = ebase + loc[k];
        }
    }
    __syncthreads();
    for (int i = t; i < NB; i += 256) {
        int c = hist[i];
        gbase[i] = (c > 0) ? atomicAdd(&bcursor[i], c) : 0;
    }
    __syncthreads();
    for (int i = t; i < NB; i += 256) hist[i] = lbase[i];
    __syncthreads();
    for (int i = t; i < n; i += 256) {
        int b = (int)(dbuf[i] >> 6);
        int p = atomicAdd(&hist[b], 1);
        perm[p] = (unsigned short)i;
    }
    __syncthreads();
    for (int p = t; p < n; p += 256) {
        int li = perm[p];
        unsigned int d = dbuf[li];
        int b = (int)(d >> 6);
        int addr = gbase[b] + (p - lbase[b]);
        int sv = src[tilebase + li];
        pairs[addr] = (unsigned int)sv | ((unsigned int)res[sv] << 17) | ((d & 63u) << 26);
    }
}

// ---------------- bucket fill (both branches): deg, dinv, rowptr, rec8, csr ----------------

__global__ void k_bucket_fill3(
        const unsigned int* __restrict__ pairs_p, const int* __restrict__ boff_p,
        const float* __restrict__ pos_p,
        int* __restrict__ csr_p, f16x4* __restrict__ rec8_p,
        float* __restrict__ dinv_p, int* __restrict__ rowptr_p, int N_p, int NB_p,
        const unsigned int* __restrict__ pairs_m, const int* __restrict__ boff_m,
        const float* __restrict__ pos_m,
        int* __restrict__ csr_m, f16x4* __restrict__ rec8_m,
        float* __restrict__ dinv_m, int* __restrict__ rowptr_m, int N_m) {
    __shared__ int cnt[64];
    __shared__ int cur[64];
    bool isP = (int)blockIdx.x < NB_p;
    const unsigned int* pairs = isP ? pairs_p : pairs_m;
    const int* boff = isP ? boff_p : boff_m;
    const float* pos = isP ? pos_p : pos_m;
    int* csr_src = isP ? csr_p : csr_m;
    f16x4* rec8 = isP ? rec8_p : rec8_m;
    float* dinvA = isP ? dinv_p : dinv_m;
    int* rowptr = isP ? rowptr_p : rowptr_m;
    int N = isP ? N_p : N_m;
    int b = isP ? blockIdx.x : blockIdx.x - NB_p;
    int t = threadIdx.x, base = b * 64;
    if (t < 64) cnt[t] = 0;
    __syncthreads();
    int lo = boff[b], hi = boff[b + 1];
    for (int e = lo + t; e < hi; e += 256)
        atomicAdd(&cnt[pairs[e] >> 26], 1);
    __syncthreads();
    if (t < 64) {
        int off = 0;
        for (int k = 0; k < t; ++k) off += cnt[k];
        int node = base + t;
        if (node < N) {
            rowptr[node] = lo + off;
            if (node == N - 1) rowptr[N] = hi;
            float d = (float)cnt[t] + 1.0f;   // +1 self loop
            float di = 1.0f / sqrtf(d);
            dinvA[node] = di;
            float px = pos[node * 3 + 0], py = pos[node * 3 + 1], pz = pos[node * 3 + 2];
            f16x4 r;
            r[0] = (f16)di; r[1] = (f16)(di * px); r[2] = (f16)(di * py); r[3] = (f16)(di * pz);
            rec8[node] = r;
        }
        cur[t] = lo + off;
    }
    __syncthreads();
    for (int e = lo + t; e < hi; e += 256) {
        unsigned int pk = pairs[e];
        int slot = atomicAdd(&cur[pk >> 26], 1);
        csr_src[slot] = (int)(pk & 0x1FFFFu);
    }
}

// ---------------- fused layer-1 (both branches): bucket agg (24-dim) + GEMM + premult ----------------
// z0_i = dinv_i*(sum_s y0_s + y0_i), y0 = dinv*[onehot,pos]; y1 = dinv*relu(z0@W+b) f16

__global__ __launch_bounds__(256) void k_l1_fused2(
        const unsigned int* __restrict__ pairs_p, const int* __restrict__ boff_p,
        const f16x4* __restrict__ rec8_p, const int* __restrict__ res_p,
        const float* __restrict__ W_p, const float* __restrict__ bias_p,
        const float* __restrict__ dinv_p, f16* __restrict__ y1_p, int N_p, int NB_p,
        const unsigned int* __restrict__ pairs_m, const int* __restrict__ boff_m,
        const f16x4* __restrict__ rec8_m, const int* __restrict__ res_m,
        const float* __restrict__ W_m, const float* __restrict__ bias_m,
        const float* __restrict__ dinv_m, f16* __restrict__ y1_m, int N_m) {
    __shared__ float acc[64][25];
    __shared__ float sdv[64];
    bool isP = (int)blockIdx.x < NB_p;
    const unsigned int* pairs = isP ? pairs_p : pairs_m;
    const int* boff = isP ? boff_p : boff_m;
    const f16x4* rec8 = isP ? rec8_p : rec8_m;
    const int* residue = isP ? res_p : res_m;
    const float* W = isP ? W_p : W_m;
    const float* bias = isP ? bias_p : bias_m;
    const float* dinvA = isP ? dinv_p : dinv_m;
    f16* y1h = isP ? y1_p : y1_m;
    int N = isP ? N_p : N_m;
    int b = isP ? blockIdx.x : blockIdx.x - NB_p;
    int t = threadIdx.x, base = b * 64;
    for (int q = t; q < 64 * 25; q += 256) ((float*)acc)[q] = 0.f;
    if (t < 64 && base + t < N) sdv[t] = dinvA[base + t];
    // per-thread W columns into registers (row-independent, coalesced)
    int jj = (t & 63) * 2, slot = t >> 6;
    float wreg[23][2];
    #pragma unroll
    for (int k = 0; k < 23; ++k) {
        float2 wv = *(const float2*)&W[k * 128 + jj];
        wreg[k][0] = wv.x; wreg[k][1] = wv.y;
    }
    __syncthreads();
    int lo = boff[b], hi = boff[b + 1];
    // 2-deep pipelined edge loop
    for (int e = lo + t; e < hi; e += 512) {
        unsigned int pk0 = pairs[e];
        int e1 = e + 256;
        bool h1 = e1 < hi;
        unsigned int pk1 = pairs[h1 ? e1 : e];
        int s0 = (int)(pk0 & 0x1FFFFu), s1 = (int)(pk1 & 0x1FFFFu);
        f16x4 r0 = rec8[s0];
        f16x4 r1 = rec8[s1];
        int dl0 = (int)(pk0 >> 26), rs0 = (int)((pk0 >> 17) & 31u);
        atomicAdd(&acc[dl0][rs0], (float)r0[0]);
        atomicAdd(&acc[dl0][20], (float)r0[1]);
        atomicAdd(&acc[dl0][21], (float)r0[2]);
        atomicAdd(&acc[dl0][22], (float)r0[3]);
        if (h1) {
            int dl1 = (int)(pk1 >> 26), rs1 = (int)((pk1 >> 17) & 31u);
            atomicAdd(&acc[dl1][rs1], (float)r1[0]);
            atomicAdd(&acc[dl1][20], (float)r1[1]);
            atomicAdd(&acc[dl1][21], (float)r1[2]);
            atomicAdd(&acc[dl1][22], (float)r1[3]);
        }
    }
    __syncthreads();
    if (t < 64) {
        int node = base + t;
        if (node < N) {
            f16x4 r = rec8[node];
            acc[t][residue[node]] += (float)r[0];
            acc[t][20] += (float)r[1];
            acc[t][21] += (float)r[2];
            acc[t][22] += (float)r[3];
            float di = sdv[t];
            #pragma unroll
            for (int k = 0; k < 23; ++k) acc[t][k] *= di;
        }
    }
    __syncthreads();
    float bj0 = bias[jj], bj1 = bias[jj + 1];
    for (int r = slot * 16; r < slot * 16 + 16; ++r) {
        int node = base + r;
        if (node >= N) break;
        float a0 = bj0, a1 = bj1;
        #pragma unroll
        for (int k = 0; k < 23; ++k) {
            float zv = acc[r][k];
            a0 += zv * wreg[k][0];
            a1 += zv * wreg[k][1];
        }
        float dv = sdv[r];
        f16x2 o;
        o[0] = (f16)(fmaxf(a0, 0.f) * dv);
        o[1] = (f16)(fmaxf(a1, 0.f) * dv);
        *(f16x2*)&y1h[(size_t)node * HID + jj] = o;
    }
}

// ---------------- wave-per-node agg into 16-row LDS z-tile (f16) ----------------

#define AGG16_TO_LDS(zs)                                                        \
    {                                                                           \
        const __half2* y2 = (const __half2*)y1h;                                \
        for (int i = 0; i < 4; ++i) {                                           \
            int node = tile + w * 4 + i;                                        \
            int cn = min(node, N - 1);                                          \
            int s0 = rowptr[cn], s1 = rowptr[cn + 1];                           \
            float ax = 0.f, ay = 0.f;                                           \
            int e = s0;                                                         \
            for (; e + 4 <= s1; e += 4) {                                       \
                int sA = csr_src[e],     sB = csr_src[e + 1];                   \
                int sC = csr_src[e + 2], sD = csr_src[e + 3];                   \
                float2 vA = __half22float2(y2[(size_t)sA * 64 + lane]);         \
                float2 vB = __half22float2(y2[(size_t)sB * 64 + lane]);         \
                float2 vC = __half22float2(y2[(size_t)sC * 64 + lane]);         \
                float2 vD = __half22float2(y2[(size_t)sD * 64 + lane]);         \
                ax += vA.x + vB.x + vC.x + vD.x;                                \
                ay += vA.y + vB.y + vC.y + vD.y;                                \
            }                                                                   \
            for (; e < s1; ++e) {                                               \
                float2 v = __half22float2(y2[(size_t)csr_src[e] * 64 + lane]);  \
                ax += v.x; ay += v.y;                                           \
            }                                                                   \
            float di = dinvA[cn];                                               \
            float2 vs = __half22float2(y2[(size_t)cn * 64 + lane]);             \
            f16x2 o;                                                            \
            o[0] = (f16)((ax + vs.x) * di);                                     \
            o[1] = (f16)((ay + vs.y) * di);                                     \
            *(f16x2*)&zs[w * 4 + i][lane * 2] = o;                              \
        }                                                                       \
    }                                                                           \
    __syncthreads();

// protein: agg(LDS,16 rows) -> x2 = relu(z@Wp2+b) -> per-wave col-pool -> psum
__global__ __launch_bounds__(256) void k_agg_gemm_pool(
        const f16* __restrict__ y1h, const int* __restrict__ rowptr,
        const int* __restrict__ csr_src, const float* __restrict__ dinvA,
        const f16* __restrict__ Wt, const float* __restrict__ b,
        const int* __restrict__ batch, float* __restrict__ psum, int N) {
    __shared__ f16 zs[16][136];
    int tile = blockIdx.x * 16;
    int t = threadIdx.x, lane = t & 63, w = t >> 6;
    AGG16_TO_LDS(zs)
    int lr = lane & 15, kb = lane >> 4;
    int g0 = batch[min(tile, N - 1)];
    bool uni = (tile + 15 < N) && (g0 == batch[tile + 15]);
    int gr[4]; bool val[4];
    if (!uni) {
        #pragma unroll
        for (int r = 0; r < 4; ++r) {
            int row = tile + kb * 4 + r;
            val[r] = row < N;
            gr[r] = batch[min(row, N - 1)];
        }
    }
    f16x8 afr[4];
    #pragma unroll
    for (int kc = 0; kc < 4; ++kc)
        afr[kc] = *(const f16x8*)&zs[lr][kc * 32 + kb * 8];
    #pragma unroll
    for (int q = 0; q < 2; ++q) {
        int ct = w * 2 + q;
        f32x4 c4 = {0.f, 0.f, 0.f, 0.f};
        int col = ct * 16 + lr;
        const f16* wp = Wt + (size_t)col * HID + kb * 8;
        #pragma unroll
        for (int kc = 0; kc < 4; ++kc) {
            f16x8 bf = *(const f16x8*)(wp + kc * 32);
            c4 = __builtin_amdgcn_mfma_f32_16x16x32_f16(afr[kc], bf, c4, 0, 0, 0);
        }
        float bj = b[col];
        if (uni) {
            float ps = 0.f;
            #pragma unroll
            for (int r = 0; r < 4; ++r) ps += fmaxf(c4[r] + bj, 0.f);
            ps += __shfl_xor(ps, 16);
            ps += __shfl_xor(ps, 32);
            if (kb == 0) atomicAdd(&psum[g0 * HID + col], ps);
        } else {
            #pragma unroll
            for (int r = 0; r < 4; ++r)
                if (val[r]) atomicAdd(&psum[gr[r] * HID + col], fmaxf(c4[r] + bj, 0.f));
        }
    }
}

// ctxW[g] = (psum[g]/cnt[g]) @ W1[128:,:] + b1
__global__ void k_ctxw_div(const float* __restrict__ psum, const int* __restrict__ pcnt,
                           const float* __restrict__ W1, const float* __restrict__ b1,
                           float* __restrict__ ctxW) {
    __shared__ float pr[128];
    int g = blockIdx.x, j = threadIdx.x;
    pr[j] = psum[g * HID + j] / fmaxf((float)pcnt[g], 1.f);
    __syncthreads();
    float a = b1[j];
    #pragma unroll 4
    for (int k = 0; k < HID; ++k) a += pr[k] * W1[(HID + k) * HID + j];
    ctxW[g * HID + j] = a;
}

// mm: agg(LDS,16 rows) -> x2 -> h -> out; wave w computes col-tiles 2w, 2w+1
__global__ __launch_bounds__(256) void k_agg_mm_tail(
        const f16* __restrict__ y1h, const int* __restrict__ rowptr,
        const int* __restrict__ csr_src, const float* __restrict__ dinvA,
        const f16* __restrict__ Wm2t, const float* __restrict__ bm2,
        const int* __restrict__ batch, const float* __restrict__ ctxW,
        const f16* __restrict__ W1at, const float* __restrict__ W2,
        const float* __restrict__ b2, float* __restrict__ out, int N) {
    __shared__ f16 zs[16][136];
    __shared__ f16 x2s[16][136];
    __shared__ float part[4][16][3];
    int tile = blockIdx.x * 16;
    int t = threadIdx.x, lane = t & 63, w = t >> 6;
    AGG16_TO_LDS(zs)
    int lr = lane & 15, kb = lane >> 4;
    // phase 1: x2 = relu(z @ Wm2 + bm2) -> x2s
    {
        f16x8 afr[4];
        #pragma unroll
        for (int kc = 0; kc < 4; ++kc)
            afr[kc] = *(const f16x8*)&zs[lr][kc * 32 + kb * 8];
        #pragma unroll
        for (int q = 0; q < 2; ++q) {
            int ct = w * 2 + q;
            f32x4 c4 = {0.f, 0.f, 0.f, 0.f};
            int col = ct * 16 + lr;
            const f16* wp = Wm2t + (size_t)col * HID + kb * 8;
            #pragma unroll
            for (int kc = 0; kc < 4; ++kc) {
                f16x8 bf = *(const f16x8*)(wp + kc * 32);
                c4 = __builtin_amdgcn_mfma_f32_16x16x32_f16(afr[kc], bf, c4, 0, 0, 0);
            }
            float bj = bm2[col];
            #pragma unroll
            for (int r = 0; r < 4; ++r)
                x2s[kb * 4 + r][col] = (f16)fmaxf(c4[r] + bj, 0.f);
        }
    }
    __syncthreads();
    // phase 2+3: h = relu(x2 @ W1a + ctxW[batch]); out partials per wave-cols
    {
        f16x8 afr[4];
        #pragma unroll
        for (int kc = 0; kc < 4; ++kc)
            afr[kc] = *(const f16x8*)&x2s[lr][kc * 32 + kb * 8];
        int gidx[4];
        #pragma unroll
        for (int r = 0; r < 4; ++r)
            gidx[r] = batch[min(tile + kb * 4 + r, N - 1)];
        float po[4][3] = {};
        #pragma unroll
        for (int q = 0; q < 2; ++q) {
            int ct = w * 2 + q;
            f32x4 c4 = {0.f, 0.f, 0.f, 0.f};
            int col = ct * 16 + lr;
            const f16* wp = W1at + (size_t)col * HID + kb * 8;
            #pragma unroll
            for (int kc = 0; kc < 4; ++kc) {
                f16x8 bf = *(const f16x8*)(wp + kc * 32);
                c4 = __builtin_amdgcn_mfma_f32_16x16x32_f16(afr[kc], bf, c4, 0, 0, 0);
            }
            float w0 = W2[col * 3 + 0], w1 = W2[col * 3 + 1], w2 = W2[col * 3 + 2];
            #pragma unroll
            for (int r = 0; r < 4; ++r) {
                float h = fmaxf(c4[r] + ctxW[gidx[r] * HID + col], 0.f);
                po[r][0] += h * w0;
                po[r][1] += h * w1;
                po[r][2] += h * w2;
            }
        }
        #pragma unroll
        for (int m = 1; m < 16; m <<= 1) {
            #pragma unroll
            for (int r = 0; r < 4; ++r) {
                po[r][0] += __shfl_xor(po[r][0], m);
                po[r][1] += __shfl_xor(po[r][1], m);
                po[r][2] += __shfl_xor(po[r][2], m);
            }
        }
        if (lr == 0) {
            #pragma unroll
            for (int r = 0; r < 4; ++r) {
                part[w][kb * 4 + r][0] = po[r][0];
                part[w][kb * 4 + r][1] = po[r][1];
                part[w][kb * 4 + r][2] = po[r][2];
            }
        }
    }
    __syncthreads();
    if (t < 48) {
        int row = t / 3, c = t - row * 3;
        int gr2 = tile + row;
        if (gr2 < N)
            out[(size_t)gr2 * 3 + c] = part[0][row][c] + part[1][row][c] +
                                       part[2][row][c] + part[3][row][c] + b2[c];
    }
}

// ---------------- launch ----------------

extern "C" void kernel_launch(void* const* d_in, const int* in_sizes, int n_in,
                              void* d_out, int out_size, void* d_ws, size_t ws_size,
                              hipStream_t stream) {
    const int*   residue_p = (const int*)d_in[0];
    const float* pos_p     = (const float*)d_in[1];
    const int*   ei_p      = (const int*)d_in[2];
    const int*   batch_p   = (const int*)d_in[3];
    const int*   residue_m = (const int*)d_in[4];
    const float* pos_m     = (const float*)d_in[5];
    const int*   ei_m      = (const int*)d_in[6];
    const int*   batch_m   = (const int*)d_in[7];
    const float* W_p1 = (const float*)d_in[8];
    const float* b_p1 = (const float*)d_in[9];
    const float* W_p2 = (const float*)d_in[10];
    const float* b_p2 = (const float*)d_in[11];
    const float* W_m1 = (const float*)d_in[12];
    const float* b_m1 = (const float*)d_in[13];
    const float* W_m2 = (const float*)d_in[14];
    const float* b_m2 = (const float*)d_in[15];
    const float* W1   = (const float*)d_in[16];
    const float* b1   = (const float*)d_in[17];
    const float* W2   = (const float*)d_in[18];
    const float* b2   = (const float*)d_in[19];

    const int N_P = in_sizes[0];
    const int E_P = in_sizes[2] / 2;
    const int N_M = in_sizes[4];
    const int E_M = in_sizes[6] / 2;
    const int G = 64;
    const int NB_P = (N_P + 63) / 64;
    const int NB_M = (N_M + 63) / 64;

    char* ws = (char*)d_ws;
    size_t off = 0;
    auto alloc = [&](size_t bytes) {
        char* p = ws + off;
        off += (bytes + 511) & ~size_t(511);
        return p;
    };
    f16*           y1_p   = (f16*)  alloc((size_t)N_P * HID * 2);
    f16*           y1_m   = (f16*)  alloc((size_t)N_M * HID * 2);
    f16x4*         rec8_p = (f16x4*)alloc((size_t)N_P * 8);
    f16x4*         rec8_m = (f16x4*)alloc((size_t)N_M * 8);
    float*         dinv_p = (float*)alloc((size_t)N_P * 4);
    float*         dinv_m = (float*)alloc((size_t)N_M * 4);
    int*           rp_p   = (int*)  alloc((size_t)(N_P + 1) * 4);
    int*           rp_m   = (int*)  alloc((size_t)(N_M + 1) * 4);
    int*           bc_p   = (int*)  alloc((NBMAX + 1) * 4);
    int*           bc_m   = (int*)  alloc((NBMAX + 1) * 4);
    int*           boff_p = (int*)  alloc((NBMAX + 1) * 4);
    int*           boff_m = (int*)  alloc((NBMAX + 1) * 4);
    int*           bcur_p = (int*)  alloc((NBMAX + 1) * 4);
    int*           bcur_m = (int*)  alloc((NBMAX + 1) * 4);
    unsigned int*  prs_p  = (unsigned int*)alloc((size_t)E_P * 4);
    unsigned int*  prs_m  = (unsigned int*)alloc((size_t)E_M * 4);
    int*           csr_p  = (int*)  alloc((size_t)E_P * 4);
    int*           csr_m  = (int*)  alloc((size_t)E_M * 4);
    float*         psum   = (float*)alloc((size_t)G * HID * 4);
    int*           pcnt   = (int*)  alloc((size_t)G * 4);
    float*         ctxW   = (float*)alloc((size_t)G * HID * 4);
    f16*           Wp2t   = (f16*)  alloc(128 * 128 * 2);
    f16*           Wm2t   = (f16*)  alloc(128 * 128 * 2);
    f16*           W1at   = (f16*)  alloc(128 * 128 * 2);

    const int TP = (E_P + BIN_T - 1) / BIN_T;
    const int TM = (E_M + BIN_T - 1) / BIN_T;

    // 1. prep (weights, counter zeroing, graph sizes)
    k_prep_all<<<64, 256, 0, stream>>>(W_p2, W_m2, W1, Wp2t, Wm2t, W1at,
                                       bc_p, bc_m, batch_p, pcnt, psum, N_P);
    // 2. histograms (both branches)
    k_hist2<<<HB_P + HB_M, 256, 0, stream>>>(ei_p + E_P, E_P, bc_p, NB_P,
                                             ei_m + E_M, E_M, bc_m, NB_M);
    // 3. scans
    k_bucket_scan2<<<2, 256, 0, stream>>>(bc_p, boff_p, bcur_p, NB_P,
                                          bc_m, boff_m, bcur_m, NB_M);
    // 4. binning (residue packed into pairs bits 17..21)
    k_tile_bin2<<<TP + TM, 256, 0, stream>>>(ei_p, ei_p + E_P, residue_p, bcur_p, prs_p,
                                             E_P, NB_P, TP,
                                             ei_m, ei_m + E_M, residue_m, bcur_m, prs_m,
                                             E_M, NB_M);
    // 5. bucket fill
    k_bucket_fill3<<<NB_P + NB_M, 256, 0, stream>>>(
        prs_p, boff_p, pos_p, csr_p, rec8_p, dinv_p, rp_p, N_P, NB_P,
        prs_m, boff_m, pos_m, csr_m, rec8_m, dinv_m, rp_m, N_M);
    // 6. layer 1 (both branches)
    k_l1_fused2<<<NB_P + NB_M, 256, 0, stream>>>(
        prs_p, boff_p, rec8_p, residue_p, W_p1, b_p1, dinv_p, y1_p, N_P, NB_P,
        prs_m, boff_m, rec8_m, residue_m, W_m1, b_m1, dinv_m, y1_m, N_M);
    // 7. protein: agg + gemm + pool (16-row tiles)
    k_agg_gemm_pool<<<(N_P + 15) / 16, 256, 0, stream>>>(y1_p, rp_p, csr_p, dinv_p,
                                                         Wp2t, b_p2, batch_p, psum, N_P);
    // 8. ctxW
    k_ctxw_div<<<G, HID, 0, stream>>>(psum, pcnt, W1, b1, ctxW);
    // 9. mm: agg + gemm + gemm + head (16-row tiles)
    k_agg_mm_tail<<<(N_M + 15) / 16, 256, 0, stream>>>(y1_m, rp_m, csr_m, dinv_m,
                                                       Wm2t, b_m2, batch_m, ctxW,
                                                       W1at, W2, b2, (float*)d_out, N_M);
}

// Round 14
// 310.986 us; speedup vs baseline: 1.4858x; 1.0719x over previous
//
#include <hip/hip_runtime.h>
#include <hip/hip_bf16.h>
#include <hip/hip_fp16.h>

#define HID 128
#define BIN_T 8192
#define NBMAX 1664   // max 64-node buckets (N <= 106496; src id fits 17 bits)
#define CAP 2560     // padded slots per bucket (mean ~1024, sigma ~32)

typedef _Float16 f16;
typedef __attribute__((ext_vector_type(2))) _Float16 f16x2;
typedef __attribute__((ext_vector_type(4))) _Float16 f16x4;
typedef __attribute__((ext_vector_type(8))) _Float16 f16x8;
typedef __attribute__((ext_vector_type(4))) float f32x4;

// pairs layout: src[16:0] | residue[21:17] | dl[31:26]
// pairs storage: bucket b occupies [b*CAP, bcur[b]) after binning.

// ---------------- prep: weight transpose tables, cursor init, graph sizes ----------------

__global__ void k_prep_all(const float* __restrict__ Wp2, const float* __restrict__ Wm2,
                           const float* __restrict__ W1,
                           f16* __restrict__ Wp2t, f16* __restrict__ Wm2t,
                           f16* __restrict__ W1at,
                           int* __restrict__ bcur_p, int* __restrict__ bcur_m,
                           const int* __restrict__ batch_p, int* __restrict__ pcnt,
                           float* __restrict__ psum, int N_P) {
    int idx = blockIdx.x * 256 + threadIdx.x;   // grid 64 -> 16384 threads
    if (idx < 16384) {
        int n = idx & 127, k = idx >> 7;
        Wp2t[n * 128 + k] = (f16)Wp2[k * 128 + n];
        Wm2t[n * 128 + k] = (f16)Wm2[k * 128 + n];
        W1at[n * 128 + k] = (f16)W1[k * 128 + n];
    }
    if (idx <= NBMAX) { bcur_p[idx] = idx * CAP; bcur_m[idx] = idx * CAP; }
    if (idx < 64 * HID) psum[idx] = 0.f;
    if (idx < 64) {
        int g = idx;
        int lo = 0, hi = N_P;
        while (lo < hi) { int mid = (lo + hi) >> 1; if (batch_p[mid] < g) lo = mid + 1; else hi = mid; }
        int a = lo;
        lo = 0; hi = N_P;
        while (lo < hi) { int mid = (lo + hi) >> 1; if (batch_p[mid] < g + 1) lo = mid + 1; else hi = mid; }
        pcnt[g] = lo - a;
    }
}

// ---------------- tile-sorted bucket binning (both branches, padded buckets) ----------------

__global__ void k_tile_bin2(const int* __restrict__ src_p, const int* __restrict__ dst_p,
                            const int* __restrict__ res_p,
                            int* __restrict__ bcur_p, unsigned int* __restrict__ pairs_p,
                            int E_p, int NB_p, int TP,
                            const int* __restrict__ src_m, const int* __restrict__ dst_m,
                            const int* __restrict__ res_m,
                            int* __restrict__ bcur_m, unsigned int* __restrict__ pairs_m,
                            int E_m, int NB_m) {
    __shared__ unsigned int dbuf[BIN_T];
    __shared__ unsigned short perm[BIN_T];
    __shared__ int hist[NBMAX];
    __shared__ int lbase[NBMAX];
    __shared__ int gbase[NBMAX];
    __shared__ int tt[256];
    bool isP = (int)blockIdx.x < TP;
    const int* src = isP ? src_p : src_m;
    const int* dst = isP ? dst_p : dst_m;
    const int* res = isP ? res_p : res_m;
    int* bcursor = isP ? bcur_p : bcur_m;
    unsigned int* pairs = isP ? pairs_p : pairs_m;
    int E = isP ? E_p : E_m;
    int NB = isP ? NB_p : NB_m;
    int tilebase = (isP ? blockIdx.x : blockIdx.x - TP) * BIN_T;
    int t = threadIdx.x;
    int n = min(BIN_T, E - tilebase);
    for (int i = t; i < NB; i += 256) hist[i] = 0;
    __syncthreads();
    for (int i = t; i < n; i += 256) {
        unsigned int d = (unsigned int)dst[tilebase + i];
        dbuf[i] = d;
        atomicAdd(&hist[d >> 6], 1);
    }
    __syncthreads();
    {
        int b0 = t * 7, loc[7], run = 0;
        #pragma unroll
        for (int k = 0; k < 7; ++k) {
            int b = b0 + k;
            int c = (b < NB) ? hist[b] : 0;
            loc[k] = run; run += c;
        }
        tt[t] = run;
        __syncthreads();
        int val = run;
        for (int off = 1; off < 256; off <<= 1) {
            int add = (t >= off) ? tt[t - off] : 0;
            __syncthreads();
            tt[t] += add;
            __syncthreads();
        }
        int ebase = tt[t] - val;
        #pragma unroll
        for (int k = 0; k < 7; ++k) {
            int b = b0 + k;
            if (b < NB) lbase[b] = ebase + loc[k];
        }
    }
    __syncthreads();
    for (int i = t; i < NB; i += 256) {
        int c = hist[i];
        gbase[i] = (c > 0) ? atomicAdd(&bcursor[i], c) : 0;
    }
    __syncthreads();
    for (int i = t; i < NB; i += 256) hist[i] = lbase[i];
    __syncthreads();
    for (int i = t; i < n; i += 256) {
        int b = (int)(dbuf[i] >> 6);
        int p = atomicAdd(&hist[b], 1);
        perm[p] = (unsigned short)i;
    }
    __syncthreads();
    for (int p = t; p < n; p += 256) {
        int li = perm[p];
        unsigned int d = dbuf[li];
        int b = (int)(d >> 6);
        int addr = gbase[b] + (p - lbase[b]);
        int sv = src[tilebase + li];
        pairs[addr] = (unsigned int)sv | ((unsigned int)res[sv] << 17) | ((d & 63u) << 26);
    }
}

// ---------------- fill A (both branches): counts -> rowptr/rowend, dinv, rec8 ----------------

__global__ void k_fill_a(
        const unsigned int* __restrict__ pairs_p, const int* __restrict__ bcur_p,
        const float* __restrict__ pos_p, f16x4* __restrict__ rec8_p,
        float* __restrict__ dinv_p, int* __restrict__ rowptr_p, int* __restrict__ rowend_p,
        int N_p, int NB_p,
        const unsigned int* __restrict__ pairs_m, const int* __restrict__ bcur_m,
        const float* __restrict__ pos_m, f16x4* __restrict__ rec8_m,
        float* __restrict__ dinv_m, int* __restrict__ rowptr_m, int* __restrict__ rowend_m,
        int N_m) {
    __shared__ int cnt[64];
    bool isP = (int)blockIdx.x < NB_p;
    const unsigned int* pairs = isP ? pairs_p : pairs_m;
    const int* bcur = isP ? bcur_p : bcur_m;
    const float* pos = isP ? pos_p : pos_m;
    f16x4* rec8 = isP ? rec8_p : rec8_m;
    float* dinvA = isP ? dinv_p : dinv_m;
    int* rowptr = isP ? rowptr_p : rowptr_m;
    int* rowend = isP ? rowend_p : rowend_m;
    int N = isP ? N_p : N_m;
    int b = isP ? blockIdx.x : blockIdx.x - NB_p;
    int t = threadIdx.x, base = b * 64;
    if (t < 64) cnt[t] = 0;
    __syncthreads();
    int lo = b * CAP, hi = bcur[b];
    for (int e = lo + t; e < hi; e += 256)
        atomicAdd(&cnt[pairs[e] >> 26], 1);
    __syncthreads();
    if (t < 64) {
        int off = 0;
        for (int k = 0; k < t; ++k) off += cnt[k];
        int node = base + t;
        if (node < N) {
            rowptr[node] = lo + off;
            rowend[node] = lo + off + cnt[t];
            float d = (float)cnt[t] + 1.0f;   // +1 self loop
            float di = 1.0f / sqrtf(d);
            dinvA[node] = di;
            float px = pos[node * 3 + 0], py = pos[node * 3 + 1], pz = pos[node * 3 + 2];
            f16x4 r;
            r[0] = (f16)di; r[1] = (f16)(di * px); r[2] = (f16)(di * py); r[3] = (f16)(di * pz);
            rec8[node] = r;
        }
    }
}

// ---------------- fused layer-1 + csr scatter (both branches) ----------------
// z0_i = dinv_i*(sum_s y0_s + y0_i), y0 = dinv*[onehot,pos]; y1 = dinv*relu(z0@W+b) f16
// same pairs pass also scatters csr_src (node-sorted source lists for layer-2 agg).

__global__ __launch_bounds__(256) void k_l1_csr(
        const unsigned int* __restrict__ pairs_p, const int* __restrict__ bcur_p,
        const f16x4* __restrict__ rec8_p, const int* __restrict__ res_p,
        const int* __restrict__ rowptr_p, int* __restrict__ csr_p,
        const float* __restrict__ W_p, const float* __restrict__ bias_p,
        const float* __restrict__ dinv_p, f16* __restrict__ y1_p, int N_p, int NB_p,
        const unsigned int* __restrict__ pairs_m, const int* __restrict__ bcur_m,
        const f16x4* __restrict__ rec8_m, const int* __restrict__ res_m,
        const int* __restrict__ rowptr_m, int* __restrict__ csr_m,
        const float* __restrict__ W_m, const float* __restrict__ bias_m,
        const float* __restrict__ dinv_m, f16* __restrict__ y1_m, int N_m) {
    __shared__ float acc[64][25];
    __shared__ float sdv[64];
    __shared__ int cur[64];
    bool isP = (int)blockIdx.x < NB_p;
    const unsigned int* pairs = isP ? pairs_p : pairs_m;
    const int* bcur = isP ? bcur_p : bcur_m;
    const f16x4* rec8 = isP ? rec8_p : rec8_m;
    const int* residue = isP ? res_p : res_m;
    const int* rowptr = isP ? rowptr_p : rowptr_m;
    int* csr_src = isP ? csr_p : csr_m;
    const float* W = isP ? W_p : W_m;
    const float* bias = isP ? bias_p : bias_m;
    const float* dinvA = isP ? dinv_p : dinv_m;
    f16* y1h = isP ? y1_p : y1_m;
    int N = isP ? N_p : N_m;
    int b = isP ? blockIdx.x : blockIdx.x - NB_p;
    int t = threadIdx.x, base = b * 64;
    for (int q = t; q < 64 * 25; q += 256) ((float*)acc)[q] = 0.f;
    if (t < 64) {
        int node = base + t;
        if (node < N) { sdv[t] = dinvA[node]; cur[t] = rowptr[node]; }
        else cur[t] = 0;
    }
    // per-thread W columns into registers (row-independent, coalesced)
    int jj = (t & 63) * 2, slot = t >> 6;
    float wreg[23][2];
    #pragma unroll
    for (int k = 0; k < 23; ++k) {
        float2 wv = *(const float2*)&W[k * 128 + jj];
        wreg[k][0] = wv.x; wreg[k][1] = wv.y;
    }
    __syncthreads();
    int lo = b * CAP, hi = bcur[b];
    // 2-deep pipelined edge loop: acc atomics + csr scatter
    for (int e = lo + t; e < hi; e += 512) {
        unsigned int pk0 = pairs[e];
        int e1 = e + 256;
        bool h1 = e1 < hi;
        unsigned int pk1 = pairs[h1 ? e1 : e];
        int s0 = (int)(pk0 & 0x1FFFFu), s1 = (int)(pk1 & 0x1FFFFu);
        f16x4 r0 = rec8[s0];
        f16x4 r1 = rec8[s1];
        int dl0 = (int)(pk0 >> 26), rs0 = (int)((pk0 >> 17) & 31u);
        int slot0 = atomicAdd(&cur[dl0], 1);
        csr_src[slot0] = s0;
        atomicAdd(&acc[dl0][rs0], (float)r0[0]);
        atomicAdd(&acc[dl0][20], (float)r0[1]);
        atomicAdd(&acc[dl0][21], (float)r0[2]);
        atomicAdd(&acc[dl0][22], (float)r0[3]);
        if (h1) {
            int dl1 = (int)(pk1 >> 26), rs1 = (int)((pk1 >> 17) & 31u);
            int slot1 = atomicAdd(&cur[dl1], 1);
            csr_src[slot1] = s1;
            atomicAdd(&acc[dl1][rs1], (float)r1[0]);
            atomicAdd(&acc[dl1][20], (float)r1[1]);
            atomicAdd(&acc[dl1][21], (float)r1[2]);
            atomicAdd(&acc[dl1][22], (float)r1[3]);
        }
    }
    __syncthreads();
    if (t < 64) {
        int node = base + t;
        if (node < N) {
            f16x4 r = rec8[node];
            acc[t][residue[node]] += (float)r[0];
            acc[t][20] += (float)r[1];
            acc[t][21] += (float)r[2];
            acc[t][22] += (float)r[3];
            float di = sdv[t];
            #pragma unroll
            for (int k = 0; k < 23; ++k) acc[t][k] *= di;
        }
    }
    __syncthreads();
    float bj0 = bias[jj], bj1 = bias[jj + 1];
    for (int r = slot * 16; r < slot * 16 + 16; ++r) {
        int node = base + r;
        if (node >= N) break;
        float a0 = bj0, a1 = bj1;
        #pragma unroll
        for (int k = 0; k < 23; ++k) {
            float zv = acc[r][k];
            a0 += zv * wreg[k][0];
            a1 += zv * wreg[k][1];
        }
        float dv = sdv[r];
        f16x2 o;
        o[0] = (f16)(fmaxf(a0, 0.f) * dv);
        o[1] = (f16)(fmaxf(a1, 0.f) * dv);
        *(f16x2*)&y1h[(size_t)node * HID + jj] = o;
    }
}

// ---------------- wave-per-node agg into 16-row LDS z-tile (f16) ----------------

#define AGG16_TO_LDS(zs)                                                        \
    {                                                                           \
        const __half2* y2 = (const __half2*)y1h;                                \
        for (int i = 0; i < 4; ++i) {                                           \
            int node = tile + w * 4 + i;                                        \
            int cn = min(node, N - 1);                                          \
            int s0 = rowptr[cn], s1 = rowend[cn];                               \
            float ax = 0.f, ay = 0.f;                                           \
            int e = s0;                                                         \
            for (; e + 4 <= s1; e += 4) {                                       \
                int sA = csr_src[e],     sB = csr_src[e + 1];                   \
                int sC = csr_src[e + 2], sD = csr_src[e + 3];                   \
                float2 vA = __half22float2(y2[(size_t)sA * 64 + lane]);         \
                float2 vB = __half22float2(y2[(size_t)sB * 64 + lane]);         \
                float2 vC = __half22float2(y2[(size_t)sC * 64 + lane]);         \
                float2 vD = __half22float2(y2[(size_t)sD * 64 + lane]);         \
                ax += vA.x + vB.x + vC.x + vD.x;                                \
                ay += vA.y + vB.y + vC.y + vD.y;                                \
            }                                                                   \
            for (; e < s1; ++e) {                                               \
                float2 v = __half22float2(y2[(size_t)csr_src[e] * 64 + lane]);  \
                ax += v.x; ay += v.y;                                           \
            }                                                                   \
            float di = dinvA[cn];                                               \
            float2 vs = __half22float2(y2[(size_t)cn * 64 + lane]);             \
            f16x2 o;                                                            \
            o[0] = (f16)((ax + vs.x) * di);                                     \
            o[1] = (f16)((ay + vs.y) * di);                                     \
            *(f16x2*)&zs[w * 4 + i][lane * 2] = o;                              \
        }                                                                       \
    }                                                                           \
    __syncthreads();

// protein: agg(LDS,16 rows) -> x2 = relu(z@Wp2+b) -> per-wave col-pool -> psum
__global__ __launch_bounds__(256) void k_agg_gemm_pool(
        const f16* __restrict__ y1h, const int* __restrict__ rowptr,
        const int* __restrict__ rowend, const int* __restrict__ csr_src,
        const float* __restrict__ dinvA,
        const f16* __restrict__ Wt, const float* __restrict__ b,
        const int* __restrict__ batch, float* __restrict__ psum, int N) {
    __shared__ f16 zs[16][136];
    int tile = blockIdx.x * 16;
    int t = threadIdx.x, lane = t & 63, w = t >> 6;
    AGG16_TO_LDS(zs)
    int lr = lane & 15, kb = lane >> 4;
    int g0 = batch[min(tile, N - 1)];
    bool uni = (tile + 15 < N) && (g0 == batch[tile + 15]);
    int gr[4]; bool val[4];
    if (!uni) {
        #pragma unroll
        for (int r = 0; r < 4; ++r) {
            int row = tile + kb * 4 + r;
            val[r] = row < N;
            gr[r] = batch[min(row, N - 1)];
        }
    }
    f16x8 afr[4];
    #pragma unroll
    for (int kc = 0; kc < 4; ++kc)
        afr[kc] = *(const f16x8*)&zs[lr][kc * 32 + kb * 8];
    #pragma unroll
    for (int q = 0; q < 2; ++q) {
        int ct = w * 2 + q;
        f32x4 c4 = {0.f, 0.f, 0.f, 0.f};
        int col = ct * 16 + lr;
        const f16* wp = Wt + (size_t)col * HID + kb * 8;
        #pragma unroll
        for (int kc = 0; kc < 4; ++kc) {
            f16x8 bf = *(const f16x8*)(wp + kc * 32);
            c4 = __builtin_amdgcn_mfma_f32_16x16x32_f16(afr[kc], bf, c4, 0, 0, 0);
        }
        float bj = b[col];
        if (uni) {
            float ps = 0.f;
            #pragma unroll
            for (int r = 0; r < 4; ++r) ps += fmaxf(c4[r] + bj, 0.f);
            ps += __shfl_xor(ps, 16);
            ps += __shfl_xor(ps, 32);
            if (kb == 0) atomicAdd(&psum[g0 * HID + col], ps);
        } else {
            #pragma unroll
            for (int r = 0; r < 4; ++r)
                if (val[r]) atomicAdd(&psum[gr[r] * HID + col], fmaxf(c4[r] + bj, 0.f));
        }
    }
}

// ctxW[g] = (psum[g]/cnt[g]) @ W1[128:,:] + b1
__global__ void k_ctxw_div(const float* __restrict__ psum, const int* __restrict__ pcnt,
                           const float* __restrict__ W1, const float* __restrict__ b1,
                           float* __restrict__ ctxW) {
    __shared__ float pr[128];
    int g = blockIdx.x, j = threadIdx.x;
    pr[j] = psum[g * HID + j] / fmaxf((float)pcnt[g], 1.f);
    __syncthreads();
    float a = b1[j];
    #pragma unroll 4
    for (int k = 0; k < HID; ++k) a += pr[k] * W1[(HID + k) * HID + j];
    ctxW[g * HID + j] = a;
}

// mm: agg(LDS,16 rows) -> x2 -> h -> out; wave w computes col-tiles 2w, 2w+1
__global__ __launch_bounds__(256) void k_agg_mm_tail(
        const f16* __restrict__ y1h, const int* __restrict__ rowptr,
        const int* __restrict__ rowend, const int* __restrict__ csr_src,
        const float* __restrict__ dinvA,
        const f16* __restrict__ Wm2t, const float* __restrict__ bm2,
        const int* __restrict__ batch, const float* __restrict__ ctxW,
        const f16* __restrict__ W1at, const float* __restrict__ W2,
        const float* __restrict__ b2, float* __restrict__ out, int N) {
    __shared__ f16 zs[16][136];
    __shared__ f16 x2s[16][136];
    __shared__ float part[4][16][3];
    int tile = blockIdx.x * 16;
    int t = threadIdx.x, lane = t & 63, w = t >> 6;
    AGG16_TO_LDS(zs)
    int lr = lane & 15, kb = lane >> 4;
    // phase 1: x2 = relu(z @ Wm2 + bm2) -> x2s
    {
        f16x8 afr[4];
        #pragma unroll
        for (int kc = 0; kc < 4; ++kc)
            afr[kc] = *(const f16x8*)&zs[lr][kc * 32 + kb * 8];
        #pragma unroll
        for (int q = 0; q < 2; ++q) {
            int ct = w * 2 + q;
            f32x4 c4 = {0.f, 0.f, 0.f, 0.f};
            int col = ct * 16 + lr;
            const f16* wp = Wm2t + (size_t)col * HID + kb * 8;
            #pragma unroll
            for (int kc = 0; kc < 4; ++kc) {
                f16x8 bf = *(const f16x8*)(wp + kc * 32);
                c4 = __builtin_amdgcn_mfma_f32_16x16x32_f16(afr[kc], bf, c4, 0, 0, 0);
            }
            float bj = bm2[col];
            #pragma unroll
            for (int r = 0; r < 4; ++r)
                x2s[kb * 4 + r][col] = (f16)fmaxf(c4[r] + bj, 0.f);
        }
    }
    __syncthreads();
    // phase 2+3: h = relu(x2 @ W1a + ctxW[batch]); out partials per wave-cols
    {
        f16x8 afr[4];
        #pragma unroll
        for (int kc = 0; kc < 4; ++kc)
            afr[kc] = *(const f16x8*)&x2s[lr][kc * 32 + kb * 8];
        int gidx[4];
        #pragma unroll
        for (int r = 0; r < 4; ++r)
            gidx[r] = batch[min(tile + kb * 4 + r, N - 1)];
        float po[4][3] = {};
        #pragma unroll
        for (int q = 0; q < 2; ++q) {
            int ct = w * 2 + q;
            f32x4 c4 = {0.f, 0.f, 0.f, 0.f};
            int col = ct * 16 + lr;
            const f16* wp = W1at + (size_t)col * HID + kb * 8;
            #pragma unroll
            for (int kc = 0; kc < 4; ++kc) {
                f16x8 bf = *(const f16x8*)(wp + kc * 32);
                c4 = __builtin_amdgcn_mfma_f32_16x16x32_f16(afr[kc], bf, c4, 0, 0, 0);
            }
            float w0 = W2[col * 3 + 0], w1 = W2[col * 3 + 1], w2 = W2[col * 3 + 2];
            #pragma unroll
            for (int r = 0; r < 4; ++r) {
                float h = fmaxf(c4[r] + ctxW[gidx[r] * HID + col], 0.f);
                po[r][0] += h * w0;
                po[r][1] += h * w1;
                po[r][2] += h * w2;
            }
        }
        #pragma unroll
        for (int m = 1; m < 16; m <<= 1) {
            #pragma unroll
            for (int r = 0; r < 4; ++r) {
                po[r][0] += __shfl_xor(po[r][0], m);
                po[r][1] += __shfl_xor(po[r][1], m);
                po[r][2] += __shfl_xor(po[r][2], m);
            }
        }
        if (lr == 0) {
            #pragma unroll
            for (int r = 0; r < 4; ++r) {
                part[w][kb * 4 + r][0] = po[r][0];
                part[w][kb * 4 + r][1] = po[r][1];
                part[w][kb * 4 + r][2] = po[r][2];
            }
        }
    }
    __syncthreads();
    if (t < 48) {
        int row = t / 3, c = t - row * 3;
        int gr2 = tile + row;
        if (gr2 < N)
            out[(size_t)gr2 * 3 + c] = part[0][row][c] + part[1][row][c] +
                                       part[2][row][c] + part[3][row][c] + b2[c];
    }
}

// ---------------- launch ----------------

extern "C" void kernel_launch(void* const* d_in, const int* in_sizes, int n_in,
                              void* d_out, int out_size, void* d_ws, size_t ws_size,
                              hipStream_t stream) {
    const int*   residue_p = (const int*)d_in[0];
    const float* pos_p     = (const float*)d_in[1];
    const int*   ei_p      = (const int*)d_in[2];
    const int*   batch_p   = (const int*)d_in[3];
    const int*   residue_m = (const int*)d_in[4];
    const float* pos_m     = (const float*)d_in[5];
    const int*   ei_m      = (const int*)d_in[6];
    const int*   batch_m   = (const int*)d_in[7];
    const float* W_p1 = (const float*)d_in[8];
    const float* b_p1 = (const float*)d_in[9];
    const float* W_p2 = (const float*)d_in[10];
    const float* b_p2 = (const float*)d_in[11];
    const float* W_m1 = (const float*)d_in[12];
    const float* b_m1 = (const float*)d_in[13];
    const float* W_m2 = (const float*)d_in[14];
    const float* b_m2 = (const float*)d_in[15];
    const float* W1   = (const float*)d_in[16];
    const float* b1   = (const float*)d_in[17];
    const float* W2   = (const float*)d_in[18];
    const float* b2   = (const float*)d_in[19];

    const int N_P = in_sizes[0];
    const int E_P = in_sizes[2] / 2;
    const int N_M = in_sizes[4];
    const int E_M = in_sizes[6] / 2;
    const int G = 64;
    const int NB_P = (N_P + 63) / 64;
    const int NB_M = (N_M + 63) / 64;

    char* ws = (char*)d_ws;
    size_t off = 0;
    auto alloc = [&](size_t bytes) {
        char* p = ws + off;
        off += (bytes + 511) & ~size_t(511);
        return p;
    };
    f16*           y1_p   = (f16*)  alloc((size_t)N_P * HID * 2);
    f16*           y1_m   = (f16*)  alloc((size_t)N_M * HID * 2);
    f16x4*         rec8_p = (f16x4*)alloc((size_t)N_P * 8);
    f16x4*         rec8_m = (f16x4*)alloc((size_t)N_M * 8);
    float*         dinv_p = (float*)alloc((size_t)N_P * 4);
    float*         dinv_m = (float*)alloc((size_t)N_M * 4);
    int*           rp_p   = (int*)  alloc((size_t)N_P * 4);
    int*           rp_m   = (int*)  alloc((size_t)N_M * 4);
    int*           re_p   = (int*)  alloc((size_t)N_P * 4);
    int*           re_m   = (int*)  alloc((size_t)N_M * 4);
    int*           bcur_p = (int*)  alloc((NBMAX + 1) * 4);
    int*           bcur_m = (int*)  alloc((NBMAX + 1) * 4);
    unsigned int*  prs_p  = (unsigned int*)alloc((size_t)NB_P * CAP * 4);
    unsigned int*  prs_m  = (unsigned int*)alloc((size_t)NB_M * CAP * 4);
    int*           csr_p  = (int*)  alloc((size_t)NB_P * CAP * 4);
    int*           csr_m  = (int*)  alloc((size_t)NB_M * CAP * 4);
    float*         psum   = (float*)alloc((size_t)G * HID * 4);
    int*           pcnt   = (int*)  alloc((size_t)G * 4);
    float*         ctxW   = (float*)alloc((size_t)G * HID * 4);
    f16*           Wp2t   = (f16*)  alloc(128 * 128 * 2);
    f16*           Wm2t   = (f16*)  alloc(128 * 128 * 2);
    f16*           W1at   = (f16*)  alloc(128 * 128 * 2);

    const int TP = (E_P + BIN_T - 1) / BIN_T;
    const int TM = (E_M + BIN_T - 1) / BIN_T;

    // 1. prep (weights, cursor init, graph sizes)
    k_prep_all<<<64, 256, 0, stream>>>(W_p2, W_m2, W1, Wp2t, Wm2t, W1at,
                                       bcur_p, bcur_m, batch_p, pcnt, psum, N_P);
    // 2. binning into padded buckets (residue packed into pairs bits 17..21)
    k_tile_bin2<<<TP + TM, 256, 0, stream>>>(ei_p, ei_p + E_P, residue_p, bcur_p, prs_p,
                                             E_P, NB_P, TP,
                                             ei_m, ei_m + E_M, residue_m, bcur_m, prs_m,
                                             E_M, NB_M);
    // 3. fill A: counts -> rowptr/rowend, dinv, rec8
    k_fill_a<<<NB_P + NB_M, 256, 0, stream>>>(
        prs_p, bcur_p, pos_p, rec8_p, dinv_p, rp_p, re_p, N_P, NB_P,
        prs_m, bcur_m, pos_m, rec8_m, dinv_m, rp_m, re_m, N_M);
    // 4. layer 1 + csr scatter (both branches)
    k_l1_csr<<<NB_P + NB_M, 256, 0, stream>>>(
        prs_p, bcur_p, rec8_p, residue_p, rp_p, csr_p, W_p1, b_p1, dinv_p, y1_p, N_P, NB_P,
        prs_m, bcur_m, rec8_m, residue_m, rp_m, csr_m, W_m1, b_m1, dinv_m, y1_m, N_M);
    // 5. protein: agg + gemm + pool (16-row tiles)
    k_agg_gemm_pool<<<(N_P + 15) / 16, 256, 0, stream>>>(y1_p, rp_p, re_p, csr_p, dinv_p,
                                                         Wp2t, b_p2, batch_p, psum, N_P);
    // 6. ctxW
    k_ctxw_div<<<G, HID, 0, stream>>>(psum, pcnt, W1, b1, ctxW);
    // 7. mm: agg + gemm + gemm + head (16-row tiles)
    k_agg_mm_tail<<<(N_M + 15) / 16, 256, 0, stream>>>(y1_m, rp_m, re_m, csr_m, dinv_m,
                                                       Wm2t, b_m2, batch_m, ctxW,
                                                       W1at, W2, b2, (float*)d_out, N_M);
}

// Round 15
// 279.835 us; speedup vs baseline: 1.6512x; 1.1113x over previous
//
#include <hip/hip_runtime.h>
#include <hip/hip_bf16.h>
#include <hip/hip_fp16.h>

#define HID 128
#define BIN_T 8192
#define NBMAX 1664   // max 64-node buckets (N <= 106496; src id fits 17 bits)
#define CAP 2560     // padded slots per bucket (mean ~1024, sigma ~32)

typedef _Float16 f16;
typedef __attribute__((ext_vector_type(2))) _Float16 f16x2;
typedef __attribute__((ext_vector_type(4))) _Float16 f16x4;
typedef __attribute__((ext_vector_type(8))) _Float16 f16x8;
typedef __attribute__((ext_vector_type(4))) float f32x4;

// pairs layout: src[16:0] | residue[21:17] | dl[31:26]
// pairs storage: bucket b occupies [b*CAP, bcur[b]) after binning.

// ---------------- prep: weight transpose tables, cursor init, graph sizes ----------------

__global__ void k_prep_all(const float* __restrict__ Wp2, const float* __restrict__ Wm2,
                           const float* __restrict__ W1,
                           f16* __restrict__ Wp2t, f16* __restrict__ Wm2t,
                           f16* __restrict__ W1at,
                           int* __restrict__ bcur_p, int* __restrict__ bcur_m,
                           const int* __restrict__ batch_p, int* __restrict__ pcnt,
                           float* __restrict__ psum, int N_P) {
    int idx = blockIdx.x * 256 + threadIdx.x;   // grid 64 -> 16384 threads
    if (idx < 16384) {
        int n = idx & 127, k = idx >> 7;
        Wp2t[n * 128 + k] = (f16)Wp2[k * 128 + n];
        Wm2t[n * 128 + k] = (f16)Wm2[k * 128 + n];
        W1at[n * 128 + k] = (f16)W1[k * 128 + n];
    }
    if (idx <= NBMAX) { bcur_p[idx] = idx * CAP; bcur_m[idx] = idx * CAP; }
    if (idx < 64 * HID) psum[idx] = 0.f;
    if (idx < 64) {
        int g = idx;
        int lo = 0, hi = N_P;
        while (lo < hi) { int mid = (lo + hi) >> 1; if (batch_p[mid] < g) lo = mid + 1; else hi = mid; }
        int a = lo;
        lo = 0; hi = N_P;
        while (lo < hi) { int mid = (lo + hi) >> 1; if (batch_p[mid] < g + 1) lo = mid + 1; else hi = mid; }
        pcnt[g] = lo - a;
    }
}

// ---------------- tile-sorted bucket binning (both branches, padded buckets) ----------------

__global__ void k_tile_bin2(const int* __restrict__ src_p, const int* __restrict__ dst_p,
                            const int* __restrict__ res_p,
                            int* __restrict__ bcur_p, unsigned int* __restrict__ pairs_p,
                            int E_p, int NB_p, int TP,
                            const int* __restrict__ src_m, const int* __restrict__ dst_m,
                            const int* __restrict__ res_m,
                            int* __restrict__ bcur_m, unsigned int* __restrict__ pairs_m,
                            int E_m, int NB_m) {
    __shared__ unsigned int dbuf[BIN_T];
    __shared__ unsigned short perm[BIN_T];
    __shared__ int hist[NBMAX];
    __shared__ int lbase[NBMAX];
    __shared__ int gbase[NBMAX];
    __shared__ int tt[256];
    bool isP = (int)blockIdx.x < TP;
    const int* src = isP ? src_p : src_m;
    const int* dst = isP ? dst_p : dst_m;
    const int* res = isP ? res_p : res_m;
    int* bcursor = isP ? bcur_p : bcur_m;
    unsigned int* pairs = isP ? pairs_p : pairs_m;
    int E = isP ? E_p : E_m;
    int NB = isP ? NB_p : NB_m;
    int tilebase = (isP ? blockIdx.x : blockIdx.x - TP) * BIN_T;
    int t = threadIdx.x;
    int n = min(BIN_T, E - tilebase);
    for (int i = t; i < NB; i += 256) hist[i] = 0;
    __syncthreads();
    for (int i = t; i < n; i += 256) {
        unsigned int d = (unsigned int)dst[tilebase + i];
        dbuf[i] = d;
        atomicAdd(&hist[d >> 6], 1);
    }
    __syncthreads();
    {
        int b0 = t * 7, loc[7], run = 0;
        #pragma unroll
        for (int k = 0; k < 7; ++k) {
            int b = b0 + k;
            int c = (b < NB) ? hist[b] : 0;
            loc[k] = run; run += c;
        }
        tt[t] = run;
        __syncthreads();
        int val = run;
        for (int off = 1; off < 256; off <<= 1) {
            int add = (t >= off) ? tt[t - off] : 0;
            __syncthreads();
            tt[t] += add;
            __syncthreads();
        }
        int ebase = tt[t] - val;
        #pragma unroll
        for (int k = 0; k < 7; ++k) {
            int b = b0 + k;
            if (b < NB) lbase[b] = ebase + loc[k];
        }
    }
    __syncthreads();
    for (int i = t; i < NB; i += 256) {
        int c = hist[i];
        gbase[i] = (c > 0) ? atomicAdd(&bcursor[i], c) : 0;
    }
    __syncthreads();
    for (int i = t; i < NB; i += 256) hist[i] = lbase[i];
    __syncthreads();
    for (int i = t; i < n; i += 256) {
        int b = (int)(dbuf[i] >> 6);
        int p = atomicAdd(&hist[b], 1);
        perm[p] = (unsigned short)i;
    }
    __syncthreads();
    for (int p = t; p < n; p += 256) {
        int li = perm[p];
        unsigned int d = dbuf[li];
        int b = (int)(d >> 6);
        int addr = gbase[b] + (p - lbase[b]);
        int sv = src[tilebase + li];
        pairs[addr] = (unsigned int)sv | ((unsigned int)res[sv] << 17) | ((d & 63u) << 26);
    }
}

// ---------------- fill A (both branches): counts -> rowptr/rowend, dinv, rec8 ----------------

__global__ void k_fill_a(
        const unsigned int* __restrict__ pairs_p, const int* __restrict__ bcur_p,
        const float* __restrict__ pos_p, f16x4* __restrict__ rec8_p,
        float* __restrict__ dinv_p, int* __restrict__ rowptr_p, int* __restrict__ rowend_p,
        int N_p, int NB_p,
        const unsigned int* __restrict__ pairs_m, const int* __restrict__ bcur_m,
        const float* __restrict__ pos_m, f16x4* __restrict__ rec8_m,
        float* __restrict__ dinv_m, int* __restrict__ rowptr_m, int* __restrict__ rowend_m,
        int N_m) {
    __shared__ int cnt[64];
    bool isP = (int)blockIdx.x < NB_p;
    const unsigned int* pairs = isP ? pairs_p : pairs_m;
    const int* bcur = isP ? bcur_p : bcur_m;
    const float* pos = isP ? pos_p : pos_m;
    f16x4* rec8 = isP ? rec8_p : rec8_m;
    float* dinvA = isP ? dinv_p : dinv_m;
    int* rowptr = isP ? rowptr_p : rowptr_m;
    int* rowend = isP ? rowend_p : rowend_m;
    int N = isP ? N_p : N_m;
    int b = isP ? blockIdx.x : blockIdx.x - NB_p;
    int t = threadIdx.x, base = b * 64;
    if (t < 64) cnt[t] = 0;
    __syncthreads();
    int lo = b * CAP, hi = bcur[b];
    for (int e = lo + t; e < hi; e += 256)
        atomicAdd(&cnt[pairs[e] >> 26], 1);
    __syncthreads();
    if (t < 64) {
        int off = 0;
        for (int k = 0; k < t; ++k) off += cnt[k];
        int node = base + t;
        if (node < N) {
            rowptr[node] = lo + off;
            rowend[node] = lo + off + cnt[t];
            float d = (float)cnt[t] + 1.0f;   // +1 self loop
            float di = 1.0f / sqrtf(d);
            dinvA[node] = di;
            float px = pos[node * 3 + 0], py = pos[node * 3 + 1], pz = pos[node * 3 + 2];
            f16x4 r;
            r[0] = (f16)di; r[1] = (f16)(di * px); r[2] = (f16)(di * py); r[3] = (f16)(di * pz);
            rec8[node] = r;
        }
    }
}

// ---------------- fused layer-1 + csr scatter (both branches) ----------------

__global__ __launch_bounds__(256) void k_l1_csr(
        const unsigned int* __restrict__ pairs_p, const int* __restrict__ bcur_p,
        const f16x4* __restrict__ rec8_p, const int* __restrict__ res_p,
        const int* __restrict__ rowptr_p, int* __restrict__ csr_p,
        const float* __restrict__ W_p, const float* __restrict__ bias_p,
        const float* __restrict__ dinv_p, f16* __restrict__ y1_p, int N_p, int NB_p,
        const unsigned int* __restrict__ pairs_m, const int* __restrict__ bcur_m,
        const f16x4* __restrict__ rec8_m, const int* __restrict__ res_m,
        const int* __restrict__ rowptr_m, int* __restrict__ csr_m,
        const float* __restrict__ W_m, const float* __restrict__ bias_m,
        const float* __restrict__ dinv_m, f16* __restrict__ y1_m, int N_m) {
    __shared__ float acc[64][25];
    __shared__ float sdv[64];
    __shared__ int cur[64];
    bool isP = (int)blockIdx.x < NB_p;
    const unsigned int* pairs = isP ? pairs_p : pairs_m;
    const int* bcur = isP ? bcur_p : bcur_m;
    const f16x4* rec8 = isP ? rec8_p : rec8_m;
    const int* residue = isP ? res_p : res_m;
    const int* rowptr = isP ? rowptr_p : rowptr_m;
    int* csr_src = isP ? csr_p : csr_m;
    const float* W = isP ? W_p : W_m;
    const float* bias = isP ? bias_p : bias_m;
    const float* dinvA = isP ? dinv_p : dinv_m;
    f16* y1h = isP ? y1_p : y1_m;
    int N = isP ? N_p : N_m;
    int b = isP ? blockIdx.x : blockIdx.x - NB_p;
    int t = threadIdx.x, base = b * 64;
    for (int q = t; q < 64 * 25; q += 256) ((float*)acc)[q] = 0.f;
    if (t < 64) {
        int node = base + t;
        if (node < N) { sdv[t] = dinvA[node]; cur[t] = rowptr[node]; }
        else cur[t] = 0;
    }
    int jj = (t & 63) * 2, slot = t >> 6;
    float wreg[23][2];
    #pragma unroll
    for (int k = 0; k < 23; ++k) {
        float2 wv = *(const float2*)&W[k * 128 + jj];
        wreg[k][0] = wv.x; wreg[k][1] = wv.y;
    }
    __syncthreads();
    int lo = b * CAP, hi = bcur[b];
    for (int e = lo + t; e < hi; e += 512) {
        unsigned int pk0 = pairs[e];
        int e1 = e + 256;
        bool h1 = e1 < hi;
        unsigned int pk1 = pairs[h1 ? e1 : e];
        int s0 = (int)(pk0 & 0x1FFFFu), s1 = (int)(pk1 & 0x1FFFFu);
        f16x4 r0 = rec8[s0];
        f16x4 r1 = rec8[s1];
        int dl0 = (int)(pk0 >> 26), rs0 = (int)((pk0 >> 17) & 31u);
        int slot0 = atomicAdd(&cur[dl0], 1);
        csr_src[slot0] = s0;
        atomicAdd(&acc[dl0][rs0], (float)r0[0]);
        atomicAdd(&acc[dl0][20], (float)r0[1]);
        atomicAdd(&acc[dl0][21], (float)r0[2]);
        atomicAdd(&acc[dl0][22], (float)r0[3]);
        if (h1) {
            int dl1 = (int)(pk1 >> 26), rs1 = (int)((pk1 >> 17) & 31u);
            int slot1 = atomicAdd(&cur[dl1], 1);
            csr_src[slot1] = s1;
            atomicAdd(&acc[dl1][rs1], (float)r1[0]);
            atomicAdd(&acc[dl1][20], (float)r1[1]);
            atomicAdd(&acc[dl1][21], (float)r1[2]);
            atomicAdd(&acc[dl1][22], (float)r1[3]);
        }
    }
    __syncthreads();
    if (t < 64) {
        int node = base + t;
        if (node < N) {
            f16x4 r = rec8[node];
            acc[t][residue[node]] += (float)r[0];
            acc[t][20] += (float)r[1];
            acc[t][21] += (float)r[2];
            acc[t][22] += (float)r[3];
            float di = sdv[t];
            #pragma unroll
            for (int k = 0; k < 23; ++k) acc[t][k] *= di;
        }
    }
    __syncthreads();
    float bj0 = bias[jj], bj1 = bias[jj + 1];
    for (int r = slot * 16; r < slot * 16 + 16; ++r) {
        int node = base + r;
        if (node >= N) break;
        float a0 = bj0, a1 = bj1;
        #pragma unroll
        for (int k = 0; k < 23; ++k) {
            float zv = acc[r][k];
            a0 += zv * wreg[k][0];
            a1 += zv * wreg[k][1];
        }
        float dv = sdv[r];
        f16x2 o;
        o[0] = (f16)(fmaxf(a0, 0.f) * dv);
        o[1] = (f16)(fmaxf(a1, 0.f) * dv);
        *(f16x2*)&y1h[(size_t)node * HID + jj] = o;
    }
}

// ---------------- wave-per-node agg into 16-row LDS z-tile (f16), 8-edge unroll ----------------

#define AGG16_TO_LDS(zs, y1h, rowptr, rowend, csr_src, dinvA, N)                \
    {                                                                           \
        const __half2* y2 = (const __half2*)y1h;                                \
        for (int i = 0; i < 4; ++i) {                                           \
            int node = tile + w * 4 + i;                                        \
            int cn = min(node, N - 1);                                          \
            int s0 = rowptr[cn], s1 = rowend[cn];                               \
            float ax = 0.f, ay = 0.f;                                           \
            int e = s0;                                                         \
            for (; e + 8 <= s1; e += 8) {                                       \
                float2 v0 = __half22float2(y2[(size_t)csr_src[e] * 64 + lane]);     \
                float2 v1 = __half22float2(y2[(size_t)csr_src[e + 1] * 64 + lane]); \
                float2 v2 = __half22float2(y2[(size_t)csr_src[e + 2] * 64 + lane]); \
                float2 v3 = __half22float2(y2[(size_t)csr_src[e + 3] * 64 + lane]); \
                float2 v4 = __half22float2(y2[(size_t)csr_src[e + 4] * 64 + lane]); \
                float2 v5 = __half22float2(y2[(size_t)csr_src[e + 5] * 64 + lane]); \
                float2 v6 = __half22float2(y2[(size_t)csr_src[e + 6] * 64 + lane]); \
                float2 v7 = __half22float2(y2[(size_t)csr_src[e + 7] * 64 + lane]); \
                ax += (v0.x + v1.x) + (v2.x + v3.x) + (v4.x + v5.x) + (v6.x + v7.x); \
                ay += (v0.y + v1.y) + (v2.y + v3.y) + (v4.y + v5.y) + (v6.y + v7.y); \
            }                                                                   \
            for (; e + 4 <= s1; e += 4) {                                       \
                float2 v0 = __half22float2(y2[(size_t)csr_src[e] * 64 + lane]);     \
                float2 v1 = __half22float2(y2[(size_t)csr_src[e + 1] * 64 + lane]); \
                float2 v2 = __half22float2(y2[(size_t)csr_src[e + 2] * 64 + lane]); \
                float2 v3 = __half22float2(y2[(size_t)csr_src[e + 3] * 64 + lane]); \
                ax += (v0.x + v1.x) + (v2.x + v3.x);                            \
                ay += (v0.y + v1.y) + (v2.y + v3.y);                            \
            }                                                                   \
            for (; e < s1; ++e) {                                               \
                float2 v = __half22float2(y2[(size_t)csr_src[e] * 64 + lane]);  \
                ax += v.x; ay += v.y;                                           \
            }                                                                   \
            float di = dinvA[cn];                                               \
            float2 vs = __half22float2(y2[(size_t)cn * 64 + lane]);             \
            f16x2 o;                                                            \
            o[0] = (f16)((ax + vs.x) * di);                                     \
            o[1] = (f16)((ay + vs.y) * di);                                     \
            *(f16x2*)&zs[w * 4 + i][lane * 2] = o;                              \
        }                                                                       \
    }                                                                           \
    __syncthreads();

// ---------------- combined: protein agg+gemm+pool  ||  mm agg+x2-gemm -> x2g ----------------

__global__ __launch_bounds__(256) void k_agg_combined(
        const f16* __restrict__ y1p, const int* __restrict__ rpp, const int* __restrict__ rep,
        const int* __restrict__ csrp, const float* __restrict__ dvp,
        const f16* __restrict__ Wp2t, const float* __restrict__ bp2,
        const int* __restrict__ batchp, float* __restrict__ psum, int Np, int PB,
        const f16* __restrict__ y1m, const int* __restrict__ rpm, const int* __restrict__ rem,
        const int* __restrict__ csrm, const float* __restrict__ dvm,
        const f16* __restrict__ Wm2t, const float* __restrict__ bm2,
        f16* __restrict__ x2g, int Nm) {
    __shared__ f16 zs[16][136];
    int t = threadIdx.x, lane = t & 63, w = t >> 6;
    int lr = lane & 15, kb = lane >> 4;
    bool isP = (int)blockIdx.x < PB;
    if (isP) {
        const f16* y1h = y1p;
        int N = Np;
        int tile = blockIdx.x * 16;
        AGG16_TO_LDS(zs, y1h, rpp, rep, csrp, dvp, N)
        int g0 = batchp[min(tile, N - 1)];
        bool uni = (tile + 15 < N) && (g0 == batchp[tile + 15]);
        int gr[4]; bool val[4];
        if (!uni) {
            #pragma unroll
            for (int r = 0; r < 4; ++r) {
                int row = tile + kb * 4 + r;
                val[r] = row < N;
                gr[r] = batchp[min(row, N - 1)];
            }
        }
        f16x8 afr[4];
        #pragma unroll
        for (int kc = 0; kc < 4; ++kc)
            afr[kc] = *(const f16x8*)&zs[lr][kc * 32 + kb * 8];
        #pragma unroll
        for (int q = 0; q < 2; ++q) {
            int ct = w * 2 + q;
            f32x4 c4 = {0.f, 0.f, 0.f, 0.f};
            int col = ct * 16 + lr;
            const f16* wp = Wp2t + (size_t)col * HID + kb * 8;
            #pragma unroll
            for (int kc = 0; kc < 4; ++kc) {
                f16x8 bf = *(const f16x8*)(wp + kc * 32);
                c4 = __builtin_amdgcn_mfma_f32_16x16x32_f16(afr[kc], bf, c4, 0, 0, 0);
            }
            float bj = bp2[col];
            if (uni) {
                float ps = 0.f;
                #pragma unroll
                for (int r = 0; r < 4; ++r) ps += fmaxf(c4[r] + bj, 0.f);
                ps += __shfl_xor(ps, 16);
                ps += __shfl_xor(ps, 32);
                if (kb == 0) atomicAdd(&psum[g0 * HID + col], ps);
            } else {
                #pragma unroll
                for (int r = 0; r < 4; ++r)
                    if (val[r]) atomicAdd(&psum[gr[r] * HID + col], fmaxf(c4[r] + bj, 0.f));
            }
        }
    } else {
        const f16* y1h = y1m;
        int N = Nm;
        int tile = (blockIdx.x - PB) * 16;
        AGG16_TO_LDS(zs, y1h, rpm, rem, csrm, dvm, N)
        f16x8 afr[4];
        #pragma unroll
        for (int kc = 0; kc < 4; ++kc)
            afr[kc] = *(const f16x8*)&zs[lr][kc * 32 + kb * 8];
        __syncthreads();
        #pragma unroll
        for (int q = 0; q < 2; ++q) {
            int ct = w * 2 + q;
            f32x4 c4 = {0.f, 0.f, 0.f, 0.f};
            int col = ct * 16 + lr;
            const f16* wp = Wm2t + (size_t)col * HID + kb * 8;
            #pragma unroll
            for (int kc = 0; kc < 4; ++kc) {
                f16x8 bf = *(const f16x8*)(wp + kc * 32);
                c4 = __builtin_amdgcn_mfma_f32_16x16x32_f16(afr[kc], bf, c4, 0, 0, 0);
            }
            float bj = bm2[col];
            #pragma unroll
            for (int r = 0; r < 4; ++r)
                zs[kb * 4 + r][col] = (f16)fmaxf(c4[r] + bj, 0.f);
        }
        __syncthreads();
        // coalesced copy out: 16 rows x 128 f16
        int row = t >> 4, c8 = (t & 15) * 8;
        if (tile + row < N)
            *(f16x8*)&x2g[(size_t)(tile + row) * HID + c8] = *(const f16x8*)&zs[row][c8];
    }
}

// ctxW[g] = (psum[g]/cnt[g]) @ W1[128:,:] + b1
__global__ void k_ctxw_div(const float* __restrict__ psum, const int* __restrict__ pcnt,
                           const float* __restrict__ W1, const float* __restrict__ b1,
                           float* __restrict__ ctxW) {
    __shared__ float pr[128];
    int g = blockIdx.x, j = threadIdx.x;
    pr[j] = psum[g * HID + j] / fmaxf((float)pcnt[g], 1.f);
    __syncthreads();
    float a = b1[j];
    #pragma unroll 4
    for (int k = 0; k < HID; ++k) a += pr[k] * W1[(HID + k) * HID + j];
    ctxW[g * HID + j] = a;
}

// mm finish: h = relu(x2 @ W1a + ctxW[batch]); out = h @ W2 + b2
__global__ __launch_bounds__(256) void k_mm_finish(
        const f16* __restrict__ x2g, const int* __restrict__ batch,
        const float* __restrict__ ctxW, const f16* __restrict__ W1at,
        const float* __restrict__ W2, const float* __restrict__ b2,
        float* __restrict__ out, int N) {
    __shared__ float part[4][16][3];
    int tile = blockIdx.x * 16;
    int t = threadIdx.x, lane = t & 63, w = t >> 6;
    int lr = lane & 15, kb = lane >> 4;
    int cr = min(tile + lr, N - 1);
    f16x8 afr[4];
    #pragma unroll
    for (int kc = 0; kc < 4; ++kc)
        afr[kc] = *(const f16x8*)&x2g[(size_t)cr * HID + kc * 32 + kb * 8];
    int gidx[4];
    #pragma unroll
    for (int r = 0; r < 4; ++r)
        gidx[r] = batch[min(tile + kb * 4 + r, N - 1)];
    float po[4][3] = {};
    #pragma unroll
    for (int q = 0; q < 2; ++q) {
        int ct = w * 2 + q;
        f32x4 c4 = {0.f, 0.f, 0.f, 0.f};
        int col = ct * 16 + lr;
        const f16* wp = W1at + (size_t)col * HID + kb * 8;
        #pragma unroll
        for (int kc = 0; kc < 4; ++kc) {
            f16x8 bf = *(const f16x8*)(wp + kc * 32);
            c4 = __builtin_amdgcn_mfma_f32_16x16x32_f16(afr[kc], bf, c4, 0, 0, 0);
        }
        float w0 = W2[col * 3 + 0], w1 = W2[col * 3 + 1], w2 = W2[col * 3 + 2];
        #pragma unroll
        for (int r = 0; r < 4; ++r) {
            float h = fmaxf(c4[r] + ctxW[gidx[r] * HID + col], 0.f);
            po[r][0] += h * w0;
            po[r][1] += h * w1;
            po[r][2] += h * w2;
        }
    }
    #pragma unroll
    for (int m = 1; m < 16; m <<= 1) {
        #pragma unroll
        for (int r = 0; r < 4; ++r) {
            po[r][0] += __shfl_xor(po[r][0], m);
            po[r][1] += __shfl_xor(po[r][1], m);
            po[r][2] += __shfl_xor(po[r][2], m);
        }
    }
    if (lr == 0) {
        #pragma unroll
        for (int r = 0; r < 4; ++r) {
            part[w][kb * 4 + r][0] = po[r][0];
            part[w][kb * 4 + r][1] = po[r][1];
            part[w][kb * 4 + r][2] = po[r][2];
        }
    }
    __syncthreads();
    if (t < 48) {
        int row = t / 3, c = t - row * 3;
        int gr2 = tile + row;
        if (gr2 < N)
            out[(size_t)gr2 * 3 + c] = part[0][row][c] + part[1][row][c] +
                                       part[2][row][c] + part[3][row][c] + b2[c];
    }
}

// ---------------- launch ----------------

extern "C" void kernel_launch(void* const* d_in, const int* in_sizes, int n_in,
                              void* d_out, int out_size, void* d_ws, size_t ws_size,
                              hipStream_t stream) {
    const int*   residue_p = (const int*)d_in[0];
    const float* pos_p     = (const float*)d_in[1];
    const int*   ei_p      = (const int*)d_in[2];
    const int*   batch_p   = (const int*)d_in[3];
    const int*   residue_m = (const int*)d_in[4];
    const float* pos_m     = (const float*)d_in[5];
    const int*   ei_m      = (const int*)d_in[6];
    const int*   batch_m   = (const int*)d_in[7];
    const float* W_p1 = (const float*)d_in[8];
    const float* b_p1 = (const float*)d_in[9];
    const float* W_p2 = (const float*)d_in[10];
    const float* b_p2 = (const float*)d_in[11];
    const float* W_m1 = (const float*)d_in[12];
    const float* b_m1 = (const float*)d_in[13];
    const float* W_m2 = (const float*)d_in[14];
    const float* b_m2 = (const float*)d_in[15];
    const float* W1   = (const float*)d_in[16];
    const float* b1   = (const float*)d_in[17];
    const float* W2   = (const float*)d_in[18];
    const float* b2   = (const float*)d_in[19];

    const int N_P = in_sizes[0];
    const int E_P = in_sizes[2] / 2;
    const int N_M = in_sizes[4];
    const int E_M = in_sizes[6] / 2;
    const int G = 64;
    const int NB_P = (N_P + 63) / 64;
    const int NB_M = (N_M + 63) / 64;
    const int PB = (N_P + 15) / 16;
    const int MB = (N_M + 15) / 16;

    char* ws = (char*)d_ws;
    size_t off = 0;
    auto alloc = [&](size_t bytes) {
        char* p = ws + off;
        off += (bytes + 511) & ~size_t(511);
        return p;
    };
    f16*           y1_p   = (f16*)  alloc((size_t)N_P * HID * 2);
    f16*           y1_m   = (f16*)  alloc((size_t)N_M * HID * 2);
    f16*           x2g    = (f16*)  alloc((size_t)N_M * HID * 2);
    f16x4*         rec8_p = (f16x4*)alloc((size_t)N_P * 8);
    f16x4*         rec8_m = (f16x4*)alloc((size_t)N_M * 8);
    float*         dinv_p = (float*)alloc((size_t)N_P * 4);
    float*         dinv_m = (float*)alloc((size_t)N_M * 4);
    int*           rp_p   = (int*)  alloc((size_t)N_P * 4);
    int*           rp_m   = (int*)  alloc((size_t)N_M * 4);
    int*           re_p   = (int*)  alloc((size_t)N_P * 4);
    int*           re_m   = (int*)  alloc((size_t)N_M * 4);
    int*           bcur_p = (int*)  alloc((NBMAX + 1) * 4);
    int*           bcur_m = (int*)  alloc((NBMAX + 1) * 4);
    unsigned int*  prs_p  = (unsigned int*)alloc((size_t)NB_P * CAP * 4);
    unsigned int*  prs_m  = (unsigned int*)alloc((size_t)NB_M * CAP * 4);
    int*           csr_p  = (int*)  alloc((size_t)NB_P * CAP * 4);
    int*           csr_m  = (int*)  alloc((size_t)NB_M * CAP * 4);
    float*         psum   = (float*)alloc((size_t)G * HID * 4);
    int*           pcnt   = (int*)  alloc((size_t)G * 4);
    float*         ctxW   = (float*)alloc((size_t)G * HID * 4);
    f16*           Wp2t   = (f16*)  alloc(128 * 128 * 2);
    f16*           Wm2t   = (f16*)  alloc(128 * 128 * 2);
    f16*           W1at   = (f16*)  alloc(128 * 128 * 2);

    const int TP = (E_P + BIN_T - 1) / BIN_T;
    const int TM = (E_M + BIN_T - 1) / BIN_T;

    // 1. prep (weights, cursor init, graph sizes)
    k_prep_all<<<64, 256, 0, stream>>>(W_p2, W_m2, W1, Wp2t, Wm2t, W1at,
                                       bcur_p, bcur_m, batch_p, pcnt, psum, N_P);
    // 2. binning into padded buckets (residue packed into pairs bits 17..21)
    k_tile_bin2<<<TP + TM, 256, 0, stream>>>(ei_p, ei_p + E_P, residue_p, bcur_p, prs_p,
                                             E_P, NB_P, TP,
                                             ei_m, ei_m + E_M, residue_m, bcur_m, prs_m,
                                             E_M, NB_M);
    // 3. fill A: counts -> rowptr/rowend, dinv, rec8
    k_fill_a<<<NB_P + NB_M, 256, 0, stream>>>(
        prs_p, bcur_p, pos_p, rec8_p, dinv_p, rp_p, re_p, N_P, NB_P,
        prs_m, bcur_m, pos_m, rec8_m, dinv_m, rp_m, re_m, N_M);
    // 4. layer 1 + csr scatter (both branches)
    k_l1_csr<<<NB_P + NB_M, 256, 0, stream>>>(
        prs_p, bcur_p, rec8_p, residue_p, rp_p, csr_p, W_p1, b_p1, dinv_p, y1_p, N_P, NB_P,
        prs_m, bcur_m, rec8_m, residue_m, rp_m, csr_m, W_m1, b_m1, dinv_m, y1_m, N_M);
    // 5. combined: protein agg+gemm+pool || mm agg+x2
    k_agg_combined<<<PB + MB, 256, 0, stream>>>(
        y1_p, rp_p, re_p, csr_p, dinv_p, Wp2t, b_p2, batch_p, psum, N_P, PB,
        y1_m, rp_m, re_m, csr_m, dinv_m, Wm2t, b_m2, x2g, N_M);
    // 6. ctxW
    k_ctxw_div<<<G, HID, 0, stream>>>(psum, pcnt, W1, b1, ctxW);
    // 7. mm finish: x2 -> h -> out
    k_mm_finish<<<MB, 256, 0, stream>>>(x2g, batch_m, ctxW, W1at, W2, b2,
                                        (float*)d_out, N_M);
}

// Round 16
// 278.149 us; speedup vs baseline: 1.6612x; 1.0061x over previous
//
#include <hip/hip_runtime.h>
#include <hip/hip_bf16.h>
#include <hip/hip_fp16.h>

#define HID 128
#define BIN_T 8192
#define NBMAX 1664   // max 64-node buckets (N <= 106496; src id fits 17 bits)
#define CAP 2560     // padded slots per bucket (mean ~1024, sigma ~32)

typedef _Float16 f16;
typedef __attribute__((ext_vector_type(2))) _Float16 f16x2;
typedef __attribute__((ext_vector_type(4))) _Float16 f16x4;
typedef __attribute__((ext_vector_type(8))) _Float16 f16x8;
typedef __attribute__((ext_vector_type(4))) float f32x4;

// pairs layout: src[16:0] | dl[31:26]
// pairs storage: bucket b occupies [b*CAP, bcur[b]) after binning.
// rec16[node]: int4 { f16x4 {dinv, dinv*px, dinv*py, dinv*pz} , res, pad }

// ---------------- prep: weight transpose tables, cursor init, graph sizes ----------------

__global__ void k_prep_all(const float* __restrict__ Wp2, const float* __restrict__ Wm2,
                           const float* __restrict__ W1,
                           f16* __restrict__ Wp2t, f16* __restrict__ Wm2t,
                           f16* __restrict__ W1at,
                           int* __restrict__ bcur_p, int* __restrict__ bcur_m,
                           const int* __restrict__ batch_p, int* __restrict__ pcnt,
                           float* __restrict__ psum, int N_P) {
    int idx = blockIdx.x * 256 + threadIdx.x;   // grid 64 -> 16384 threads
    if (idx < 16384) {
        int n = idx & 127, k = idx >> 7;
        Wp2t[n * 128 + k] = (f16)Wp2[k * 128 + n];
        Wm2t[n * 128 + k] = (f16)Wm2[k * 128 + n];
        W1at[n * 128 + k] = (f16)W1[k * 128 + n];
    }
    if (idx <= NBMAX) { bcur_p[idx] = idx * CAP; bcur_m[idx] = idx * CAP; }
    if (idx < 64 * HID) psum[idx] = 0.f;
    if (idx < 64) {
        int g = idx;
        int lo = 0, hi = N_P;
        while (lo < hi) { int mid = (lo + hi) >> 1; if (batch_p[mid] < g) lo = mid + 1; else hi = mid; }
        int a = lo;
        lo = 0; hi = N_P;
        while (lo < hi) { int mid = (lo + hi) >> 1; if (batch_p[mid] < g + 1) lo = mid + 1; else hi = mid; }
        pcnt[g] = lo - a;
    }
}

// ---------------- tile-sorted bucket binning (both branches, padded buckets) ----------------

__global__ void k_tile_bin2(const int* __restrict__ src_p, const int* __restrict__ dst_p,
                            int* __restrict__ bcur_p, unsigned int* __restrict__ pairs_p,
                            int E_p, int NB_p, int TP,
                            const int* __restrict__ src_m, const int* __restrict__ dst_m,
                            int* __restrict__ bcur_m, unsigned int* __restrict__ pairs_m,
                            int E_m, int NB_m) {
    __shared__ unsigned int dbuf[BIN_T];
    __shared__ unsigned short perm[BIN_T];
    __shared__ int hist[NBMAX];
    __shared__ int lbase[NBMAX];
    __shared__ int gbase[NBMAX];
    __shared__ int tt[256];
    bool isP = (int)blockIdx.x < TP;
    const int* src = isP ? src_p : src_m;
    const int* dst = isP ? dst_p : dst_m;
    int* bcursor = isP ? bcur_p : bcur_m;
    unsigned int* pairs = isP ? pairs_p : pairs_m;
    int E = isP ? E_p : E_m;
    int NB = isP ? NB_p : NB_m;
    int tilebase = (isP ? blockIdx.x : blockIdx.x - TP) * BIN_T;
    int t = threadIdx.x;
    int n = min(BIN_T, E - tilebase);
    for (int i = t; i < NB; i += 256) hist[i] = 0;
    __syncthreads();
    for (int i = t; i < n; i += 256) {
        unsigned int d = (unsigned int)dst[tilebase + i];
        dbuf[i] = d;
        atomicAdd(&hist[d >> 6], 1);
    }
    __syncthreads();
    {
        int b0 = t * 7, loc[7], run = 0;
        #pragma unroll
        for (int k = 0; k < 7; ++k) {
            int b = b0 + k;
            int c = (b < NB) ? hist[b] : 0;
            loc[k] = run; run += c;
        }
        tt[t] = run;
        __syncthreads();
        int val = run;
        for (int off = 1; off < 256; off <<= 1) {
            int add = (t >= off) ? tt[t - off] : 0;
            __syncthreads();
            tt[t] += add;
            __syncthreads();
        }
        int ebase = tt[t] - val;
        #pragma unroll
        for (int k = 0; k < 7; ++k) {
            int b = b0 + k;
            if (b < NB) lbase[b] = ebase + loc[k];
        }
    }
    __syncthreads();
    for (int i = t; i < NB; i += 256) {
        int c = hist[i];
        gbase[i] = (c > 0) ? atomicAdd(&bcursor[i], c) : 0;
    }
    __syncthreads();
    for (int i = t; i < NB; i += 256) hist[i] = lbase[i];
    __syncthreads();
    for (int i = t; i < n; i += 256) {
        int b = (int)(dbuf[i] >> 6);
        int p = atomicAdd(&hist[b], 1);
        perm[p] = (unsigned short)i;
    }
    __syncthreads();
    for (int p = t; p < n; p += 256) {
        int li = perm[p];
        unsigned int d = dbuf[li];
        int b = (int)(d >> 6);
        int addr = gbase[b] + (p - lbase[b]);
        pairs[addr] = (unsigned int)src[tilebase + li] | ((d & 63u) << 26);
    }
}

// ---------------- fill A (both branches): counts -> rowptr/rowend, dinv, rec16, csr ----------------

__global__ void k_fill_a(
        const unsigned int* __restrict__ pairs_p, const int* __restrict__ bcur_p,
        const int* __restrict__ res_p, const float* __restrict__ pos_p,
        int4* __restrict__ rec16_p, float* __restrict__ dinv_p,
        int* __restrict__ rowptr_p, int* __restrict__ rowend_p, int* __restrict__ csr_p,
        int N_p, int NB_p,
        const unsigned int* __restrict__ pairs_m, const int* __restrict__ bcur_m,
        const int* __restrict__ res_m, const float* __restrict__ pos_m,
        int4* __restrict__ rec16_m, float* __restrict__ dinv_m,
        int* __restrict__ rowptr_m, int* __restrict__ rowend_m, int* __restrict__ csr_m,
        int N_m) {
    __shared__ int cnt[64];
    __shared__ int cur[64];
    bool isP = (int)blockIdx.x < NB_p;
    const unsigned int* pairs = isP ? pairs_p : pairs_m;
    const int* bcur = isP ? bcur_p : bcur_m;
    const int* residue = isP ? res_p : res_m;
    const float* pos = isP ? pos_p : pos_m;
    int4* rec16 = isP ? rec16_p : rec16_m;
    float* dinvA = isP ? dinv_p : dinv_m;
    int* rowptr = isP ? rowptr_p : rowptr_m;
    int* rowend = isP ? rowend_p : rowend_m;
    int* csr_src = isP ? csr_p : csr_m;
    int N = isP ? N_p : N_m;
    int b = isP ? blockIdx.x : blockIdx.x - NB_p;
    int t = threadIdx.x, base = b * 64;
    if (t < 64) cnt[t] = 0;
    __syncthreads();
    int lo = b * CAP, hi = bcur[b];
    for (int e = lo + t; e < hi; e += 256)
        atomicAdd(&cnt[pairs[e] >> 26], 1);
    __syncthreads();
    if (t < 64) {
        int off = 0;
        for (int k = 0; k < t; ++k) off += cnt[k];
        int node = base + t;
        if (node < N) {
            rowptr[node] = lo + off;
            rowend[node] = lo + off + cnt[t];
            float d = (float)cnt[t] + 1.0f;   // +1 self loop
            float di = 1.0f / sqrtf(d);
            dinvA[node] = di;
            float px = pos[node * 3 + 0], py = pos[node * 3 + 1], pz = pos[node * 3 + 2];
            f16x4 r;
            r[0] = (f16)di; r[1] = (f16)(di * px); r[2] = (f16)(di * py); r[3] = (f16)(di * pz);
            int4 rc;
            rc.x = ((const int*)&r)[0];
            rc.y = ((const int*)&r)[1];
            rc.z = residue[node];
            rc.w = 0;
            rec16[node] = rc;
        }
        cur[t] = lo + off;
    }
    __syncthreads();
    // second pass (L2-hot): scatter csr (node-sorted src lists)
    for (int e = lo + t; e < hi; e += 256) {
        unsigned int pk = pairs[e];
        int slot = atomicAdd(&cur[pk >> 26], 1);
        csr_src[slot] = (int)(pk & 0x1FFFFu);
    }
}

// ---------------- fused layer-1 (both branches): bucket agg (24-dim) + GEMM + premult ----------------
// z0_i = dinv_i*(sum_s y0_s + y0_i), y0 = dinv*[onehot,pos]; y1 = dinv*relu(z0@W+b) f16

__global__ __launch_bounds__(256) void k_l1(
        const unsigned int* __restrict__ pairs_p, const int* __restrict__ bcur_p,
        const int4* __restrict__ rec16_p,
        const float* __restrict__ W_p, const float* __restrict__ bias_p,
        const float* __restrict__ dinv_p, f16* __restrict__ y1_p, int N_p, int NB_p,
        const unsigned int* __restrict__ pairs_m, const int* __restrict__ bcur_m,
        const int4* __restrict__ rec16_m,
        const float* __restrict__ W_m, const float* __restrict__ bias_m,
        const float* __restrict__ dinv_m, f16* __restrict__ y1_m, int N_m) {
    __shared__ float acc[64][25];
    __shared__ float sdv[64];
    bool isP = (int)blockIdx.x < NB_p;
    const unsigned int* pairs = isP ? pairs_p : pairs_m;
    const int* bcur = isP ? bcur_p : bcur_m;
    const int4* rec16 = isP ? rec16_p : rec16_m;
    const float* W = isP ? W_p : W_m;
    const float* bias = isP ? bias_p : bias_m;
    const float* dinvA = isP ? dinv_p : dinv_m;
    f16* y1h = isP ? y1_p : y1_m;
    int N = isP ? N_p : N_m;
    int b = isP ? blockIdx.x : blockIdx.x - NB_p;
    int t = threadIdx.x, base = b * 64;
    for (int q = t; q < 64 * 25; q += 256) ((float*)acc)[q] = 0.f;
    if (t < 64 && base + t < N) sdv[t] = dinvA[base + t];
    int jj = (t & 63) * 2, slot = t >> 6;
    float wreg[23][2];
    #pragma unroll
    for (int k = 0; k < 23; ++k) {
        float2 wv = *(const float2*)&W[k * 128 + jj];
        wreg[k][0] = wv.x; wreg[k][1] = wv.y;
    }
    __syncthreads();
    int lo = b * CAP, hi = bcur[b];
    // 4-deep pipelined edge loop: pairs load + rec16 gather + 4 LDS atomics
    for (int e = lo + t; e < hi; e += 1024) {
        unsigned int pk[4];
        int4 rc[4];
        bool hv[4];
        #pragma unroll
        for (int u = 0; u < 4; ++u) {
            int ee = e + u * 256;
            hv[u] = ee < hi;
            pk[u] = pairs[hv[u] ? ee : e];
        }
        #pragma unroll
        for (int u = 0; u < 4; ++u)
            rc[u] = rec16[pk[u] & 0x1FFFFu];
        #pragma unroll
        for (int u = 0; u < 4; ++u) {
            if (!hv[u]) continue;
            f16x2 lo2 = *(const f16x2*)&rc[u].x;
            f16x2 hi2 = *(const f16x2*)&rc[u].y;
            int dl = (int)(pk[u] >> 26);
            int rs = rc[u].z;
            atomicAdd(&acc[dl][rs], (float)lo2[0]);
            atomicAdd(&acc[dl][20], (float)lo2[1]);
            atomicAdd(&acc[dl][21], (float)hi2[0]);
            atomicAdd(&acc[dl][22], (float)hi2[1]);
        }
    }
    __syncthreads();
    if (t < 64) {
        int node = base + t;
        if (node < N) {
            int4 rc = rec16[node];
            f16x2 lo2 = *(const f16x2*)&rc.x;
            f16x2 hi2 = *(const f16x2*)&rc.y;
            acc[t][rc.z] += (float)lo2[0];
            acc[t][20] += (float)lo2[1];
            acc[t][21] += (float)hi2[0];
            acc[t][22] += (float)hi2[1];
            float di = sdv[t];
            #pragma unroll
            for (int k = 0; k < 23; ++k) acc[t][k] *= di;
        }
    }
    __syncthreads();
    float bj0 = bias[jj], bj1 = bias[jj + 1];
    for (int r = slot * 16; r < slot * 16 + 16; ++r) {
        int node = base + r;
        if (node >= N) break;
        float a0 = bj0, a1 = bj1;
        #pragma unroll
        for (int k = 0; k < 23; ++k) {
            float zv = acc[r][k];
            a0 += zv * wreg[k][0];
            a1 += zv * wreg[k][1];
        }
        float dv = sdv[r];
        f16x2 o;
        o[0] = (f16)(fmaxf(a0, 0.f) * dv);
        o[1] = (f16)(fmaxf(a1, 0.f) * dv);
        *(f16x2*)&y1h[(size_t)node * HID + jj] = o;
    }
}

// ---------------- wave-per-node agg into 16-row LDS z-tile (f16), 8-edge unroll ----------------

#define AGG16_TO_LDS(zs, y1h, rowptr, rowend, csr_src, dinvA, N)                \
    {                                                                           \
        const __half2* y2 = (const __half2*)y1h;                                \
        for (int i = 0; i < 4; ++i) {                                           \
            int node = tile + w * 4 + i;                                        \
            int cn = min(node, N - 1);                                          \
            int s0 = rowptr[cn], s1 = rowend[cn];                               \
            float ax = 0.f, ay = 0.f;                                           \
            int e = s0;                                                         \
            for (; e + 8 <= s1; e += 8) {                                       \
                float2 v0 = __half22float2(y2[(size_t)csr_src[e] * 64 + lane]);     \
                float2 v1 = __half22float2(y2[(size_t)csr_src[e + 1] * 64 + lane]); \
                float2 v2 = __half22float2(y2[(size_t)csr_src[e + 2] * 64 + lane]); \
                float2 v3 = __half22float2(y2[(size_t)csr_src[e + 3] * 64 + lane]); \
                float2 v4 = __half22float2(y2[(size_t)csr_src[e + 4] * 64 + lane]); \
                float2 v5 = __half22float2(y2[(size_t)csr_src[e + 5] * 64 + lane]); \
                float2 v6 = __half22float2(y2[(size_t)csr_src[e + 6] * 64 + lane]); \
                float2 v7 = __half22float2(y2[(size_t)csr_src[e + 7] * 64 + lane]); \
                ax += (v0.x + v1.x) + (v2.x + v3.x) + (v4.x + v5.x) + (v6.x + v7.x); \
                ay += (v0.y + v1.y) + (v2.y + v3.y) + (v4.y + v5.y) + (v6.y + v7.y); \
            }                                                                   \
            for (; e + 4 <= s1; e += 4) {                                       \
                float2 v0 = __half22float2(y2[(size_t)csr_src[e] * 64 + lane]);     \
                float2 v1 = __half22float2(y2[(size_t)csr_src[e + 1] * 64 + lane]); \
                float2 v2 = __half22float2(y2[(size_t)csr_src[e + 2] * 64 + lane]); \
                float2 v3 = __half22float2(y2[(size_t)csr_src[e + 3] * 64 + lane]); \
                ax += (v0.x + v1.x) + (v2.x + v3.x);                            \
                ay += (v0.y + v1.y) + (v2.y + v3.y);                            \
            }                                                                   \
            for (; e < s1; ++e) {                                               \
                float2 v = __half22float2(y2[(size_t)csr_src[e] * 64 + lane]);  \
                ax += v.x; ay += v.y;                                           \
            }                                                                   \
            float di = dinvA[cn];                                               \
            float2 vs = __half22float2(y2[(size_t)cn * 64 + lane]);             \
            f16x2 o;                                                            \
            o[0] = (f16)((ax + vs.x) * di);                                     \
            o[1] = (f16)((ay + vs.y) * di);                                     \
            *(f16x2*)&zs[w * 4 + i][lane * 2] = o;                              \
        }                                                                       \
    }                                                                           \
    __syncthreads();

// ---------------- combined: protein agg+gemm+pool  ||  mm agg+x2-gemm -> x2g ----------------

__global__ __launch_bounds__(256) void k_agg_combined(
        const f16* __restrict__ y1p, const int* __restrict__ rpp, const int* __restrict__ rep,
        const int* __restrict__ csrp, const float* __restrict__ dvp,
        const f16* __restrict__ Wp2t, const float* __restrict__ bp2,
        const int* __restrict__ batchp, float* __restrict__ psum, int Np, int PB,
        const f16* __restrict__ y1m, const int* __restrict__ rpm, const int* __restrict__ rem,
        const int* __restrict__ csrm, const float* __restrict__ dvm,
        const f16* __restrict__ Wm2t, const float* __restrict__ bm2,
        f16* __restrict__ x2g, int Nm) {
    __shared__ f16 zs[16][136];
    int t = threadIdx.x, lane = t & 63, w = t >> 6;
    int lr = lane & 15, kb = lane >> 4;
    bool isP = (int)blockIdx.x < PB;
    if (isP) {
        const f16* y1h = y1p;
        int N = Np;
        int tile = blockIdx.x * 16;
        AGG16_TO_LDS(zs, y1h, rpp, rep, csrp, dvp, N)
        int g0 = batchp[min(tile, N - 1)];
        bool uni = (tile + 15 < N) && (g0 == batchp[tile + 15]);
        int gr[4]; bool val[4];
        if (!uni) {
            #pragma unroll
            for (int r = 0; r < 4; ++r) {
                int row = tile + kb * 4 + r;
                val[r] = row < N;
                gr[r] = batchp[min(row, N - 1)];
            }
        }
        f16x8 afr[4];
        #pragma unroll
        for (int kc = 0; kc < 4; ++kc)
            afr[kc] = *(const f16x8*)&zs[lr][kc * 32 + kb * 8];
        #pragma unroll
        for (int q = 0; q < 2; ++q) {
            int ct = w * 2 + q;
            f32x4 c4 = {0.f, 0.f, 0.f, 0.f};
            int col = ct * 16 + lr;
            const f16* wp = Wp2t + (size_t)col * HID + kb * 8;
            #pragma unroll
            for (int kc = 0; kc < 4; ++kc) {
                f16x8 bf = *(const f16x8*)(wp + kc * 32);
                c4 = __builtin_amdgcn_mfma_f32_16x16x32_f16(afr[kc], bf, c4, 0, 0, 0);
            }
            float bj = bp2[col];
            if (uni) {
                float ps = 0.f;
                #pragma unroll
                for (int r = 0; r < 4; ++r) ps += fmaxf(c4[r] + bj, 0.f);
                ps += __shfl_xor(ps, 16);
                ps += __shfl_xor(ps, 32);
                if (kb == 0) atomicAdd(&psum[g0 * HID + col], ps);
            } else {
                #pragma unroll
                for (int r = 0; r < 4; ++r)
                    if (val[r]) atomicAdd(&psum[gr[r] * HID + col], fmaxf(c4[r] + bj, 0.f));
            }
        }
    } else {
        const f16* y1h = y1m;
        int N = Nm;
        int tile = (blockIdx.x - PB) * 16;
        AGG16_TO_LDS(zs, y1h, rpm, rem, csrm, dvm, N)
        f16x8 afr[4];
        #pragma unroll
        for (int kc = 0; kc < 4; ++kc)
            afr[kc] = *(const f16x8*)&zs[lr][kc * 32 + kb * 8];
        __syncthreads();
        #pragma unroll
        for (int q = 0; q < 2; ++q) {
            int ct = w * 2 + q;
            f32x4 c4 = {0.f, 0.f, 0.f, 0.f};
            int col = ct * 16 + lr;
            const f16* wp = Wm2t + (size_t)col * HID + kb * 8;
            #pragma unroll
            for (int kc = 0; kc < 4; ++kc) {
                f16x8 bf = *(const f16x8*)(wp + kc * 32);
                c4 = __builtin_amdgcn_mfma_f32_16x16x32_f16(afr[kc], bf, c4, 0, 0, 0);
            }
            float bj = bm2[col];
            #pragma unroll
            for (int r = 0; r < 4; ++r)
                zs[kb * 4 + r][col] = (f16)fmaxf(c4[r] + bj, 0.f);
        }
        __syncthreads();
        // coalesced copy out: 16 rows x 128 f16
        int row = t >> 4, c8 = (t & 15) * 8;
        if (tile + row < N)
            *(f16x8*)&x2g[(size_t)(tile + row) * HID + c8] = *(const f16x8*)&zs[row][c8];
    }
}

// ctxW[g] = (psum[g]/cnt[g]) @ W1[128:,:] + b1
__global__ void k_ctxw_div(const float* __restrict__ psum, const int* __restrict__ pcnt,
                           const float* __restrict__ W1, const float* __restrict__ b1,
                           float* __restrict__ ctxW) {
    __shared__ float pr[128];
    int g = blockIdx.x, j = threadIdx.x;
    pr[j] = psum[g * HID + j] / fmaxf((float)pcnt[g], 1.f);
    __syncthreads();
    float a = b1[j];
    #pragma unroll 4
    for (int k = 0; k < HID; ++k) a += pr[k] * W1[(HID + k) * HID + j];
    ctxW[g * HID + j] = a;
}

// mm finish: h = relu(x2 @ W1a + ctxW[batch]); out = h @ W2 + b2
__global__ __launch_bounds__(256) void k_mm_finish(
        const f16* __restrict__ x2g, const int* __restrict__ batch,
        const float* __restrict__ ctxW, const f16* __restrict__ W1at,
        const float* __restrict__ W2, const float* __restrict__ b2,
        float* __restrict__ out, int N) {
    __shared__ float part[4][16][3];
    int tile = blockIdx.x * 16;
    int t = threadIdx.x, lane = t & 63, w = t >> 6;
    int lr = lane & 15, kb = lane >> 4;
    int cr = min(tile + lr, N - 1);
    f16x8 afr[4];
    #pragma unroll
    for (int kc = 0; kc < 4; ++kc)
        afr[kc] = *(const f16x8*)&x2g[(size_t)cr * HID + kc * 32 + kb * 8];
    int gidx[4];
    #pragma unroll
    for (int r = 0; r < 4; ++r)
        gidx[r] = batch[min(tile + kb * 4 + r, N - 1)];
    float po[4][3] = {};
    #pragma unroll
    for (int q = 0; q < 2; ++q) {
        int ct = w * 2 + q;
        f32x4 c4 = {0.f, 0.f, 0.f, 0.f};
        int col = ct * 16 + lr;
        const f16* wp = W1at + (size_t)col * HID + kb * 8;
        #pragma unroll
        for (int kc = 0; kc < 4; ++kc) {
            f16x8 bf = *(const f16x8*)(wp + kc * 32);
            c4 = __builtin_amdgcn_mfma_f32_16x16x32_f16(afr[kc], bf, c4, 0, 0, 0);
        }
        float w0 = W2[col * 3 + 0], w1 = W2[col * 3 + 1], w2 = W2[col * 3 + 2];
        #pragma unroll
        for (int r = 0; r < 4; ++r) {
            float h = fmaxf(c4[r] + ctxW[gidx[r] * HID + col], 0.f);
            po[r][0] += h * w0;
            po[r][1] += h * w1;
            po[r][2] += h * w2;
        }
    }
    #pragma unroll
    for (int m = 1; m < 16; m <<= 1) {
        #pragma unroll
        for (int r = 0; r < 4; ++r) {
            po[r][0] += __shfl_xor(po[r][0], m);
            po[r][1] += __shfl_xor(po[r][1], m);
            po[r][2] += __shfl_xor(po[r][2], m);
        }
    }
    if (lr == 0) {
        #pragma unroll
        for (int r = 0; r < 4; ++r) {
            part[w][kb * 4 + r][0] = po[r][0];
            part[w][kb * 4 + r][1] = po[r][1];
            part[w][kb * 4 + r][2] = po[r][2];
        }
    }
    __syncthreads();
    if (t < 48) {
        int row = t / 3, c = t - row * 3;
        int gr2 = tile + row;
        if (gr2 < N)
            out[(size_t)gr2 * 3 + c] = part[0][row][c] + part[1][row][c] +
                                       part[2][row][c] + part[3][row][c] + b2[c];
    }
}

// ---------------- launch ----------------

extern "C" void kernel_launch(void* const* d_in, const int* in_sizes, int n_in,
                              void* d_out, int out_size, void* d_ws, size_t ws_size,
                              hipStream_t stream) {
    const int*   residue_p = (const int*)d_in[0];
    const float* pos_p     = (const float*)d_in[1];
    const int*   ei_p      = (const int*)d_in[2];
    const int*   batch_p   = (const int*)d_in[3];
    const int*   residue_m = (const int*)d_in[4];
    const float* pos_m     = (const float*)d_in[5];
    const int*   ei_m      = (const int*)d_in[6];
    const int*   batch_m   = (const int*)d_in[7];
    const float* W_p1 = (const float*)d_in[8];
    const float* b_p1 = (const float*)d_in[9];
    const float* W_p2 = (const float*)d_in[10];
    const float* b_p2 = (const float*)d_in[11];
    const float* W_m1 = (const float*)d_in[12];
    const float* b_m1 = (const float*)d_in[13];
    const float* W_m2 = (const float*)d_in[14];
    const float* b_m2 = (const float*)d_in[15];
    const float* W1   = (const float*)d_in[16];
    const float* b1   = (const float*)d_in[17];
    const float* W2   = (const float*)d_in[18];
    const float* b2   = (const float*)d_in[19];

    const int N_P = in_sizes[0];
    const int E_P = in_sizes[2] / 2;
    const int N_M = in_sizes[4];
    const int E_M = in_sizes[6] / 2;
    const int G = 64;
    const int NB_P = (N_P + 63) / 64;
    const int NB_M = (N_M + 63) / 64;
    const int PB = (N_P + 15) / 16;
    const int MB = (N_M + 15) / 16;

    char* ws = (char*)d_ws;
    size_t off = 0;
    auto alloc = [&](size_t bytes) {
        char* p = ws + off;
        off += (bytes + 511) & ~size_t(511);
        return p;
    };
    f16*           y1_p    = (f16*)  alloc((size_t)N_P * HID * 2);
    f16*           y1_m    = (f16*)  alloc((size_t)N_M * HID * 2);
    f16*           x2g     = (f16*)  alloc((size_t)N_M * HID * 2);
    int4*          rec16_p = (int4*) alloc((size_t)N_P * 16);
    int4*          rec16_m = (int4*) alloc((size_t)N_M * 16);
    float*         dinv_p  = (float*)alloc((size_t)N_P * 4);
    float*         dinv_m  = (float*)alloc((size_t)N_M * 4);
    int*           rp_p    = (int*)  alloc((size_t)N_P * 4);
    int*           rp_m    = (int*)  alloc((size_t)N_M * 4);
    int*           re_p    = (int*)  alloc((size_t)N_P * 4);
    int*           re_m    = (int*)  alloc((size_t)N_M * 4);
    int*           bcur_p  = (int*)  alloc((NBMAX + 1) * 4);
    int*           bcur_m  = (int*)  alloc((NBMAX + 1) * 4);
    unsigned int*  prs_p   = (unsigned int*)alloc((size_t)NB_P * CAP * 4);
    unsigned int*  prs_m   = (unsigned int*)alloc((size_t)NB_M * CAP * 4);
    int*           csr_p   = (int*)  alloc((size_t)NB_P * CAP * 4);
    int*           csr_m   = (int*)  alloc((size_t)NB_M * CAP * 4);
    float*         psum    = (float*)alloc((size_t)G * HID * 4);
    int*           pcnt    = (int*)  alloc((size_t)G * 4);
    float*         ctxW    = (float*)alloc((size_t)G * HID * 4);
    f16*           Wp2t    = (f16*)  alloc(128 * 128 * 2);
    f16*           Wm2t    = (f16*)  alloc(128 * 128 * 2);
    f16*           W1at    = (f16*)  alloc(128 * 128 * 2);

    const int TP = (E_P + BIN_T - 1) / BIN_T;
    const int TM = (E_M + BIN_T - 1) / BIN_T;

    // 1. prep (weights, cursor init, graph sizes)
    k_prep_all<<<64, 256, 0, stream>>>(W_p2, W_m2, W1, Wp2t, Wm2t, W1at,
                                       bcur_p, bcur_m, batch_p, pcnt, psum, N_P);
    // 2. binning into padded buckets
    k_tile_bin2<<<TP + TM, 256, 0, stream>>>(ei_p, ei_p + E_P, bcur_p, prs_p, E_P, NB_P, TP,
                                             ei_m, ei_m + E_M, bcur_m, prs_m, E_M, NB_M);
    // 3. fill A: counts -> rowptr/rowend, dinv, rec16, csr scatter
    k_fill_a<<<NB_P + NB_M, 256, 0, stream>>>(
        prs_p, bcur_p, residue_p, pos_p, rec16_p, dinv_p, rp_p, re_p, csr_p, N_P, NB_P,
        prs_m, bcur_m, residue_m, pos_m, rec16_m, dinv_m, rp_m, re_m, csr_m, N_M);
    // 4. layer 1 (both branches)
    k_l1<<<NB_P + NB_M, 256, 0, stream>>>(
        prs_p, bcur_p, rec16_p, W_p1, b_p1, dinv_p, y1_p, N_P, NB_P,
        prs_m, bcur_m, rec16_m, W_m1, b_m1, dinv_m, y1_m, N_M);
    // 5. combined: protein agg+gemm+pool || mm agg+x2
    k_agg_combined<<<PB + MB, 256, 0, stream>>>(
        y1_p, rp_p, re_p, csr_p, dinv_p, Wp2t, b_p2, batch_p, psum, N_P, PB,
        y1_m, rp_m, re_m, csr_m, dinv_m, Wm2t, b_m2, x2g, N_M);
    // 6. ctxW
    k_ctxw_div<<<G, HID, 0, stream>>>(psum, pcnt, W1, b1, ctxW);
    // 7. mm finish: x2 -> h -> out
    k_mm_finish<<<MB, 256, 0, stream>>>(x2g, batch_m, ctxW, W1at, W2, b2,
                                        (float*)d_out, N_M);
}

// Round 17
// 269.954 us; speedup vs baseline: 1.7117x; 1.0304x over previous
//
#include <hip/hip_runtime.h>
#include <hip/hip_bf16.h>
#include <hip/hip_fp16.h>

#define HID 128
#define BIN_T 8192
#define NBMAX 1664   // max 64-node buckets (N <= 106496; src id fits 17 bits)
#define CAP 2560     // padded slots per bucket (mean ~1024, sigma ~32)

typedef _Float16 f16;
typedef __attribute__((ext_vector_type(2))) _Float16 f16x2;
typedef __attribute__((ext_vector_type(4))) _Float16 f16x4;
typedef __attribute__((ext_vector_type(8))) _Float16 f16x8;
typedef __attribute__((ext_vector_type(4))) float f32x4;

// pairs layout: src[16:0] | dl[31:26]
// pairs storage: bucket b occupies [b*CAP, bcur[b]) after binning.
// rec16[node]: int4 { f16x4 {dinv, dinv*px, dinv*py, dinv*pz} , res, pad }

// ---------------- prep: weight transpose tables, cursor init, graph sizes ----------------

__global__ void k_prep_all(const float* __restrict__ Wp2, const float* __restrict__ Wm2,
                           const float* __restrict__ W1,
                           f16* __restrict__ Wp2t, f16* __restrict__ Wm2t,
                           f16* __restrict__ W1at,
                           int* __restrict__ bcur_p, int* __restrict__ bcur_m,
                           const int* __restrict__ batch_p, int* __restrict__ pcnt,
                           float* __restrict__ psum, int N_P) {
    int idx = blockIdx.x * 256 + threadIdx.x;   // grid 64 -> 16384 threads
    if (idx < 16384) {
        int n = idx & 127, k = idx >> 7;
        Wp2t[n * 128 + k] = (f16)Wp2[k * 128 + n];
        Wm2t[n * 128 + k] = (f16)Wm2[k * 128 + n];
        W1at[n * 128 + k] = (f16)W1[k * 128 + n];
    }
    if (idx <= NBMAX) { bcur_p[idx] = idx * CAP; bcur_m[idx] = idx * CAP; }
    if (idx < 64 * HID) psum[idx] = 0.f;
    if (idx < 64) {
        int g = idx;
        int lo = 0, hi = N_P;
        while (lo < hi) { int mid = (lo + hi) >> 1; if (batch_p[mid] < g) lo = mid + 1; else hi = mid; }
        int a = lo;
        lo = 0; hi = N_P;
        while (lo < hi) { int mid = (lo + hi) >> 1; if (batch_p[mid] < g + 1) lo = mid + 1; else hi = mid; }
        pcnt[g] = lo - a;
    }
}

// ---------------- tile-sorted bucket binning (both branches, padded buckets) ----------------

__global__ void k_tile_bin2(const int* __restrict__ src_p, const int* __restrict__ dst_p,
                            int* __restrict__ bcur_p, unsigned int* __restrict__ pairs_p,
                            int E_p, int NB_p, int TP,
                            const int* __restrict__ src_m, const int* __restrict__ dst_m,
                            int* __restrict__ bcur_m, unsigned int* __restrict__ pairs_m,
                            int E_m, int NB_m) {
    __shared__ unsigned int dbuf[BIN_T];
    __shared__ unsigned short perm[BIN_T];
    __shared__ int hist[NBMAX];
    __shared__ int lbase[NBMAX];
    __shared__ int gbase[NBMAX];
    __shared__ int tt[256];
    bool isP = (int)blockIdx.x < TP;
    const int* src = isP ? src_p : src_m;
    const int* dst = isP ? dst_p : dst_m;
    int* bcursor = isP ? bcur_p : bcur_m;
    unsigned int* pairs = isP ? pairs_p : pairs_m;
    int E = isP ? E_p : E_m;
    int NB = isP ? NB_p : NB_m;
    int tilebase = (isP ? blockIdx.x : blockIdx.x - TP) * BIN_T;
    int t = threadIdx.x;
    int n = min(BIN_T, E - tilebase);
    for (int i = t; i < NB; i += 256) hist[i] = 0;
    __syncthreads();
    for (int i = t; i < n; i += 256) {
        unsigned int d = (unsigned int)dst[tilebase + i];
        dbuf[i] = d;
        atomicAdd(&hist[d >> 6], 1);
    }
    __syncthreads();
    {
        int b0 = t * 7, loc[7], run = 0;
        #pragma unroll
        for (int k = 0; k < 7; ++k) {
            int b = b0 + k;
            int c = (b < NB) ? hist[b] : 0;
            loc[k] = run; run += c;
        }
        tt[t] = run;
        __syncthreads();
        int val = run;
        for (int off = 1; off < 256; off <<= 1) {
            int add = (t >= off) ? tt[t - off] : 0;
            __syncthreads();
            tt[t] += add;
            __syncthreads();
        }
        int ebase = tt[t] - val;
        #pragma unroll
        for (int k = 0; k < 7; ++k) {
            int b = b0 + k;
            if (b < NB) lbase[b] = ebase + loc[k];
        }
    }
    __syncthreads();
    for (int i = t; i < NB; i += 256) {
        int c = hist[i];
        gbase[i] = (c > 0) ? atomicAdd(&bcursor[i], c) : 0;
    }
    __syncthreads();
    for (int i = t; i < NB; i += 256) hist[i] = lbase[i];
    __syncthreads();
    for (int i = t; i < n; i += 256) {
        int b = (int)(dbuf[i] >> 6);
        int p = atomicAdd(&hist[b], 1);
        perm[p] = (unsigned short)i;
    }
    __syncthreads();
    for (int p = t; p < n; p += 256) {
        int li = perm[p];
        unsigned int d = dbuf[li];
        int b = (int)(d >> 6);
        int addr = gbase[b] + (p - lbase[b]);
        pairs[addr] = (unsigned int)src[tilebase + li] | ((d & 63u) << 26);
    }
}

// ---------------- fill A (both branches): counts -> rowptr/rowend, dinv, rec16, csr ----------------

__global__ void k_fill_a(
        const unsigned int* __restrict__ pairs_p, const int* __restrict__ bcur_p,
        const int* __restrict__ res_p, const float* __restrict__ pos_p,
        int4* __restrict__ rec16_p, float* __restrict__ dinv_p,
        int* __restrict__ rowptr_p, int* __restrict__ rowend_p, int* __restrict__ csr_p,
        int N_p, int NB_p,
        const unsigned int* __restrict__ pairs_m, const int* __restrict__ bcur_m,
        const int* __restrict__ res_m, const float* __restrict__ pos_m,
        int4* __restrict__ rec16_m, float* __restrict__ dinv_m,
        int* __restrict__ rowptr_m, int* __restrict__ rowend_m, int* __restrict__ csr_m,
        int N_m) {
    __shared__ int cnt[64];
    __shared__ int cur[64];
    bool isP = (int)blockIdx.x < NB_p;
    const unsigned int* pairs = isP ? pairs_p : pairs_m;
    const int* bcur = isP ? bcur_p : bcur_m;
    const int* residue = isP ? res_p : res_m;
    const float* pos = isP ? pos_p : pos_m;
    int4* rec16 = isP ? rec16_p : rec16_m;
    float* dinvA = isP ? dinv_p : dinv_m;
    int* rowptr = isP ? rowptr_p : rowptr_m;
    int* rowend = isP ? rowend_p : rowend_m;
    int* csr_src = isP ? csr_p : csr_m;
    int N = isP ? N_p : N_m;
    int b = isP ? blockIdx.x : blockIdx.x - NB_p;
    int t = threadIdx.x, base = b * 64;
    if (t < 64) cnt[t] = 0;
    __syncthreads();
    int lo = b * CAP, hi = bcur[b];
    for (int e = lo + t; e < hi; e += 256)
        atomicAdd(&cnt[pairs[e] >> 26], 1);
    __syncthreads();
    if (t < 64) {
        int off = 0;
        for (int k = 0; k < t; ++k) off += cnt[k];
        int node = base + t;
        if (node < N) {
            rowptr[node] = lo + off;
            rowend[node] = lo + off + cnt[t];
            float d = (float)cnt[t] + 1.0f;   // +1 self loop
            float di = 1.0f / sqrtf(d);
            dinvA[node] = di;
            float px = pos[node * 3 + 0], py = pos[node * 3 + 1], pz = pos[node * 3 + 2];
            f16x4 r;
            r[0] = (f16)di; r[1] = (f16)(di * px); r[2] = (f16)(di * py); r[3] = (f16)(di * pz);
            int4 rc;
            rc.x = ((const int*)&r)[0];
            rc.y = ((const int*)&r)[1];
            rc.z = residue[node];
            rc.w = 0;
            rec16[node] = rc;
        }
        cur[t] = lo + off;
    }
    __syncthreads();
    // second pass (L2-hot): scatter csr (node-sorted src lists)
    for (int e = lo + t; e < hi; e += 256) {
        unsigned int pk = pairs[e];
        int slot = atomicAdd(&cur[pk >> 26], 1);
        csr_src[slot] = (int)(pk & 0x1FFFFu);
    }
}

// ---------------- fused layer-1 (both branches): bucket agg (24-dim) + GEMM + premult ----------------
// z0_i = dinv_i*(sum_s y0_s + y0_i), y0 = dinv*[onehot,pos]; y1 = dinv*relu(z0@W+b) f16

__global__ __launch_bounds__(256) void k_l1(
        const unsigned int* __restrict__ pairs_p, const int* __restrict__ bcur_p,
        const int4* __restrict__ rec16_p,
        const float* __restrict__ W_p, const float* __restrict__ bias_p,
        const float* __restrict__ dinv_p, f16* __restrict__ y1_p, int N_p, int NB_p,
        const unsigned int* __restrict__ pairs_m, const int* __restrict__ bcur_m,
        const int4* __restrict__ rec16_m,
        const float* __restrict__ W_m, const float* __restrict__ bias_m,
        const float* __restrict__ dinv_m, f16* __restrict__ y1_m, int N_m) {
    __shared__ float acc[64][25];
    __shared__ float sdv[64];
    bool isP = (int)blockIdx.x < NB_p;
    const unsigned int* pairs = isP ? pairs_p : pairs_m;
    const int* bcur = isP ? bcur_p : bcur_m;
    const int4* rec16 = isP ? rec16_p : rec16_m;
    const float* W = isP ? W_p : W_m;
    const float* bias = isP ? bias_p : bias_m;
    const float* dinvA = isP ? dinv_p : dinv_m;
    f16* y1h = isP ? y1_p : y1_m;
    int N = isP ? N_p : N_m;
    int b = isP ? blockIdx.x : blockIdx.x - NB_p;
    int t = threadIdx.x, base = b * 64;
    for (int q = t; q < 64 * 25; q += 256) ((float*)acc)[q] = 0.f;
    if (t < 64 && base + t < N) sdv[t] = dinvA[base + t];
    int jj = (t & 63) * 2, slot = t >> 6;
    float wreg[23][2];
    #pragma unroll
    for (int k = 0; k < 23; ++k) {
        float2 wv = *(const float2*)&W[k * 128 + jj];
        wreg[k][0] = wv.x; wreg[k][1] = wv.y;
    }
    __syncthreads();
    int lo = b * CAP, hi = bcur[b];
    // 4-deep pipelined edge loop: pairs load + rec16 gather + 4 LDS atomics
    for (int e = lo + t; e < hi; e += 1024) {
        unsigned int pk[4];
        int4 rc[4];
        bool hv[4];
        #pragma unroll
        for (int u = 0; u < 4; ++u) {
            int ee = e + u * 256;
            hv[u] = ee < hi;
            pk[u] = pairs[hv[u] ? ee : e];
        }
        #pragma unroll
        for (int u = 0; u < 4; ++u)
            rc[u] = rec16[pk[u] & 0x1FFFFu];
        #pragma unroll
        for (int u = 0; u < 4; ++u) {
            if (!hv[u]) continue;
            f16x2 lo2 = *(const f16x2*)&rc[u].x;
            f16x2 hi2 = *(const f16x2*)&rc[u].y;
            int dl = (int)(pk[u] >> 26);
            int rs = rc[u].z;
            atomicAdd(&acc[dl][rs], (float)lo2[0]);
            atomicAdd(&acc[dl][20], (float)lo2[1]);
            atomicAdd(&acc[dl][21], (float)hi2[0]);
            atomicAdd(&acc[dl][22], (float)hi2[1]);
        }
    }
    __syncthreads();
    if (t < 64) {
        int node = base + t;
        if (node < N) {
            int4 rc = rec16[node];
            f16x2 lo2 = *(const f16x2*)&rc.x;
            f16x2 hi2 = *(const f16x2*)&rc.y;
            acc[t][rc.z] += (float)lo2[0];
            acc[t][20] += (float)lo2[1];
            acc[t][21] += (float)hi2[0];
            acc[t][22] += (float)hi2[1];
            float di = sdv[t];
            #pragma unroll
            for (int k = 0; k < 23; ++k) acc[t][k] *= di;
        }
    }
    __syncthreads();
    float bj0 = bias[jj], bj1 = bias[jj + 1];
    for (int r = slot * 16; r < slot * 16 + 16; ++r) {
        int node = base + r;
        if (node >= N) break;
        float a0 = bj0, a1 = bj1;
        #pragma unroll
        for (int k = 0; k < 23; ++k) {
            float zv = acc[r][k];
            a0 += zv * wreg[k][0];
            a1 += zv * wreg[k][1];
        }
        float dv = sdv[r];
        f16x2 o;
        o[0] = (f16)(fmaxf(a0, 0.f) * dv);
        o[1] = (f16)(fmaxf(a1, 0.f) * dv);
        *(f16x2*)&y1h[(size_t)node * HID + jj] = o;
    }
}

// ---------------- wave-per-node agg into 16-row LDS z-tile (f16) ----------------
// Index span staged in LDS (contiguous per 16-node tile). 4 edges per wave-instr:
// lane (kb=edge-of-4, lr=16B column slice); f32 accum; shfl_xor(16/32) folds kb.

#define AGG16_TO_LDS(zs, sidx, y1h, rowptr, rowend, csr_src, dinvA, N)          \
    {                                                                           \
        int sp0 = rowptr[tile];                                                 \
        int sp1 = rowend[min(tile + 15, N - 1)];                                \
        int slen = sp1 - sp0;                                                   \
        for (int i = t; i < slen; i += 256) sidx[i] = csr_src[sp0 + i];         \
        __syncthreads();                                                        \
        for (int i = 0; i < 4; ++i) {                                           \
            int node = tile + w * 4 + i;                                        \
            int cn = min(node, N - 1);                                          \
            int lb = rowptr[cn] - sp0, le = rowend[cn] - sp0;                   \
            float fa[8] = {};                                                   \
            int e = lb;                                                         \
            for (; e + 8 <= le; e += 8) {                                       \
                int i0 = sidx[e + kb], i1 = sidx[e + 4 + kb];                   \
                f16x8 v0 = *(const f16x8*)(y1h + (size_t)i0 * HID + lr * 8);    \
                f16x8 v1 = *(const f16x8*)(y1h + (size_t)i1 * HID + lr * 8);    \
                _Pragma("unroll")                                               \
                for (int j = 0; j < 8; ++j)                                     \
                    fa[j] += (float)v0[j] + (float)v1[j];                       \
            }                                                                   \
            if (e + 4 <= le) {                                                  \
                int i0 = sidx[e + kb];                                          \
                f16x8 v0 = *(const f16x8*)(y1h + (size_t)i0 * HID + lr * 8);    \
                _Pragma("unroll")                                               \
                for (int j = 0; j < 8; ++j) fa[j] += (float)v0[j];              \
                e += 4;                                                         \
            }                                                                   \
            if (e + kb < le) {                                                  \
                int i0 = sidx[e + kb];                                          \
                f16x8 v0 = *(const f16x8*)(y1h + (size_t)i0 * HID + lr * 8);    \
                _Pragma("unroll")                                               \
                for (int j = 0; j < 8; ++j) fa[j] += (float)v0[j];              \
            }                                                                   \
            _Pragma("unroll")                                                   \
            for (int j = 0; j < 8; ++j) {                                       \
                fa[j] += __shfl_xor(fa[j], 16);                                 \
                fa[j] += __shfl_xor(fa[j], 32);                                 \
            }                                                                   \
            if (kb == 0) {                                                      \
                f16x8 sv = *(const f16x8*)(y1h + (size_t)cn * HID + lr * 8);    \
                float di = dinvA[cn];                                           \
                f16x8 o;                                                        \
                _Pragma("unroll")                                               \
                for (int j = 0; j < 8; ++j)                                     \
                    o[j] = (f16)((fa[j] + (float)sv[j]) * di);                  \
                *(f16x8*)&zs[w * 4 + i][lr * 8] = o;                            \
            }                                                                   \
        }                                                                       \
    }                                                                           \
    __syncthreads();

// ---------------- combined: protein agg+gemm+pool  ||  mm agg+x2-gemm -> x2g ----------------

__global__ __launch_bounds__(256) void k_agg_combined(
        const f16* __restrict__ y1p, const int* __restrict__ rpp, const int* __restrict__ rep,
        const int* __restrict__ csrp, const float* __restrict__ dvp,
        const f16* __restrict__ Wp2t, const float* __restrict__ bp2,
        const int* __restrict__ batchp, float* __restrict__ psum, int Np, int PB,
        const f16* __restrict__ y1m, const int* __restrict__ rpm, const int* __restrict__ rem,
        const int* __restrict__ csrm, const float* __restrict__ dvm,
        const f16* __restrict__ Wm2t, const float* __restrict__ bm2,
        f16* __restrict__ x2g, int Nm) {
    __shared__ __attribute__((aligned(16))) f16 zs[16][136];
    __shared__ int sidx[CAP];
    int t = threadIdx.x, lane = t & 63, w = t >> 6;
    int lr = lane & 15, kb = lane >> 4;
    bool isP = (int)blockIdx.x < PB;
    if (isP) {
        const f16* y1h = y1p;
        int N = Np;
        int tile = blockIdx.x * 16;
        AGG16_TO_LDS(zs, sidx, y1h, rpp, rep, csrp, dvp, N)
        int g0 = batchp[min(tile, N - 1)];
        bool uni = (tile + 15 < N) && (g0 == batchp[tile + 15]);
        int gr[4]; bool val[4];
        if (!uni) {
            #pragma unroll
            for (int r = 0; r < 4; ++r) {
                int row = tile + kb * 4 + r;
                val[r] = row < N;
                gr[r] = batchp[min(row, N - 1)];
            }
        }
        f16x8 afr[4];
        #pragma unroll
        for (int kc = 0; kc < 4; ++kc)
            afr[kc] = *(const f16x8*)&zs[lr][kc * 32 + kb * 8];
        #pragma unroll
        for (int q = 0; q < 2; ++q) {
            int ct = w * 2 + q;
            f32x4 c4 = {0.f, 0.f, 0.f, 0.f};
            int col = ct * 16 + lr;
            const f16* wp = Wp2t + (size_t)col * HID + kb * 8;
            #pragma unroll
            for (int kc = 0; kc < 4; ++kc) {
                f16x8 bf = *(const f16x8*)(wp + kc * 32);
                c4 = __builtin_amdgcn_mfma_f32_16x16x32_f16(afr[kc], bf, c4, 0, 0, 0);
            }
            float bj = bp2[col];
            if (uni) {
                float ps = 0.f;
                #pragma unroll
                for (int r = 0; r < 4; ++r) ps += fmaxf(c4[r] + bj, 0.f);
                ps += __shfl_xor(ps, 16);
                ps += __shfl_xor(ps, 32);
                if (kb == 0) atomicAdd(&psum[g0 * HID + col], ps);
            } else {
                #pragma unroll
                for (int r = 0; r < 4; ++r)
                    if (val[r]) atomicAdd(&psum[gr[r] * HID + col], fmaxf(c4[r] + bj, 0.f));
            }
        }
    } else {
        const f16* y1h = y1m;
        int N = Nm;
        int tile = (blockIdx.x - PB) * 16;
        AGG16_TO_LDS(zs, sidx, y1h, rpm, rem, csrm, dvm, N)
        f16x8 afr[4];
        #pragma unroll
        for (int kc = 0; kc < 4; ++kc)
            afr[kc] = *(const f16x8*)&zs[lr][kc * 32 + kb * 8];
        __syncthreads();
        #pragma unroll
        for (int q = 0; q < 2; ++q) {
            int ct = w * 2 + q;
            f32x4 c4 = {0.f, 0.f, 0.f, 0.f};
            int col = ct * 16 + lr;
            const f16* wp = Wm2t + (size_t)col * HID + kb * 8;
            #pragma unroll
            for (int kc = 0; kc < 4; ++kc) {
                f16x8 bf = *(const f16x8*)(wp + kc * 32);
                c4 = __builtin_amdgcn_mfma_f32_16x16x32_f16(afr[kc], bf, c4, 0, 0, 0);
            }
            float bj = bm2[col];
            #pragma unroll
            for (int r = 0; r < 4; ++r)
                zs[kb * 4 + r][col] = (f16)fmaxf(c4[r] + bj, 0.f);
        }
        __syncthreads();
        // coalesced copy out: 16 rows x 128 f16
        int row = t >> 4, c8 = (t & 15) * 8;
        if (tile + row < N)
            *(f16x8*)&x2g[(size_t)(tile + row) * HID + c8] = *(const f16x8*)&zs[row][c8];
    }
}

// ctxW[g] = (psum[g]/cnt[g]) @ W1[128:,:] + b1
__global__ void k_ctxw_div(const float* __restrict__ psum, const int* __restrict__ pcnt,
                           const float* __restrict__ W1, const float* __restrict__ b1,
                           float* __restrict__ ctxW) {
    __shared__ float pr[128];
    int g = blockIdx.x, j = threadIdx.x;
    pr[j] = psum[g * HID + j] / fmaxf((float)pcnt[g], 1.f);
    __syncthreads();
    float a = b1[j];
    #pragma unroll 4
    for (int k = 0; k < HID; ++k) a += pr[k] * W1[(HID + k) * HID + j];
    ctxW[g * HID + j] = a;
}

// mm finish: h = relu(x2 @ W1a + ctxW[batch]); out = h @ W2 + b2
__global__ __launch_bounds__(256) void k_mm_finish(
        const f16* __restrict__ x2g, const int* __restrict__ batch,
        const float* __restrict__ ctxW, const f16* __restrict__ W1at,
        const float* __restrict__ W2, const float* __restrict__ b2,
        float* __restrict__ out, int N) {
    __shared__ float part[4][16][3];
    int tile = blockIdx.x * 16;
    int t = threadIdx.x, lane = t & 63, w = t >> 6;
    int lr = lane & 15, kb = lane >> 4;
    int cr = min(tile + lr, N - 1);
    f16x8 afr[4];
    #pragma unroll
    for (int kc = 0; kc < 4; ++kc)
        afr[kc] = *(const f16x8*)&x2g[(size_t)cr * HID + kc * 32 + kb * 8];
    int gidx[4];
    #pragma unroll
    for (int r = 0; r < 4; ++r)
        gidx[r] = batch[min(tile + kb * 4 + r, N - 1)];
    float po[4][3] = {};
    #pragma unroll
    for (int q = 0; q < 2; ++q) {
        int ct = w * 2 + q;
        f32x4 c4 = {0.f, 0.f, 0.f, 0.f};
        int col = ct * 16 + lr;
        const f16* wp = W1at + (size_t)col * HID + kb * 8;
        #pragma unroll
        for (int kc = 0; kc < 4; ++kc) {
            f16x8 bf = *(const f16x8*)(wp + kc * 32);
            c4 = __builtin_amdgcn_mfma_f32_16x16x32_f16(afr[kc], bf, c4, 0, 0, 0);
        }
        float w0 = W2[col * 3 + 0], w1 = W2[col * 3 + 1], w2 = W2[col * 3 + 2];
        #pragma unroll
        for (int r = 0; r < 4; ++r) {
            float h = fmaxf(c4[r] + ctxW[gidx[r] * HID + col], 0.f);
            po[r][0] += h * w0;
            po[r][1] += h * w1;
            po[r][2] += h * w2;
        }
    }
    #pragma unroll
    for (int m = 1; m < 16; m <<= 1) {
        #pragma unroll
        for (int r = 0; r < 4; ++r) {
            po[r][0] += __shfl_xor(po[r][0], m);
            po[r][1] += __shfl_xor(po[r][1], m);
            po[r][2] += __shfl_xor(po[r][2], m);
        }
    }
    if (lr == 0) {
        #pragma unroll
        for (int r = 0; r < 4; ++r) {
            part[w][kb * 4 + r][0] = po[r][0];
            part[w][kb * 4 + r][1] = po[r][1];
            part[w][kb * 4 + r][2] = po[r][2];
        }
    }
    __syncthreads();
    if (t < 48) {
        int row = t / 3, c = t - row * 3;
        int gr2 = tile + row;
        if (gr2 < N)
            out[(size_t)gr2 * 3 + c] = part[0][row][c] + part[1][row][c] +
                                       part[2][row][c] + part[3][row][c] + b2[c];
    }
}

// ---------------- launch ----------------

extern "C" void kernel_launch(void* const* d_in, const int* in_sizes, int n_in,
                              void* d_out, int out_size, void* d_ws, size_t ws_size,
                              hipStream_t stream) {
    const int*   residue_p = (const int*)d_in[0];
    const float* pos_p     = (const float*)d_in[1];
    const int*   ei_p      = (const int*)d_in[2];
    const int*   batch_p   = (const int*)d_in[3];
    const int*   residue_m = (const int*)d_in[4];
    const float* pos_m     = (const float*)d_in[5];
    const int*   ei_m      = (const int*)d_in[6];
    const int*   batch_m   = (const int*)d_in[7];
    const float* W_p1 = (const float*)d_in[8];
    const float* b_p1 = (const float*)d_in[9];
    const float* W_p2 = (const float*)d_in[10];
    const float* b_p2 = (const float*)d_in[11];
    const float* W_m1 = (const float*)d_in[12];
    const float* b_m1 = (const float*)d_in[13];
    const float* W_m2 = (const float*)d_in[14];
    const float* b_m2 = (const float*)d_in[15];
    const float* W1   = (const float*)d_in[16];
    const float* b1   = (const float*)d_in[17];
    const float* W2   = (const float*)d_in[18];
    const float* b2   = (const float*)d_in[19];

    const int N_P = in_sizes[0];
    const int E_P = in_sizes[2] / 2;
    const int N_M = in_sizes[4];
    const int E_M = in_sizes[6] / 2;
    const int G = 64;
    const int NB_P = (N_P + 63) / 64;
    const int NB_M = (N_M + 63) / 64;
    const int PB = (N_P + 15) / 16;
    const int MB = (N_M + 15) / 16;

    char* ws = (char*)d_ws;
    size_t off = 0;
    auto alloc = [&](size_t bytes) {
        char* p = ws + off;
        off += (bytes + 511) & ~size_t(511);
        return p;
    };
    f16*           y1_p    = (f16*)  alloc((size_t)N_P * HID * 2);
    f16*           y1_m    = (f16*)  alloc((size_t)N_M * HID * 2);
    f16*           x2g     = (f16*)  alloc((size_t)N_M * HID * 2);
    int4*          rec16_p = (int4*) alloc((size_t)N_P * 16);
    int4*          rec16_m = (int4*) alloc((size_t)N_M * 16);
    float*         dinv_p  = (float*)alloc((size_t)N_P * 4);
    float*         dinv_m  = (float*)alloc((size_t)N_M * 4);
    int*           rp_p    = (int*)  alloc((size_t)N_P * 4);
    int*           rp_m    = (int*)  alloc((size_t)N_M * 4);
    int*           re_p    = (int*)  alloc((size_t)N_P * 4);
    int*           re_m    = (int*)  alloc((size_t)N_M * 4);
    int*           bcur_p  = (int*)  alloc((NBMAX + 1) * 4);
    int*           bcur_m  = (int*)  alloc((NBMAX + 1) * 4);
    unsigned int*  prs_p   = (unsigned int*)alloc((size_t)NB_P * CAP * 4);
    unsigned int*  prs_m   = (unsigned int*)alloc((size_t)NB_M * CAP * 4);
    int*           csr_p   = (int*)  alloc((size_t)NB_P * CAP * 4);
    int*           csr_m   = (int*)  alloc((size_t)NB_M * CAP * 4);
    float*         psum    = (float*)alloc((size_t)G * HID * 4);
    int*           pcnt    = (int*)  alloc((size_t)G * 4);
    float*         ctxW    = (float*)alloc((size_t)G * HID * 4);
    f16*           Wp2t    = (f16*)  alloc(128 * 128 * 2);
    f16*           Wm2t    = (f16*)  alloc(128 * 128 * 2);
    f16*           W1at    = (f16*)  alloc(128 * 128 * 2);

    const int TP = (E_P + BIN_T - 1) / BIN_T;
    const int TM = (E_M + BIN_T - 1) / BIN_T;

    // 1. prep (weights, cursor init, graph sizes)
    k_prep_all<<<64, 256, 0, stream>>>(W_p2, W_m2, W1, Wp2t, Wm2t, W1at,
                                       bcur_p, bcur_m, batch_p, pcnt, psum, N_P);
    // 2. binning into padded buckets
    k_tile_bin2<<<TP + TM, 256, 0, stream>>>(ei_p, ei_p + E_P, bcur_p, prs_p, E_P, NB_P, TP,
                                             ei_m, ei_m + E_M, bcur_m, prs_m, E_M, NB_M);
    // 3. fill A: counts -> rowptr/rowend, dinv, rec16, csr scatter
    k_fill_a<<<NB_P + NB_M, 256, 0, stream>>>(
        prs_p, bcur_p, residue_p, pos_p, rec16_p, dinv_p, rp_p, re_p, csr_p, N_P, NB_P,
        prs_m, bcur_m, residue_m, pos_m, rec16_m, dinv_m, rp_m, re_m, csr_m, N_M);
    // 4. layer 1 (both branches)
    k_l1<<<NB_P + NB_M, 256, 0, stream>>>(
        prs_p, bcur_p, rec16_p, W_p1, b_p1, dinv_p, y1_p, N_P, NB_P,
        prs_m, bcur_m, rec16_m, W_m1, b_m1, dinv_m, y1_m, N_M);
    // 5. combined: protein agg+gemm+pool || mm agg+x2
    k_agg_combined<<<PB + MB, 256, 0, stream>>>(
        y1_p, rp_p, re_p, csr_p, dinv_p, Wp2t, b_p2, batch_p, psum, N_P, PB,
        y1_m, rp_m, re_m, csr_m, dinv_m, Wm2t, b_m2, x2g, N_M);
    // 6. ctxW
    k_ctxw_div<<<G, HID, 0, stream>>>(psum, pcnt, W1, b1, ctxW);
    // 7. mm finish: x2 -> h -> out
    k_mm_finish<<<MB, 256, 0, stream>>>(x2g, batch_m, ctxW, W1at, W2, b2,
                                        (float*)d_out, N_M);
}

// Round 18
// 241.069 us; speedup vs baseline: 1.9167x; 1.1198x over previous
//
#include <hip/hip_runtime.h>
#include <hip/hip_bf16.h>
#include <hip/hip_fp16.h>

#define HID 128
#define BIN_T 8192
#define NBMAX 1664   // max 64-node buckets (N <= 106496; src id fits 17 bits)
#define CAP 2560     // padded slots per bucket (mean ~1024, sigma ~32)
#define SIDX 1024    // staged csr span per 16-node tile (mean ~256)

typedef _Float16 f16;
typedef __attribute__((ext_vector_type(2))) _Float16 f16x2;
typedef __attribute__((ext_vector_type(4))) _Float16 f16x4;
typedef __attribute__((ext_vector_type(8))) _Float16 f16x8;
typedef __attribute__((ext_vector_type(4))) float f32x4;

// pairs layout: src[16:0] | res[21:17] | dl[31:26]
// csr entry:   src[16:0] | res[21:17]
// rec8[node]: f16x4 { dinv, dinv*px, dinv*py, dinv*pz }

// ---------------- prep: weight transpose tables, cursor init, graph sizes ----------------

__global__ void k_prep_all(const float* __restrict__ Wp2, const float* __restrict__ Wm2,
                           const float* __restrict__ W1,
                           f16* __restrict__ Wp2t, f16* __restrict__ Wm2t,
                           f16* __restrict__ W1at,
                           int* __restrict__ bcur_p, int* __restrict__ bcur_m,
                           const int* __restrict__ batch_p, int* __restrict__ pcnt,
                           float* __restrict__ psum, int N_P) {
    int idx = blockIdx.x * 256 + threadIdx.x;   // grid 64 -> 16384 threads
    if (idx < 16384) {
        int n = idx & 127, k = idx >> 7;
        Wp2t[n * 128 + k] = (f16)Wp2[k * 128 + n];
        Wm2t[n * 128 + k] = (f16)Wm2[k * 128 + n];
        W1at[n * 128 + k] = (f16)W1[k * 128 + n];
    }
    if (idx <= NBMAX) { bcur_p[idx] = idx * CAP; bcur_m[idx] = idx * CAP; }
    if (idx < 64 * HID) psum[idx] = 0.f;
    if (idx < 64) {
        int g = idx;
        int lo = 0, hi = N_P;
        while (lo < hi) { int mid = (lo + hi) >> 1; if (batch_p[mid] < g) lo = mid + 1; else hi = mid; }
        int a = lo;
        lo = 0; hi = N_P;
        while (lo < hi) { int mid = (lo + hi) >> 1; if (batch_p[mid] < g + 1) lo = mid + 1; else hi = mid; }
        pcnt[g] = lo - a;
    }
}

// ---------------- tile-sorted bucket binning (both branches, padded buckets) ----------------

__global__ void k_tile_bin2(const int* __restrict__ src_p, const int* __restrict__ dst_p,
                            const int* __restrict__ res_p,
                            int* __restrict__ bcur_p, unsigned int* __restrict__ pairs_p,
                            int E_p, int NB_p, int TP,
                            const int* __restrict__ src_m, const int* __restrict__ dst_m,
                            const int* __restrict__ res_m,
                            int* __restrict__ bcur_m, unsigned int* __restrict__ pairs_m,
                            int E_m, int NB_m) {
    __shared__ unsigned int dbuf[BIN_T];
    __shared__ unsigned short perm[BIN_T];
    __shared__ int hist[NBMAX];
    __shared__ int lbase[NBMAX];
    __shared__ int gbase[NBMAX];
    __shared__ int tt[256];
    bool isP = (int)blockIdx.x < TP;
    const int* src = isP ? src_p : src_m;
    const int* dst = isP ? dst_p : dst_m;
    const int* res = isP ? res_p : res_m;
    int* bcursor = isP ? bcur_p : bcur_m;
    unsigned int* pairs = isP ? pairs_p : pairs_m;
    int E = isP ? E_p : E_m;
    int NB = isP ? NB_p : NB_m;
    int tilebase = (isP ? blockIdx.x : blockIdx.x - TP) * BIN_T;
    int t = threadIdx.x;
    int n = min(BIN_T, E - tilebase);
    for (int i = t; i < NB; i += 256) hist[i] = 0;
    __syncthreads();
    for (int i = t; i < n; i += 256) {
        unsigned int d = (unsigned int)dst[tilebase + i];
        dbuf[i] = d;
        atomicAdd(&hist[d >> 6], 1);
    }
    __syncthreads();
    {
        int b0 = t * 7, loc[7], run = 0;
        #pragma unroll
        for (int k = 0; k < 7; ++k) {
            int b = b0 + k;
            int c = (b < NB) ? hist[b] : 0;
            loc[k] = run; run += c;
        }
        tt[t] = run;
        __syncthreads();
        int val = run;
        for (int off = 1; off < 256; off <<= 1) {
            int add = (t >= off) ? tt[t - off] : 0;
            __syncthreads();
            tt[t] += add;
            __syncthreads();
        }
        int ebase = tt[t] - val;
        #pragma unroll
        for (int k = 0; k < 7; ++k) {
            int b = b0 + k;
            if (b < NB) lbase[b] = ebase + loc[k];
        }
    }
    __syncthreads();
    for (int i = t; i < NB; i += 256) {
        int c = hist[i];
        gbase[i] = (c > 0) ? atomicAdd(&bcursor[i], c) : 0;
    }
    __syncthreads();
    for (int i = t; i < NB; i += 256) hist[i] = lbase[i];
    __syncthreads();
    for (int i = t; i < n; i += 256) {
        int b = (int)(dbuf[i] >> 6);
        int p = atomicAdd(&hist[b], 1);
        perm[p] = (unsigned short)i;
    }
    __syncthreads();
    for (int p = t; p < n; p += 256) {
        int li = perm[p];
        unsigned int d = dbuf[li];
        int b = (int)(d >> 6);
        int addr = gbase[b] + (p - lbase[b]);
        int sv = src[tilebase + li];
        pairs[addr] = (unsigned int)sv | ((unsigned int)res[sv] << 17) | ((d & 63u) << 26);
    }
}

// ---------------- fill A (both branches): counts -> rowptr/rowend, dinv, rec8, csr ----------------

__global__ void k_fill_a(
        const unsigned int* __restrict__ pairs_p, const int* __restrict__ bcur_p,
        const float* __restrict__ pos_p,
        f16x4* __restrict__ rec8_p, float* __restrict__ dinv_p,
        int* __restrict__ rowptr_p, int* __restrict__ rowend_p, int* __restrict__ csr_p,
        int N_p, int NB_p,
        const unsigned int* __restrict__ pairs_m, const int* __restrict__ bcur_m,
        const float* __restrict__ pos_m,
        f16x4* __restrict__ rec8_m, float* __restrict__ dinv_m,
        int* __restrict__ rowptr_m, int* __restrict__ rowend_m, int* __restrict__ csr_m,
        int N_m) {
    __shared__ int cnt[64];
    __shared__ int cur[64];
    bool isP = (int)blockIdx.x < NB_p;
    const unsigned int* pairs = isP ? pairs_p : pairs_m;
    const int* bcur = isP ? bcur_p : bcur_m;
    const float* pos = isP ? pos_p : pos_m;
    f16x4* rec8 = isP ? rec8_p : rec8_m;
    float* dinvA = isP ? dinv_p : dinv_m;
    int* rowptr = isP ? rowptr_p : rowptr_m;
    int* rowend = isP ? rowend_p : rowend_m;
    int* csr_src = isP ? csr_p : csr_m;
    int N = isP ? N_p : N_m;
    int b = isP ? blockIdx.x : blockIdx.x - NB_p;
    int t = threadIdx.x, base = b * 64;
    if (t < 64) cnt[t] = 0;
    __syncthreads();
    int lo = b * CAP, hi = bcur[b];
    for (int e = lo + t; e < hi; e += 256)
        atomicAdd(&cnt[pairs[e] >> 26], 1);
    __syncthreads();
    if (t < 64) {
        int off = 0;
        for (int k = 0; k < t; ++k) off += cnt[k];
        int node = base + t;
        if (node < N) {
            rowptr[node] = lo + off;
            rowend[node] = lo + off + cnt[t];
            float d = (float)cnt[t] + 1.0f;   // +1 self loop
            float di = 1.0f / sqrtf(d);
            dinvA[node] = di;
            float px = pos[node * 3 + 0], py = pos[node * 3 + 1], pz = pos[node * 3 + 2];
            f16x4 r;
            r[0] = (f16)di; r[1] = (f16)(di * px); r[2] = (f16)(di * py); r[3] = (f16)(di * pz);
            rec8[node] = r;
        }
        cur[t] = lo + off;
    }
    __syncthreads();
    // second pass (L2-hot): scatter csr entries (src | res<<17), node-sorted
    for (int e = lo + t; e < hi; e += 256) {
        unsigned int pk = pairs[e];
        int slot = atomicAdd(&cur[pk >> 26], 1);
        csr_src[slot] = (int)(pk & 0x3FFFFFu);
    }
}

// ---------------- layer-1 (both branches): node-centric quad agg + GEMM + premult ----------------
// z0_i = dinv_i*(sum_s y0_s + y0_i), y0 = dinv*[onehot,pos]; y1 = dinv*relu(z0@W+b) f16
// 4 threads per node walk csr quarters; pos-slots in regs (quad shfl), 1 LDS atomic/edge.

__global__ __launch_bounds__(256) void k_l1(
        const int* __restrict__ csr_p, const int* __restrict__ rowptr_p,
        const int* __restrict__ rowend_p, const f16x4* __restrict__ rec8_p,
        const int* __restrict__ res_p,
        const float* __restrict__ W_p, const float* __restrict__ bias_p,
        const float* __restrict__ dinv_p, f16* __restrict__ y1_p, int N_p, int NB_p,
        const int* __restrict__ csr_m, const int* __restrict__ rowptr_m,
        const int* __restrict__ rowend_m, const f16x4* __restrict__ rec8_m,
        const int* __restrict__ res_m,
        const float* __restrict__ W_m, const float* __restrict__ bias_m,
        const float* __restrict__ dinv_m, f16* __restrict__ y1_m, int N_m) {
    __shared__ float acc[64][25];
    __shared__ float sdv[64];
    bool isP = (int)blockIdx.x < NB_p;
    const int* csr = isP ? csr_p : csr_m;
    const int* rowptr = isP ? rowptr_p : rowptr_m;
    const int* rowend = isP ? rowend_p : rowend_m;
    const f16x4* rec8 = isP ? rec8_p : rec8_m;
    const int* residue = isP ? res_p : res_m;
    const float* W = isP ? W_p : W_m;
    const float* bias = isP ? bias_p : bias_m;
    const float* dinvA = isP ? dinv_p : dinv_m;
    f16* y1h = isP ? y1_p : y1_m;
    int N = isP ? N_p : N_m;
    int b = isP ? blockIdx.x : blockIdx.x - NB_p;
    int t = threadIdx.x, base = b * 64;
    for (int q2 = t; q2 < 64 * 25; q2 += 256) ((float*)acc)[q2] = 0.f;
    if (t < 64 && base + t < N) sdv[t] = dinvA[base + t];
    int jj = (t & 63) * 2, slot = t >> 6;
    float wreg[23][2];
    #pragma unroll
    for (int k = 0; k < 23; ++k) {
        float2 wv = *(const float2*)&W[k * 128 + jj];
        wreg[k][0] = wv.x; wreg[k][1] = wv.y;
    }
    __syncthreads();
    {
        int nl = t >> 2, q = t & 3;
        int node = base + nl;
        int cn = min(node, N - 1);
        int lb = rowptr[cn], le = rowend[cn];
        float f20 = 0.f, f21 = 0.f, f22 = 0.f;
        int e = lb + q;
        // 2-deep pipelined quad walk
        for (; e + 4 < le; e += 8) {
            unsigned int c0 = (unsigned int)csr[e];
            unsigned int c1 = (unsigned int)csr[e + 4];
            f16x4 r0 = rec8[c0 & 0x1FFFFu];
            f16x4 r1 = rec8[c1 & 0x1FFFFu];
            atomicAdd(&acc[nl][(c0 >> 17) & 31u], (float)r0[0]);
            f20 += (float)r0[1]; f21 += (float)r0[2]; f22 += (float)r0[3];
            atomicAdd(&acc[nl][(c1 >> 17) & 31u], (float)r1[0]);
            f20 += (float)r1[1]; f21 += (float)r1[2]; f22 += (float)r1[3];
        }
        if (e < le) {
            unsigned int c0 = (unsigned int)csr[e];
            f16x4 r0 = rec8[c0 & 0x1FFFFu];
            atomicAdd(&acc[nl][(c0 >> 17) & 31u], (float)r0[0]);
            f20 += (float)r0[1]; f21 += (float)r0[2]; f22 += (float)r0[3];
        }
        f20 += __shfl_xor(f20, 1); f20 += __shfl_xor(f20, 2);
        f21 += __shfl_xor(f21, 1); f21 += __shfl_xor(f21, 2);
        f22 += __shfl_xor(f22, 1); f22 += __shfl_xor(f22, 2);
        if (q == 0 && node < N) {
            acc[nl][20] = f20;   // slots 20-22 untouched by atomics (rs < 20)
            acc[nl][21] = f21;
            acc[nl][22] = f22;
        }
    }
    __syncthreads();
    if (t < 64) {
        int node = base + t;
        if (node < N) {
            f16x4 r = rec8[node];
            acc[t][residue[node]] += (float)r[0];
            acc[t][20] += (float)r[1];
            acc[t][21] += (float)r[2];
            acc[t][22] += (float)r[3];
            float di = sdv[t];
            #pragma unroll
            for (int k = 0; k < 23; ++k) acc[t][k] *= di;
        }
    }
    __syncthreads();
    float bj0 = bias[jj], bj1 = bias[jj + 1];
    for (int r = slot * 16; r < slot * 16 + 16; ++r) {
        int node = base + r;
        if (node >= N) break;
        float a0 = bj0, a1 = bj1;
        #pragma unroll
        for (int k = 0; k < 23; ++k) {
            float zv = acc[r][k];
            a0 += zv * wreg[k][0];
            a1 += zv * wreg[k][1];
        }
        float dv = sdv[r];
        f16x2 o;
        o[0] = (f16)(fmaxf(a0, 0.f) * dv);
        o[1] = (f16)(fmaxf(a1, 0.f) * dv);
        *(f16x2*)&y1h[(size_t)node * HID + jj] = o;
    }
}

// ---------------- wave-per-node agg into 16-row LDS z-tile (f16) ----------------
// csr span staged in LDS when it fits (uniform branch). 4 edges per wave-instr:
// lane (kb=edge-of-4, lr=16B column slice); f32 accum; shfl_xor(16/32) folds kb.

#define AGG16_TO_LDS(zs, sidx, y1h, rowptr, rowend, csr_src, dinvA, N)          \
    {                                                                           \
        int sp0 = rowptr[tile];                                                 \
        int sp1 = rowend[min(tile + 15, N - 1)];                                \
        int slen = sp1 - sp0;                                                   \
        bool staged = slen <= SIDX;                                             \
        if (staged)                                                             \
            for (int i = t; i < slen; i += 256) sidx[i] = csr_src[sp0 + i];     \
        __syncthreads();                                                        \
        const int* idxp = staged ? sidx : (csr_src + sp0);                      \
        for (int i = 0; i < 4; ++i) {                                           \
            int node = tile + w * 4 + i;                                        \
            int cn = min(node, N - 1);                                          \
            int lb = rowptr[cn] - sp0, le = rowend[cn] - sp0;                   \
            float fa[8] = {};                                                   \
            int e = lb;                                                         \
            for (; e + 16 <= le; e += 16) {                                     \
                int i0 = idxp[e + kb] & 0x1FFFF;                                \
                int i1 = idxp[e + 4 + kb] & 0x1FFFF;                            \
                int i2 = idxp[e + 8 + kb] & 0x1FFFF;                            \
                int i3 = idxp[e + 12 + kb] & 0x1FFFF;                           \
                f16x8 v0 = *(const f16x8*)(y1h + (size_t)i0 * HID + lr * 8);    \
                f16x8 v1 = *(const f16x8*)(y1h + (size_t)i1 * HID + lr * 8);    \
                f16x8 v2 = *(const f16x8*)(y1h + (size_t)i2 * HID + lr * 8);    \
                f16x8 v3 = *(const f16x8*)(y1h + (size_t)i3 * HID + lr * 8);    \
                _Pragma("unroll")                                               \
                for (int j = 0; j < 8; ++j)                                     \
                    fa[j] += ((float)v0[j] + (float)v1[j]) +                    \
                             ((float)v2[j] + (float)v3[j]);                     \
            }                                                                   \
            for (; e + 8 <= le; e += 8) {                                       \
                int i0 = idxp[e + kb] & 0x1FFFF;                                \
                int i1 = idxp[e + 4 + kb] & 0x1FFFF;                            \
                f16x8 v0 = *(const f16x8*)(y1h + (size_t)i0 * HID + lr * 8);    \
                f16x8 v1 = *(const f16x8*)(y1h + (size_t)i1 * HID + lr * 8);    \
                _Pragma("unroll")                                               \
                for (int j = 0; j < 8; ++j)                                     \
                    fa[j] += (float)v0[j] + (float)v1[j];                       \
            }                                                                   \
            if (e + 4 <= le) {                                                  \
                int i0 = idxp[e + kb] & 0x1FFFF;                                \
                f16x8 v0 = *(const f16x8*)(y1h + (size_t)i0 * HID + lr * 8);    \
                _Pragma("unroll")                                               \
                for (int j = 0; j < 8; ++j) fa[j] += (float)v0[j];              \
                e += 4;                                                         \
            }                                                                   \
            if (e + kb < le) {                                                  \
                int i0 = idxp[e + kb] & 0x1FFFF;                                \
                f16x8 v0 = *(const f16x8*)(y1h + (size_t)i0 * HID + lr * 8);    \
                _Pragma("unroll")                                               \
                for (int j = 0; j < 8; ++j) fa[j] += (float)v0[j];              \
            }                                                                   \
            _Pragma("unroll")                                                   \
            for (int j = 0; j < 8; ++j) {                                       \
                fa[j] += __shfl_xor(fa[j], 16);                                 \
                fa[j] += __shfl_xor(fa[j], 32);                                 \
            }                                                                   \
            if (kb == 0) {                                                      \
                f16x8 sv = *(const f16x8*)(y1h + (size_t)cn * HID + lr * 8);    \
                float di = dinvA[cn];                                           \
                f16x8 o;                                                        \
                _Pragma("unroll")                                               \
                for (int j = 0; j < 8; ++j)                                     \
                    o[j] = (f16)((fa[j] + (float)sv[j]) * di);                  \
                *(f16x8*)&zs[w * 4 + i][lr * 8] = o;                            \
            }                                                                   \
        }                                                                       \
    }                                                                           \
    __syncthreads();

// ---------------- combined: protein agg+gemm+pool  ||  mm agg+x2-gemm -> x2g ----------------

__global__ __launch_bounds__(256) void k_agg_combined(
        const f16* __restrict__ y1p, const int* __restrict__ rpp, const int* __restrict__ rep,
        const int* __restrict__ csrp, const float* __restrict__ dvp,
        const f16* __restrict__ Wp2t, const float* __restrict__ bp2,
        const int* __restrict__ batchp, float* __restrict__ psum, int Np, int PB,
        const f16* __restrict__ y1m, const int* __restrict__ rpm, const int* __restrict__ rem,
        const int* __restrict__ csrm, const float* __restrict__ dvm,
        const f16* __restrict__ Wm2t, const float* __restrict__ bm2,
        f16* __restrict__ x2g, int Nm) {
    __shared__ __attribute__((aligned(16))) f16 zs[16][136];
    __shared__ int sidx[SIDX];
    int t = threadIdx.x, lane = t & 63, w = t >> 6;
    int lr = lane & 15, kb = lane >> 4;
    bool isP = (int)blockIdx.x < PB;
    if (isP) {
        const f16* y1h = y1p;
        int N = Np;
        int tile = blockIdx.x * 16;
        AGG16_TO_LDS(zs, sidx, y1h, rpp, rep, csrp, dvp, N)
        int g0 = batchp[min(tile, N - 1)];
        bool uni = (tile + 15 < N) && (g0 == batchp[tile + 15]);
        int gr[4]; bool val[4];
        if (!uni) {
            #pragma unroll
            for (int r = 0; r < 4; ++r) {
                int row = tile + kb * 4 + r;
                val[r] = row < N;
                gr[r] = batchp[min(row, N - 1)];
            }
        }
        f16x8 afr[4];
        #pragma unroll
        for (int kc = 0; kc < 4; ++kc)
            afr[kc] = *(const f16x8*)&zs[lr][kc * 32 + kb * 8];
        #pragma unroll
        for (int q = 0; q < 2; ++q) {
            int ct = w * 2 + q;
            f32x4 c4 = {0.f, 0.f, 0.f, 0.f};
            int col = ct * 16 + lr;
            const f16* wp = Wp2t + (size_t)col * HID + kb * 8;
            #pragma unroll
            for (int kc = 0; kc < 4; ++kc) {
                f16x8 bf = *(const f16x8*)(wp + kc * 32);
                c4 = __builtin_amdgcn_mfma_f32_16x16x32_f16(afr[kc], bf, c4, 0, 0, 0);
            }
            float bj = bp2[col];
            if (uni) {
                float ps = 0.f;
                #pragma unroll
                for (int r = 0; r < 4; ++r) ps += fmaxf(c4[r] + bj, 0.f);
                ps += __shfl_xor(ps, 16);
                ps += __shfl_xor(ps, 32);
                if (kb == 0) atomicAdd(&psum[g0 * HID + col], ps);
            } else {
                #pragma unroll
                for (int r = 0; r < 4; ++r)
                    if (val[r]) atomicAdd(&psum[gr[r] * HID + col], fmaxf(c4[r] + bj, 0.f));
            }
        }
    } else {
        const f16* y1h = y1m;
        int N = Nm;
        int tile = (blockIdx.x - PB) * 16;
        AGG16_TO_LDS(zs, sidx, y1h, rpm, rem, csrm, dvm, N)
        f16x8 afr[4];
        #pragma unroll
        for (int kc = 0; kc < 4; ++kc)
            afr[kc] = *(const f16x8*)&zs[lr][kc * 32 + kb * 8];
        __syncthreads();
        #pragma unroll
        for (int q = 0; q < 2; ++q) {
            int ct = w * 2 + q;
            f32x4 c4 = {0.f, 0.f, 0.f, 0.f};
            int col = ct * 16 + lr;
            const f16* wp = Wm2t + (size_t)col * HID + kb * 8;
            #pragma unroll
            for (int kc = 0; kc < 4; ++kc) {
                f16x8 bf = *(const f16x8*)(wp + kc * 32);
                c4 = __builtin_amdgcn_mfma_f32_16x16x32_f16(afr[kc], bf, c4, 0, 0, 0);
            }
            float bj = bm2[col];
            #pragma unroll
            for (int r = 0; r < 4; ++r)
                zs[kb * 4 + r][col] = (f16)fmaxf(c4[r] + bj, 0.f);
        }
        __syncthreads();
        // coalesced copy out: 16 rows x 128 f16
        int row = t >> 4, c8 = (t & 15) * 8;
        if (tile + row < N)
            *(f16x8*)&x2g[(size_t)(tile + row) * HID + c8] = *(const f16x8*)&zs[row][c8];
    }
}

// ctxW[g] = (psum[g]/cnt[g]) @ W1[128:,:] + b1
__global__ void k_ctxw_div(const float* __restrict__ psum, const int* __restrict__ pcnt,
                           const float* __restrict__ W1, const float* __restrict__ b1,
                           float* __restrict__ ctxW) {
    __shared__ float pr[128];
    int g = blockIdx.x, j = threadIdx.x;
    pr[j] = psum[g * HID + j] / fmaxf((float)pcnt[g], 1.f);
    __syncthreads();
    float a = b1[j];
    #pragma unroll 4
    for (int k = 0; k < HID; ++k) a += pr[k] * W1[(HID + k) * HID + j];
    ctxW[g * HID + j] = a;
}

// mm finish: h = relu(x2 @ W1a + ctxW[batch]); out = h @ W2 + b2
__global__ __launch_bounds__(256) void k_mm_finish(
        const f16* __restrict__ x2g, const int* __restrict__ batch,
        const float* __restrict__ ctxW, const f16* __restrict__ W1at,
        const float* __restrict__ W2, const float* __restrict__ b2,
        float* __restrict__ out, int N) {
    __shared__ float part[4][16][3];
    int tile = blockIdx.x * 16;
    int t = threadIdx.x, lane = t & 63, w = t >> 6;
    int lr = lane & 15, kb = lane >> 4;
    int cr = min(tile + lr, N - 1);
    f16x8 afr[4];
    #pragma unroll
    for (int kc = 0; kc < 4; ++kc)
        afr[kc] = *(const f16x8*)&x2g[(size_t)cr * HID + kc * 32 + kb * 8];
    int gidx[4];
    #pragma unroll
    for (int r = 0; r < 4; ++r)
        gidx[r] = batch[min(tile + kb * 4 + r, N - 1)];
    float po[4][3] = {};
    #pragma unroll
    for (int q = 0; q < 2; ++q) {
        int ct = w * 2 + q;
        f32x4 c4 = {0.f, 0.f, 0.f, 0.f};
        int col = ct * 16 + lr;
        const f16* wp = W1at + (size_t)col * HID + kb * 8;
        #pragma unroll
        for (int kc = 0; kc < 4; ++kc) {
            f16x8 bf = *(const f16x8*)(wp + kc * 32);
            c4 = __builtin_amdgcn_mfma_f32_16x16x32_f16(afr[kc], bf, c4, 0, 0, 0);
        }
        float w0 = W2[col * 3 + 0], w1 = W2[col * 3 + 1], w2 = W2[col * 3 + 2];
        #pragma unroll
        for (int r = 0; r < 4; ++r) {
            float h = fmaxf(c4[r] + ctxW[gidx[r] * HID + col], 0.f);
            po[r][0] += h * w0;
            po[r][1] += h * w1;
            po[r][2] += h * w2;
        }
    }
    #pragma unroll
    for (int m = 1; m < 16; m <<= 1) {
        #pragma unroll
        for (int r = 0; r < 4; ++r) {
            po[r][0] += __shfl_xor(po[r][0], m);
            po[r][1] += __shfl_xor(po[r][1], m);
            po[r][2] += __shfl_xor(po[r][2], m);
        }
    }
    if (lr == 0) {
        #pragma unroll
        for (int r = 0; r < 4; ++r) {
            part[w][kb * 4 + r][0] = po[r][0];
            part[w][kb * 4 + r][1] = po[r][1];
            part[w][kb * 4 + r][2] = po[r][2];
        }
    }
    __syncthreads();
    if (t < 48) {
        int row = t / 3, c = t - row * 3;
        int gr2 = tile + row;
        if (gr2 < N)
            out[(size_t)gr2 * 3 + c] = part[0][row][c] + part[1][row][c] +
                                       part[2][row][c] + part[3][row][c] + b2[c];
    }
}

// ---------------- launch ----------------

extern "C" void kernel_launch(void* const* d_in, const int* in_sizes, int n_in,
                              void* d_out, int out_size, void* d_ws, size_t ws_size,
                              hipStream_t stream) {
    const int*   residue_p = (const int*)d_in[0];
    const float* pos_p     = (const float*)d_in[1];
    const int*   ei_p      = (const int*)d_in[2];
    const int*   batch_p   = (const int*)d_in[3];
    const int*   residue_m = (const int*)d_in[4];
    const float* pos_m     = (const float*)d_in[5];
    const int*   ei_m      = (const int*)d_in[6];
    const int*   batch_m   = (const int*)d_in[7];
    const float* W_p1 = (const float*)d_in[8];
    const float* b_p1 = (const float*)d_in[9];
    const float* W_p2 = (const float*)d_in[10];
    const float* b_p2 = (const float*)d_in[11];
    const float* W_m1 = (const float*)d_in[12];
    const float* b_m1 = (const float*)d_in[13];
    const float* W_m2 = (const float*)d_in[14];
    const float* b_m2 = (const float*)d_in[15];
    const float* W1   = (const float*)d_in[16];
    const float* b1   = (const float*)d_in[17];
    const float* W2   = (const float*)d_in[18];
    const float* b2   = (const float*)d_in[19];

    const int N_P = in_sizes[0];
    const int E_P = in_sizes[2] / 2;
    const int N_M = in_sizes[4];
    const int E_M = in_sizes[6] / 2;
    const int G = 64;
    const int NB_P = (N_P + 63) / 64;
    const int NB_M = (N_M + 63) / 64;
    const int PB = (N_P + 15) / 16;
    const int MB = (N_M + 15) / 16;

    char* ws = (char*)d_ws;
    size_t off = 0;
    auto alloc = [&](size_t bytes) {
        char* p = ws + off;
        off += (bytes + 511) & ~size_t(511);
        return p;
    };
    f16*           y1_p   = (f16*)  alloc((size_t)N_P * HID * 2);
    f16*           y1_m   = (f16*)  alloc((size_t)N_M * HID * 2);
    f16*           x2g    = (f16*)  alloc((size_t)N_M * HID * 2);
    f16x4*         rec8_p = (f16x4*)alloc((size_t)N_P * 8);
    f16x4*         rec8_m = (f16x4*)alloc((size_t)N_M * 8);
    float*         dinv_p = (float*)alloc((size_t)N_P * 4);
    float*         dinv_m = (float*)alloc((size_t)N_M * 4);
    int*           rp_p   = (int*)  alloc((size_t)N_P * 4);
    int*           rp_m   = (int*)  alloc((size_t)N_M * 4);
    int*           re_p   = (int*)  alloc((size_t)N_P * 4);
    int*           re_m   = (int*)  alloc((size_t)N_M * 4);
    int*           bcur_p = (int*)  alloc((NBMAX + 1) * 4);
    int*           bcur_m = (int*)  alloc((NBMAX + 1) * 4);
    unsigned int*  prs_p  = (unsigned int*)alloc((size_t)NB_P * CAP * 4);
    unsigned int*  prs_m  = (unsigned int*)alloc((size_t)NB_M * CAP * 4);
    int*           csr_p  = (int*)  alloc((size_t)NB_P * CAP * 4);
    int*           csr_m  = (int*)  alloc((size_t)NB_M * CAP * 4);
    float*         psum   = (float*)alloc((size_t)G * HID * 4);
    int*           pcnt   = (int*)  alloc((size_t)G * 4);
    float*         ctxW   = (float*)alloc((size_t)G * HID * 4);
    f16*           Wp2t   = (f16*)  alloc(128 * 128 * 2);
    f16*           Wm2t   = (f16*)  alloc(128 * 128 * 2);
    f16*           W1at   = (f16*)  alloc(128 * 128 * 2);

    const int TP = (E_P + BIN_T - 1) / BIN_T;
    const int TM = (E_M + BIN_T - 1) / BIN_T;

    // 1. prep (weights, cursor init, graph sizes)
    k_prep_all<<<64, 256, 0, stream>>>(W_p2, W_m2, W1, Wp2t, Wm2t, W1at,
                                       bcur_p, bcur_m, batch_p, pcnt, psum, N_P);
    // 2. binning into padded buckets (res packed into pairs bits 17..21)
    k_tile_bin2<<<TP + TM, 256, 0, stream>>>(ei_p, ei_p + E_P, residue_p, bcur_p, prs_p,
                                             E_P, NB_P, TP,
                                             ei_m, ei_m + E_M, residue_m, bcur_m, prs_m,
                                             E_M, NB_M);
    // 3. fill A: counts -> rowptr/rowend, dinv, rec8, csr scatter
    k_fill_a<<<NB_P + NB_M, 256, 0, stream>>>(
        prs_p, bcur_p, pos_p, rec8_p, dinv_p, rp_p, re_p, csr_p, N_P, NB_P,
        prs_m, bcur_m, pos_m, rec8_m, dinv_m, rp_m, re_m, csr_m, N_M);
    // 4. layer 1 (both branches, node-centric)
    k_l1<<<NB_P + NB_M, 256, 0, stream>>>(
        csr_p, rp_p, re_p, rec8_p, residue_p, W_p1, b_p1, dinv_p, y1_p, N_P, NB_P,
        csr_m, rp_m, re_m, rec8_m, residue_m, W_m1, b_m1, dinv_m, y1_m, N_M);
    // 5. combined: protein agg+gemm+pool || mm agg+x2
    k_agg_combined<<<PB + MB, 256, 0, stream>>>(
        y1_p, rp_p, re_p, csr_p, dinv_p, Wp2t, b_p2, batch_p, psum, N_P, PB,
        y1_m, rp_m, re_m, csr_m, dinv_m, Wm2t, b_m2, x2g, N_M);
    // 6. ctxW
    k_ctxw_div<<<G, HID, 0, stream>>>(psum, pcnt, W1, b1, ctxW);
    // 7. mm finish: x2 -> h -> out
    k_mm_finish<<<MB, 256, 0, stream>>>(x2g, batch_m, ctxW, W1at, W2, b2,
                                        (float*)d_out, N_M);
}

// Round 20
// 240.920 us; speedup vs baseline: 1.9179x; 1.0006x over previous
//
#include <hip/hip_runtime.h>
#include <hip/hip_bf16.h>
#include <hip/hip_fp16.h>

#define HID 128
#define BIN_T 8192
#define NBMAX 1664   // max 64-node buckets (N <= 106496; src id fits 17 bits)
#define CAP 2560     // padded slots per bucket (mean ~1024, sigma ~32)
#define SIDX 1024    // staged csr span per 16-node tile (mean ~256)

typedef _Float16 f16;
typedef __attribute__((ext_vector_type(2))) _Float16 f16x2;
typedef __attribute__((ext_vector_type(4))) _Float16 f16x4;
typedef __attribute__((ext_vector_type(8))) _Float16 f16x8;
typedef __attribute__((ext_vector_type(4))) float f32x4;

// pairs layout: src[16:0] | res[21:17] | dl[31:26]
// csr entry:   src[16:0] | res[21:17]
// rec8[node]: f16x4 { dinv, dinv*px, dinv*py, dinv*pz }

// ---------------- prep: weight transpose tables, cursor init, graph sizes ----------------

__global__ void k_prep_all(const float* __restrict__ Wp2, const float* __restrict__ Wm2,
                           const float* __restrict__ W1,
                           f16* __restrict__ Wp2t, f16* __restrict__ Wm2t,
                           f16* __restrict__ W1at,
                           int* __restrict__ bcur_p, int* __restrict__ bcur_m,
                           const int* __restrict__ batch_p, int* __restrict__ pcnt,
                           float* __restrict__ psum, int N_P) {
    int idx = blockIdx.x * 256 + threadIdx.x;   // grid 64 -> 16384 threads
    if (idx < 16384) {
        int n = idx & 127, k = idx >> 7;
        Wp2t[n * 128 + k] = (f16)Wp2[k * 128 + n];
        Wm2t[n * 128 + k] = (f16)Wm2[k * 128 + n];
        W1at[n * 128 + k] = (f16)W1[k * 128 + n];
    }
    if (idx <= NBMAX) { bcur_p[idx] = idx * CAP; bcur_m[idx] = idx * CAP; }
    if (idx < 64 * HID) psum[idx] = 0.f;
    if (idx < 64) {
        int g = idx;
        int lo = 0, hi = N_P;
        while (lo < hi) { int mid = (lo + hi) >> 1; if (batch_p[mid] < g) lo = mid + 1; else hi = mid; }
        int a = lo;
        lo = 0; hi = N_P;
        while (lo < hi) { int mid = (lo + hi) >> 1; if (batch_p[mid] < g + 1) lo = mid + 1; else hi = mid; }
        pcnt[g] = lo - a;
    }
}

// ---------------- tile-sorted bucket binning (both branches, padded buckets) ----------------

__global__ void k_tile_bin2(const int* __restrict__ src_p, const int* __restrict__ dst_p,
                            const int* __restrict__ res_p,
                            int* __restrict__ bcur_p, unsigned int* __restrict__ pairs_p,
                            int E_p, int NB_p, int TP,
                            const int* __restrict__ src_m, const int* __restrict__ dst_m,
                            const int* __restrict__ res_m,
                            int* __restrict__ bcur_m, unsigned int* __restrict__ pairs_m,
                            int E_m, int NB_m) {
    __shared__ unsigned int dbuf[BIN_T];
    __shared__ unsigned short perm[BIN_T];
    __shared__ int hist[NBMAX];
    __shared__ int lbase[NBMAX];
    __shared__ int gbase[NBMAX];
    __shared__ int tt[256];
    bool isP = (int)blockIdx.x < TP;
    const int* src = isP ? src_p : src_m;
    const int* dst = isP ? dst_p : dst_m;
    const int* res = isP ? res_p : res_m;
    int* bcursor = isP ? bcur_p : bcur_m;
    unsigned int* pairs = isP ? pairs_p : pairs_m;
    int E = isP ? E_p : E_m;
    int NB = isP ? NB_p : NB_m;
    int tilebase = (isP ? blockIdx.x : blockIdx.x - TP) * BIN_T;
    int t = threadIdx.x;
    int n = min(BIN_T, E - tilebase);
    for (int i = t; i < NB; i += 256) hist[i] = 0;
    __syncthreads();
    for (int i = t; i < n; i += 256) {
        unsigned int d = (unsigned int)dst[tilebase + i];
        dbuf[i] = d;
        atomicAdd(&hist[d >> 6], 1);
    }
    __syncthreads();
    {
        int b0 = t * 7, loc[7], run = 0;
        #pragma unroll
        for (int k = 0; k < 7; ++k) {
            int b = b0 + k;
            int c = (b < NB) ? hist[b] : 0;
            loc[k] = run; run += c;
        }
        tt[t] = run;
        __syncthreads();
        int val = run;
        for (int off = 1; off < 256; off <<= 1) {
            int add = (t >= off) ? tt[t - off] : 0;
            __syncthreads();
            tt[t] += add;
            __syncthreads();
        }
        int ebase = tt[t] - val;
        #pragma unroll
        for (int k = 0; k < 7; ++k) {
            int b = b0 + k;
            if (b < NB) lbase[b] = ebase + loc[k];
        }
    }
    __syncthreads();
    for (int i = t; i < NB; i += 256) {
        int c = hist[i];
        gbase[i] = (c > 0) ? atomicAdd(&bcursor[i], c) : 0;
    }
    __syncthreads();
    for (int i = t; i < NB; i += 256) hist[i] = lbase[i];
    __syncthreads();
    for (int i = t; i < n; i += 256) {
        int b = (int)(dbuf[i] >> 6);
        int p = atomicAdd(&hist[b], 1);
        perm[p] = (unsigned short)i;
    }
    __syncthreads();
    for (int p = t; p < n; p += 256) {
        int li = perm[p];
        unsigned int d = dbuf[li];
        int b = (int)(d >> 6);
        int addr = gbase[b] + (p - lbase[b]);
        int sv = src[tilebase + li];
        pairs[addr] = (unsigned int)sv | ((unsigned int)res[sv] << 17) | ((d & 63u) << 26);
    }
}

// ---------------- fill A (both branches): counts -> rowptr/rowend, dinv, rec8, csr ----------------

__global__ void k_fill_a(
        const unsigned int* __restrict__ pairs_p, const int* __restrict__ bcur_p,
        const float* __restrict__ pos_p,
        f16x4* __restrict__ rec8_p, float* __restrict__ dinv_p,
        int* __restrict__ rowptr_p, int* __restrict__ rowend_p, int* __restrict__ csr_p,
        int N_p, int NB_p,
        const unsigned int* __restrict__ pairs_m, const int* __restrict__ bcur_m,
        const float* __restrict__ pos_m,
        f16x4* __restrict__ rec8_m, float* __restrict__ dinv_m,
        int* __restrict__ rowptr_m, int* __restrict__ rowend_m, int* __restrict__ csr_m,
        int N_m) {
    __shared__ int cnt[64];
    __shared__ int cur[64];
    bool isP = (int)blockIdx.x < NB_p;
    const unsigned int* pairs = isP ? pairs_p : pairs_m;
    const int* bcur = isP ? bcur_p : bcur_m;
    const float* pos = isP ? pos_p : pos_m;
    f16x4* rec8 = isP ? rec8_p : rec8_m;
    float* dinvA = isP ? dinv_p : dinv_m;
    int* rowptr = isP ? rowptr_p : rowptr_m;
    int* rowend = isP ? rowend_p : rowend_m;
    int* csr_src = isP ? csr_p : csr_m;
    int N = isP ? N_p : N_m;
    int b = isP ? blockIdx.x : blockIdx.x - NB_p;
    int t = threadIdx.x, base = b * 64;
    if (t < 64) cnt[t] = 0;
    __syncthreads();
    int lo = b * CAP, hi = bcur[b];
    for (int e = lo + t; e < hi; e += 256)
        atomicAdd(&cnt[pairs[e] >> 26], 1);
    __syncthreads();
    if (t < 64) {
        int off = 0;
        for (int k = 0; k < t; ++k) off += cnt[k];
        int node = base + t;
        if (node < N) {
            rowptr[node] = lo + off;
            rowend[node] = lo + off + cnt[t];
            float d = (float)cnt[t] + 1.0f;   // +1 self loop
            float di = 1.0f / sqrtf(d);
            dinvA[node] = di;
            float px = pos[node * 3 + 0], py = pos[node * 3 + 1], pz = pos[node * 3 + 2];
            f16x4 r;
            r[0] = (f16)di; r[1] = (f16)(di * px); r[2] = (f16)(di * py); r[3] = (f16)(di * pz);
            rec8[node] = r;
        }
        cur[t] = lo + off;
    }
    __syncthreads();
    // second pass (L2-hot): scatter csr entries (src | res<<17), node-sorted
    for (int e = lo + t; e < hi; e += 256) {
        unsigned int pk = pairs[e];
        int slot = atomicAdd(&cur[pk >> 26], 1);
        csr_src[slot] = (int)(pk & 0x3FFFFFu);
    }
}

// ---------------- layer-1 (both branches): node-centric quad agg + GEMM + premult ----------------
// z0_i = dinv_i*(sum_s y0_s + y0_i), y0 = dinv*[onehot,pos]; y1 = dinv*relu(z0@W+b) f16
// 4 threads per node walk csr quarters; pos-slots in regs (quad shfl), 1 LDS atomic/edge.

__global__ __launch_bounds__(256) void k_l1(
        const int* __restrict__ csr_p, const int* __restrict__ rowptr_p,
        const int* __restrict__ rowend_p, const f16x4* __restrict__ rec8_p,
        const int* __restrict__ res_p,
        const float* __restrict__ W_p, const float* __restrict__ bias_p,
        const float* __restrict__ dinv_p, f16* __restrict__ y1_p, int N_p, int NB_p,
        const int* __restrict__ csr_m, const int* __restrict__ rowptr_m,
        const int* __restrict__ rowend_m, const f16x4* __restrict__ rec8_m,
        const int* __restrict__ res_m,
        const float* __restrict__ W_m, const float* __restrict__ bias_m,
        const float* __restrict__ dinv_m, f16* __restrict__ y1_m, int N_m) {
    __shared__ float acc[64][25];
    __shared__ float sdv[64];
    bool isP = (int)blockIdx.x < NB_p;
    const int* csr = isP ? csr_p : csr_m;
    const int* rowptr = isP ? rowptr_p : rowptr_m;
    const int* rowend = isP ? rowend_p : rowend_m;
    const f16x4* rec8 = isP ? rec8_p : rec8_m;
    const int* residue = isP ? res_p : res_m;
    const float* W = isP ? W_p : W_m;
    const float* bias = isP ? bias_p : bias_m;
    const float* dinvA = isP ? dinv_p : dinv_m;
    f16* y1h = isP ? y1_p : y1_m;
    int N = isP ? N_p : N_m;
    int b = isP ? blockIdx.x : blockIdx.x - NB_p;
    int t = threadIdx.x, base = b * 64;
    for (int q2 = t; q2 < 64 * 25; q2 += 256) ((float*)acc)[q2] = 0.f;
    if (t < 64 && base + t < N) sdv[t] = dinvA[base + t];
    int jj = (t & 63) * 2, slot = t >> 6;
    float wreg[23][2];
    #pragma unroll
    for (int k = 0; k < 23; ++k) {
        float2 wv = *(const float2*)&W[k * 128 + jj];
        wreg[k][0] = wv.x; wreg[k][1] = wv.y;
    }
    __syncthreads();
    {
        int nl = t >> 2, q = t & 3;
        int node = base + nl;
        int cn = min(node, N - 1);
        int lb = rowptr[cn], le = rowend[cn];
        float f20 = 0.f, f21 = 0.f, f22 = 0.f;
        int e = lb + q;
        // 2-deep pipelined quad walk
        for (; e + 4 < le; e += 8) {
            unsigned int c0 = (unsigned int)csr[e];
            unsigned int c1 = (unsigned int)csr[e + 4];
            f16x4 r0 = rec8[c0 & 0x1FFFFu];
            f16x4 r1 = rec8[c1 & 0x1FFFFu];
            atomicAdd(&acc[nl][(c0 >> 17) & 31u], (float)r0[0]);
            f20 += (float)r0[1]; f21 += (float)r0[2]; f22 += (float)r0[3];
            atomicAdd(&acc[nl][(c1 >> 17) & 31u], (float)r1[0]);
            f20 += (float)r1[1]; f21 += (float)r1[2]; f22 += (float)r1[3];
        }
        if (e < le) {
            unsigned int c0 = (unsigned int)csr[e];
            f16x4 r0 = rec8[c0 & 0x1FFFFu];
            atomicAdd(&acc[nl][(c0 >> 17) & 31u], (float)r0[0]);
            f20 += (float)r0[1]; f21 += (float)r0[2]; f22 += (float)r0[3];
        }
        f20 += __shfl_xor(f20, 1); f20 += __shfl_xor(f20, 2);
        f21 += __shfl_xor(f21, 1); f21 += __shfl_xor(f21, 2);
        f22 += __shfl_xor(f22, 1); f22 += __shfl_xor(f22, 2);
        if (q == 0 && node < N) {
            acc[nl][20] = f20;   // slots 20-22 untouched by atomics (rs < 20)
            acc[nl][21] = f21;
            acc[nl][22] = f22;
        }
    }
    __syncthreads();
    if (t < 64) {
        int node = base + t;
        if (node < N) {
            f16x4 r = rec8[node];
            acc[t][residue[node]] += (float)r[0];
            acc[t][20] += (float)r[1];
            acc[t][21] += (float)r[2];
            acc[t][22] += (float)r[3];
            float di = sdv[t];
            #pragma unroll
            for (int k = 0; k < 23; ++k) acc[t][k] *= di;
        }
    }
    __syncthreads();
    float bj0 = bias[jj], bj1 = bias[jj + 1];
    for (int r = slot * 16; r < slot * 16 + 16; ++r) {
        int node = base + r;
        if (node >= N) break;
        float a0 = bj0, a1 = bj1;
        #pragma unroll
        for (int k = 0; k < 23; ++k) {
            float zv = acc[r][k];
            a0 += zv * wreg[k][0];
            a1 += zv * wreg[k][1];
        }
        float dv = sdv[r];
        f16x2 o;
        o[0] = (f16)(fmaxf(a0, 0.f) * dv);
        o[1] = (f16)(fmaxf(a1, 0.f) * dv);
        *(f16x2*)&y1h[(size_t)node * HID + jj] = o;
    }
}

// ---------------- wave-per-node agg into 16-row LDS z-tile (f16) ----------------
// csr span staged in LDS when it fits (uniform branch). 4 edges per wave-instr:
// lane (kb=edge-of-4, lr=16B column slice); f32 accum; shfl_xor(16/32) folds kb.

#define AGG16_TO_LDS(zs, sidx, y1h, rowptr, rowend, csr_src, dinvA, N)          \
    {                                                                           \
        int sp0 = rowptr[tile];                                                 \
        int sp1 = rowend[min(tile + 15, N - 1)];                                \
        int slen = sp1 - sp0;                                                   \
        bool staged = slen <= SIDX;                                             \
        if (staged)                                                             \
            for (int i = t; i < slen; i += 256) sidx[i] = csr_src[sp0 + i];     \
        __syncthreads();                                                        \
        const int* idxp = staged ? sidx : (csr_src + sp0);                      \
        for (int i = 0; i < 4; ++i) {                                           \
            int node = tile + w * 4 + i;                                        \
            int cn = min(node, N - 1);                                          \
            int lb = rowptr[cn] - sp0, le = rowend[cn] - sp0;                   \
            float fa[8] = {};                                                   \
            int e = lb;                                                         \
            for (; e + 16 <= le; e += 16) {                                     \
                int i0 = idxp[e + kb] & 0x1FFFF;                                \
                int i1 = idxp[e + 4 + kb] & 0x1FFFF;                            \
                int i2 = idxp[e + 8 + kb] & 0x1FFFF;                            \
                int i3 = idxp[e + 12 + kb] & 0x1FFFF;                           \
                f16x8 v0 = *(const f16x8*)(y1h + (size_t)i0 * HID + lr * 8);    \
                f16x8 v1 = *(const f16x8*)(y1h + (size_t)i1 * HID + lr * 8);    \
                f16x8 v2 = *(const f16x8*)(y1h + (size_t)i2 * HID + lr * 8);    \
                f16x8 v3 = *(const f16x8*)(y1h + (size_t)i3 * HID + lr * 8);    \
                _Pragma("unroll")                                               \
                for (int j = 0; j < 8; ++j)                                     \
                    fa[j] += ((float)v0[j] + (float)v1[j]) +                    \
                             ((float)v2[j] + (float)v3[j]);                     \
            }                                                                   \
            for (; e + 8 <= le; e += 8) {                                       \
                int i0 = idxp[e + kb] & 0x1FFFF;                                \
                int i1 = idxp[e + 4 + kb] & 0x1FFFF;                            \
                f16x8 v0 = *(const f16x8*)(y1h + (size_t)i0 * HID + lr * 8);    \
                f16x8 v1 = *(const f16x8*)(y1h + (size_t)i1 * HID + lr * 8);    \
                _Pragma("unroll")                                               \
                for (int j = 0; j < 8; ++j)                                     \
                    fa[j] += (float)v0[j] + (float)v1[j];                       \
            }                                                                   \
            if (e + 4 <= le) {                                                  \
                int i0 = idxp[e + kb] & 0x1FFFF;                                \
                f16x8 v0 = *(const f16x8*)(y1h + (size_t)i0 * HID + lr * 8);    \
                _Pragma("unroll")                                               \
                for (int j = 0; j < 8; ++j) fa[j] += (float)v0[j];              \
                e += 4;                                                         \
            }                                                                   \
            if (e + kb < le) {                                                  \
                int i0 = idxp[e + kb] & 0x1FFFF;                                \
                f16x8 v0 = *(const f16x8*)(y1h + (size_t)i0 * HID + lr * 8);    \
                _Pragma("unroll")                                               \
                for (int j = 0; j < 8; ++j) fa[j] += (float)v0[j];              \
            }                                                                   \
            _Pragma("unroll")                                                   \
            for (int j = 0; j < 8; ++j) {                                       \
                fa[j] += __shfl_xor(fa[j], 16);                                 \
                fa[j] += __shfl_xor(fa[j], 32);                                 \
            }                                                                   \
            if (kb == 0) {                                                      \
                f16x8 sv = *(const f16x8*)(y1h + (size_t)cn * HID + lr * 8);    \
                float di = dinvA[cn];                                           \
                f16x8 o;                                                        \
                _Pragma("unroll")                                               \
                for (int j = 0; j < 8; ++j)                                     \
                    o[j] = (f16)((fa[j] + (float)sv[j]) * di);                  \
                *(f16x8*)&zs[w * 4 + i][lr * 8] = o;                            \
            }                                                                   \
        }                                                                       \
    }                                                                           \
    __syncthreads();

// ---------------- combined: protein agg+gemm+pool  ||  mm agg+x2-gemm -> x2g ----------------

__global__ __launch_bounds__(256) void k_agg_combined(
        const f16* __restrict__ y1p, const int* __restrict__ rpp, const int* __restrict__ rep,
        const int* __restrict__ csrp, const float* __restrict__ dvp,
        const f16* __restrict__ Wp2t, const float* __restrict__ bp2,
        const int* __restrict__ batchp, float* __restrict__ psum, int Np, int PB,
        const f16* __restrict__ y1m, const int* __restrict__ rpm, const int* __restrict__ rem,
        const int* __restrict__ csrm, const float* __restrict__ dvm,
        const f16* __restrict__ Wm2t, const float* __restrict__ bm2,
        f16* __restrict__ x2g, int Nm) {
    __shared__ __attribute__((aligned(16))) f16 zs[16][136];
    __shared__ int sidx[SIDX];
    int t = threadIdx.x, lane = t & 63, w = t >> 6;
    int lr = lane & 15, kb = lane >> 4;
    bool isP = (int)blockIdx.x < PB;
    if (isP) {
        const f16* y1h = y1p;
        int N = Np;
        int tile = blockIdx.x * 16;
        AGG16_TO_LDS(zs, sidx, y1h, rpp, rep, csrp, dvp, N)
        int g0 = batchp[min(tile, N - 1)];
        bool uni = (tile + 15 < N) && (g0 == batchp[tile + 15]);
        int gr[4]; bool val[4];
        if (!uni) {
            #pragma unroll
            for (int r = 0; r < 4; ++r) {
                int row = tile + kb * 4 + r;
                val[r] = row < N;
                gr[r] = batchp[min(row, N - 1)];
            }
        }
        f16x8 afr[4];
        #pragma unroll
        for (int kc = 0; kc < 4; ++kc)
            afr[kc] = *(const f16x8*)&zs[lr][kc * 32 + kb * 8];
        #pragma unroll
        for (int q = 0; q < 2; ++q) {
            int ct = w * 2 + q;
            f32x4 c4 = {0.f, 0.f, 0.f, 0.f};
            int col = ct * 16 + lr;
            const f16* wp = Wp2t + (size_t)col * HID + kb * 8;
            #pragma unroll
            for (int kc = 0; kc < 4; ++kc) {
                f16x8 bf = *(const f16x8*)(wp + kc * 32);
                c4 = __builtin_amdgcn_mfma_f32_16x16x32_f16(afr[kc], bf, c4, 0, 0, 0);
            }
            float bj = bp2[col];
            if (uni) {
                float ps = 0.f;
                #pragma unroll
                for (int r = 0; r < 4; ++r) ps += fmaxf(c4[r] + bj, 0.f);
                ps += __shfl_xor(ps, 16);
                ps += __shfl_xor(ps, 32);
                if (kb == 0) atomicAdd(&psum[g0 * HID + col], ps);
            } else {
                #pragma unroll
                for (int r = 0; r < 4; ++r)
                    if (val[r]) atomicAdd(&psum[gr[r] * HID + col], fmaxf(c4[r] + bj, 0.f));
            }
        }
    } else {
        const f16* y1h = y1m;
        int N = Nm;
        int tile = (blockIdx.x - PB) * 16;
        AGG16_TO_LDS(zs, sidx, y1h, rpm, rem, csrm, dvm, N)
        f16x8 afr[4];
        #pragma unroll
        for (int kc = 0; kc < 4; ++kc)
            afr[kc] = *(const f16x8*)&zs[lr][kc * 32 + kb * 8];
        __syncthreads();
        #pragma unroll
        for (int q = 0; q < 2; ++q) {
            int ct = w * 2 + q;
            f32x4 c4 = {0.f, 0.f, 0.f, 0.f};
            int col = ct * 16 + lr;
            const f16* wp = Wm2t + (size_t)col * HID + kb * 8;
            #pragma unroll
            for (int kc = 0; kc < 4; ++kc) {
                f16x8 bf = *(const f16x8*)(wp + kc * 32);
                c4 = __builtin_amdgcn_mfma_f32_16x16x32_f16(afr[kc], bf, c4, 0, 0, 0);
            }
            float bj = bm2[col];
            #pragma unroll
            for (int r = 0; r < 4; ++r)
                zs[kb * 4 + r][col] = (f16)fmaxf(c4[r] + bj, 0.f);
        }
        __syncthreads();
        // coalesced copy out: 16 rows x 128 f16
        int row = t >> 4, c8 = (t & 15) * 8;
        if (tile + row < N)
            *(f16x8*)&x2g[(size_t)(tile + row) * HID + c8] = *(const f16x8*)&zs[row][c8];
    }
}

// ctxW[g] = (psum[g]/cnt[g]) @ W1[128:,:] + b1
__global__ void k_ctxw_div(const float* __restrict__ psum, const int* __restrict__ pcnt,
                           const float* __restrict__ W1, const float* __restrict__ b1,
                           float* __restrict__ ctxW) {
    __shared__ float pr[128];
    int g = blockIdx.x, j = threadIdx.x;
    pr[j] = psum[g * HID + j] / fmaxf((float)pcnt[g], 1.f);
    __syncthreads();
    float a = b1[j];
    #pragma unroll 4
    for (int k = 0; k < HID; ++k) a += pr[k] * W1[(HID + k) * HID + j];
    ctxW[g * HID + j] = a;
}

// mm finish: h = relu(x2 @ W1a + ctxW[batch]); out = h @ W2 + b2
__global__ __launch_bounds__(256) void k_mm_finish(
        const f16* __restrict__ x2g, const int* __restrict__ batch,
        const float* __restrict__ ctxW, const f16* __restrict__ W1at,
        const float* __restrict__ W2, const float* __restrict__ b2,
        float* __restrict__ out, int N) {
    __shared__ float part[4][16][3];
    int tile = blockIdx.x * 16;
    int t = threadIdx.x, lane = t & 63, w = t >> 6;
    int lr = lane & 15, kb = lane >> 4;
    int cr = min(tile + lr, N - 1);
    f16x8 afr[4];
    #pragma unroll
    for (int kc = 0; kc < 4; ++kc)
        afr[kc] = *(const f16x8*)&x2g[(size_t)cr * HID + kc * 32 + kb * 8];
    int gidx[4];
    #pragma unroll
    for (int r = 0; r < 4; ++r)
        gidx[r] = batch[min(tile + kb * 4 + r, N - 1)];
    float po[4][3] = {};
    #pragma unroll
    for (int q = 0; q < 2; ++q) {
        int ct = w * 2 + q;
        f32x4 c4 = {0.f, 0.f, 0.f, 0.f};
        int col = ct * 16 + lr;
        const f16* wp = W1at + (size_t)col * HID + kb * 8;
        #pragma unroll
        for (int kc = 0; kc < 4; ++kc) {
            f16x8 bf = *(const f16x8*)(wp + kc * 32);
            c4 = __builtin_amdgcn_mfma_f32_16x16x32_f16(afr[kc], bf, c4, 0, 0, 0);
        }
        float w0 = W2[col * 3 + 0], w1 = W2[col * 3 + 1], w2 = W2[col * 3 + 2];
        #pragma unroll
        for (int r = 0; r < 4; ++r) {
            float h = fmaxf(c4[r] + ctxW[gidx[r] * HID + col], 0.f);
            po[r][0] += h * w0;
            po[r][1] += h * w1;
            po[r][2] += h * w2;
        }
    }
    #pragma unroll
    for (int m = 1; m < 16; m <<= 1) {
        #pragma unroll
        for (int r = 0; r < 4; ++r) {
            po[r][0] += __shfl_xor(po[r][0], m);
            po[r][1] += __shfl_xor(po[r][1], m);
            po[r][2] += __shfl_xor(po[r][2], m);
        }
    }
    if (lr == 0) {
        #pragma unroll
        for (int r = 0; r < 4; ++r) {
            part[w][kb * 4 + r][0] = po[r][0];
            part[w][kb * 4 + r][1] = po[r][1];
            part[w][kb * 4 + r][2] = po[r][2];
        }
    }
    __syncthreads();
    if (t < 48) {
        int row = t / 3, c = t - row * 3;
        int gr2 = tile + row;
        if (gr2 < N)
            out[(size_t)gr2 * 3 + c] = part[0][row][c] + part[1][row][c] +
                                       part[2][row][c] + part[3][row][c] + b2[c];
    }
}

// ---------------- launch ----------------

extern "C" void kernel_launch(void* const* d_in, const int* in_sizes, int n_in,
                              void* d_out, int out_size, void* d_ws, size_t ws_size,
                              hipStream_t stream) {
    const int*   residue_p = (const int*)d_in[0];
    const float* pos_p     = (const float*)d_in[1];
    const int*   ei_p      = (const int*)d_in[2];
    const int*   batch_p   = (const int*)d_in[3];
    const int*   residue_m = (const int*)d_in[4];
    const float* pos_m     = (const float*)d_in[5];
    const int*   ei_m      = (const int*)d_in[6];
    const int*   batch_m   = (const int*)d_in[7];
    const float* W_p1 = (const float*)d_in[8];
    const float* b_p1 = (const float*)d_in[9];
    const float* W_p2 = (const float*)d_in[10];
    const float* b_p2 = (const float*)d_in[11];
    const float* W_m1 = (const float*)d_in[12];
    const float* b_m1 = (const float*)d_in[13];
    const float* W_m2 = (const float*)d_in[14];
    const float* b_m2 = (const float*)d_in[15];
    const float* W1   = (const float*)d_in[16];
    const float* b1   = (const float*)d_in[17];
    const float* W2   = (const float*)d_in[18];
    const float* b2   = (const float*)d_in[19];

    const int N_P = in_sizes[0];
    const int E_P = in_sizes[2] / 2;
    const int N_M = in_sizes[4];
    const int E_M = in_sizes[6] / 2;
    const int G = 64;
    const int NB_P = (N_P + 63) / 64;
    const int NB_M = (N_M + 63) / 64;
    const int PB = (N_P + 15) / 16;
    const int MB = (N_M + 15) / 16;

    char* ws = (char*)d_ws;
    size_t off = 0;
    auto alloc = [&](size_t bytes) {
        char* p = ws + off;
        off += (bytes + 511) & ~size_t(511);
        return p;
    };
    f16*           y1_p   = (f16*)  alloc((size_t)N_P * HID * 2);
    f16*           y1_m   = (f16*)  alloc((size_t)N_M * HID * 2);
    f16*           x2g    = (f16*)  alloc((size_t)N_M * HID * 2);
    f16x4*         rec8_p = (f16x4*)alloc((size_t)N_P * 8);
    f16x4*         rec8_m = (f16x4*)alloc((size_t)N_M * 8);
    float*         dinv_p = (float*)alloc((size_t)N_P * 4);
    float*         dinv_m = (float*)alloc((size_t)N_M * 4);
    int*           rp_p   = (int*)  alloc((size_t)N_P * 4);
    int*           rp_m   = (int*)  alloc((size_t)N_M * 4);
    int*           re_p   = (int*)  alloc((size_t)N_P * 4);
    int*           re_m   = (int*)  alloc((size_t)N_M * 4);
    int*           bcur_p = (int*)  alloc((NBMAX + 1) * 4);
    int*           bcur_m = (int*)  alloc((NBMAX + 1) * 4);
    unsigned int*  prs_p  = (unsigned int*)alloc((size_t)NB_P * CAP * 4);
    unsigned int*  prs_m  = (unsigned int*)alloc((size_t)NB_M * CAP * 4);
    int*           csr_p  = (int*)  alloc((size_t)NB_P * CAP * 4);
    int*           csr_m  = (int*)  alloc((size_t)NB_M * CAP * 4);
    float*         psum   = (float*)alloc((size_t)G * HID * 4);
    int*           pcnt   = (int*)  alloc((size_t)G * 4);
    float*         ctxW   = (float*)alloc((size_t)G * HID * 4);
    f16*           Wp2t   = (f16*)  alloc(128 * 128 * 2);
    f16*           Wm2t   = (f16*)  alloc(128 * 128 * 2);
    f16*           W1at   = (f16*)  alloc(128 * 128 * 2);

    const int TP = (E_P + BIN_T - 1) / BIN_T;
    const int TM = (E_M + BIN_T - 1) / BIN_T;

    // 1. prep (weights, cursor init, graph sizes)
    k_prep_all<<<64, 256, 0, stream>>>(W_p2, W_m2, W1, Wp2t, Wm2t, W1at,
                                       bcur_p, bcur_m, batch_p, pcnt, psum, N_P);
    // 2. binning into padded buckets (res packed into pairs bits 17..21)
    k_tile_bin2<<<TP + TM, 256, 0, stream>>>(ei_p, ei_p + E_P, residue_p, bcur_p, prs_p,
                                             E_P, NB_P, TP,
                                             ei_m, ei_m + E_M, residue_m, bcur_m, prs_m,
                                             E_M, NB_M);
    // 3. fill A: counts -> rowptr/rowend, dinv, rec8, csr scatter
    k_fill_a<<<NB_P + NB_M, 256, 0, stream>>>(
        prs_p, bcur_p, pos_p, rec8_p, dinv_p, rp_p, re_p, csr_p, N_P, NB_P,
        prs_m, bcur_m, pos_m, rec8_m, dinv_m, rp_m, re_m, csr_m, N_M);
    // 4. layer 1 (both branches, node-centric)
    k_l1<<<NB_P + NB_M, 256, 0, stream>>>(
        csr_p, rp_p, re_p, rec8_p, residue_p, W_p1, b_p1, dinv_p, y1_p, N_P, NB_P,
        csr_m, rp_m, re_m, rec8_m, residue_m, W_m1, b_m1, dinv_m, y1_m, N_M);
    // 5. combined: protein agg+gemm+pool || mm agg+x2
    k_agg_combined<<<PB + MB, 256, 0, stream>>>(
        y1_p, rp_p, re_p, csr_p, dinv_p, Wp2t, b_p2, batch_p, psum, N_P, PB,
        y1_m, rp_m, re_m, csr_m, dinv_m, Wm2t, b_m2, x2g, N_M);
    // 6. ctxW
    k_ctxw_div<<<G, HID, 0, stream>>>(psum, pcnt, W1, b1, ctxW);
    // 7. mm finish: x2 -> h -> out
    k_mm_finish<<<MB, 256, 0, stream>>>(x2g, batch_m, ctxW, W1at, W2, b2,
                                        (float*)d_out, N_M);
}